// Round 7
// baseline (897.552 us; speedup 1.0000x reference)
//
#include <hip/hip_runtime.h>
#include <math.h>

// ---------------- constants ----------------
#define NSAMP 32768
#define NFRM  128

// ---- ws layout (float offsets) ----
static constexpr int S_OFF  = 0;                   // 32772 (prefix sums, 32769 used)
static constexpr int HP     = 32772;               // 16384
static constexpr int NSQ    = HP + 16384;          // 16 (unused now)
static constexpr int HA     = NSQ + 16;            // 16384
static constexpr int HB     = HA + 16384;          // 16384
static constexpr int TFQ    = HA;                  // 32768 tf scores (overlays HA+HB, dead after topk)
static constexpr int WC     = HB + 16384;          // 245760 combined dilated weights
static constexpr int WBC    = WC + 245760;         // 640 combined dilated bias
static constexpr int EWS    = WBC + 640;           // 2048 encoded
static constexpr int TIMEO  = EWS + 2048;          // 2048
static constexpr int TRANSO = TIMEO + 2048;        // 2048
static constexpr int PE     = TRANSO + 2048;       // 2048 softmax impulse weights
static constexpr int RSEL   = PE + 2048;           // 1024 (unused now)
static constexpr int ENVO   = RSEL + 1024;         // 4096 env (16,256)
static constexpr int BUFA   = ENVO + 4096;         // 524288  (env stack A)
static constexpr int BUFB   = BUFA + 524288;       // 524288  (env stack B)
static constexpr int WT     = BUFB + 524288;       // transposed weights, 1064960 total
static constexpr int WT_POS = WT;                  // 327680  [l][(c*4+k)*128+o]
static constexpr int WT_ENV = WT + 327680;         // 294912  [l][(c*3+k)*128+o]
static constexpr int WT_TFU = WT + 622592;         // 147456
static constexpr int WT_TT  = WT + 770048;         // 16384   [c][o]
static constexpr int WT_TR  = WT + 786432;         // 16384
static constexpr int LT_POS = WT + 802816;         // 65536   [k][r], R=512
static constexpr int LT_ENV = WT + 868352;         // 65536
static constexpr int LT_TFU = WT + 933888;         // 131072  [k][r], R=1024
static constexpr int SINES  = WT + 1064960;        // 2097152 (64 x 32768)
static constexpr int ENVS   = SINES + 2097152;     // 524288 (16 x 32768 f32)
// SLAB overlays SINES+ENVS (both dead once k_bigmfma runs)
static constexpr int SLAB   = SINES;
// bf16 conv operands (ushort-indexed off these f32 offsets)
static constexpr int CRB0   = ENVS + 524288;       // 16 x 32832 ushort ; CRB0[x]=c[32768-x]
static constexpr int CRB1   = CRB0 + 262656;       // 16 x 32832 ushort ; CRB1[y]=c[32767-y]
static constexpr int KB     = CRB1 + 262656;       // 16 x 34816 ushort ; KB[2048+u]=K[u]
// pos / tfu stack ping-pong buffers (disjoint from env's BUFA/BUFB)
static constexpr int PA     = KB + 278528;         // 262144
static constexpr int PB     = PA + 262144;         // 262144
static constexpr int TA     = PB + 262144;         // 131072
static constexpr int TB     = TA + 131072;         // 131072

// ---- output offsets ----
static constexpr int O_IDX  = 32768;
static constexpr int O_ENC  = 32784;
static constexpr int O_ENV  = 34832;
static constexpr int O_TIME = 38928;
static constexpr int O_TR   = 40976;

typedef short bf16x8 __attribute__((ext_vector_type(8)));
typedef float f32x4  __attribute__((ext_vector_type(4)));
typedef float f32x16 __attribute__((ext_vector_type(16)));

static __device__ __forceinline__ unsigned short f2bf(float f){
  unsigned int u = __float_as_uint(f);
  unsigned int r = (u + 0x7FFFu + ((u >> 16) & 1u)) >> 16;
  return (unsigned short)r;
}

// ================= fused setup: prefix + wtrans + combW + sines + zero =================
// Block map: [0]=prefix, [1,1041)=wtrans, [1041,1121)=combW, [1121,3169)=sines, [3169,3201)=zero
__global__ void k_setup(const float* __restrict__ x,
                        const float* __restrict__ posw, const float* __restrict__ envw,
                        const float* __restrict__ tfuw, const float* __restrict__ ttw,
                        const float* __restrict__ trw,  const float* __restrict__ lpw,
                        const float* __restrict__ lew,  const float* __restrict__ ltw,
                        const float* __restrict__ dw,   const float* __restrict__ db,
                        const float* __restrict__ pw,   const float* __restrict__ pb2,
                        float* __restrict__ ws){
  __shared__ float ps[1024];
  int b = blockIdx.x, tid = threadIdx.x;
  if (b == 0){
    // exclusive prefix sums of x into S
    float* S = ws + S_OFF;
    float v[32];
    const float4* x4 = (const float4*)(x + tid*32);
    float s = 0.f;
#pragma unroll
    for (int i=0;i<8;++i){
      float4 q = x4[i];
      v[4*i]=q.x; v[4*i+1]=q.y; v[4*i+2]=q.z; v[4*i+3]=q.w;
      s += q.x+q.y+q.z+q.w;
    }
    ps[tid] = s; __syncthreads();
    for (int ofs=1; ofs<1024; ofs<<=1){
      float add = (tid>=ofs)? ps[tid-ofs] : 0.f;
      __syncthreads();
      ps[tid] += add;
      __syncthreads();
    }
    float run = ps[tid] - s;
#pragma unroll
    for (int i=0;i<32;++i){ S[tid*32+i] = run; run += v[i]; }
    if (tid==1023) S[32768] = ps[1023];
  } else if (b < 1041){
    int i = (b-1)*1024 + tid;
    float v;
    if (i < 327680){                       // pos_up (5,128,128,4) -> [l][(c*4+k)*128+o]
      int l = i>>16, r = i & 65535, o = r & 127, ck = r>>7, c = ck>>2, k = ck&3;
      v = posw[(l<<16) + (((o<<7)+c)<<2) + k];
    } else if (i < 622592){                // env_up (6,128,128,3)
      int i2 = i - 327680; int l = i2/49152, r = i2 - l*49152, o = r&127, ck = r>>7;
      int c = ck/3, k = ck - 3*c;
      v = envw[l*49152 + ((o<<7)+c)*3 + k];
    } else if (i < 770048){                // tfu_up (3,128,128,3)
      int i2 = i - 622592; int l = i2/49152, r = i2 - l*49152, o = r&127, ck = r>>7;
      int c = ck/3, k = ck - 3*c;
      v = tfuw[l*49152 + ((o<<7)+c)*3 + k];
    } else if (i < 786432){                // tt_w -> [c][o]
      int i2 = i - 770048; int o = i2 & 127, c = i2 >> 7;
      v = ttw[(o<<7) + c];
    } else if (i < 802816){                // tr_w
      int i2 = i - 786432; int o = i2 & 127, c = i2 >> 7;
      v = trw[(o<<7) + c];
    } else if (i < 868352){                // pos_lin -> [k][r]
      int i2 = i - 802816; int r = i2 & 511, k = i2 >> 9;
      v = lpw[(r<<7) + k];
    } else if (i < 933888){                // env_lin
      int i2 = i - 868352; int r = i2 & 511, k = i2 >> 9;
      v = lew[(r<<7) + k];
    } else {                               // tfu_lin
      int i2 = i - 933888; int r = i2 & 1023, k = i2 >> 10;
      v = ltw[(r<<7) + k];
    }
    ws[WT + i] = v;
  } else if (b < 1121){
    // combW: fold pointwise (pw) into dilated weights
    int idx = (b-1041)*1024 + tid;
    if (idx < 81920){
      int l = idx >> 14, r = idx & 16383, o = r >> 7, c = r & 127;
      float a0=0.f, a1=0.f, a2=0.f;
      for (int m=0;m<128;++m){
        float p = pw[(l*128 + o)*128 + m];
        const float* dp = dw + ((l*128 + m)*128 + c)*3;
        a0 += p*dp[0]; a1 += p*dp[1]; a2 += p*dp[2];
      }
      float* W = ws + WC + ((l*128 + o)*128 + c)*3;
      W[0]=a0; W[1]=a1; W[2]=a2;
      if (c==0){
        float bb = pb2[l*128 + o];
        for (int m=0;m<128;++m) bb += pw[(l*128 + o)*128 + m] * db[l*128 + m];
        ws[WBC + l*128 + o] = bb;
      }
    }
  } else if (b < 3169){
    int b2 = b - 1121;
    int band = b2 >> 5;
    int t = ((b2 & 31) << 10) + tid;
    if (tid == 0){
      float l0 = __fdiv_rn((float)log(20.0),   (float)log(10.0));
      float l1 = __fdiv_rn((float)log(9922.5), (float)log(10.0));
      float dl = __fdiv_rn(__fsub_rn(l1, l0), 63.0f);
      float lb = __fadd_rn(l0, __fmul_rn((float)band, dl));
      float freq = (float)pow(10.0, (double)lb);
      ps[0] = __fmul_rn((float)(2.0*M_PI), freq);
    }
    __syncthreads();
    float w = ps[0];
    float tn = __fdiv_rn((float)t, 22050.0f);
    ws[SINES + band*NSAMP + t] = sinf(__fmul_rn(w, tn));
  } else {
    int i = (b-3169)*1024 + tid;   // [0,32768)
    {
      int e = i >> 11, r = i & 2047;
      ((unsigned short*)(ws + KB))[e*34816 + r] = 0;
    }
    if (i < 16*128){
      int e = i >> 7, r = i & 127;
      if (r < 64) ((unsigned short*)(ws + CRB0))[e*32832 + (r==0 ? 0 : 32768 + r)] = 0;
      else        ((unsigned short*)(ws + CRB1))[e*32832 + 32768 + (r-64)] = 0;
    }
  }
}

// ================= front-end =================

__global__ void k_fbpool(const float* __restrict__ fbw, float* __restrict__ ws){
  const float* S = ws + S_OFF;
  int c = blockIdx.x >> 5, j0 = (blockIdx.x & 31) << 2;
  int jj = threadIdx.x >> 7, kk = threadIdx.x & 127;
  int j = j0 + jj;
  int i0 = max(0, 256*j - 256), i1 = min(32767, 256*j + 255);
  float acc = 0.f;
#pragma unroll
  for (int m=0;m<4;++m){
    int k = kk + (m<<7);
    int hi = min(max(i1 + k - 255, 0), 32768);
    int lo = min(max(i0 + k - 256, 0), 32768);
    acc += fbw[c*512 + k] * (S[hi] - S[lo]);
  }
  for (int o=32;o;o>>=1) acc += __shfl_down(acc, o);
  __shared__ float red[8];
  if ((threadIdx.x & 63) == 0) red[threadIdx.x>>6] = acc;
  __syncthreads();
  if (threadIdx.x < 4)
    ws[HP + c*128 + j0 + threadIdx.x] = (red[2*threadIdx.x] + red[2*threadIdx.x+1]) * (1.0f/512.0f);
}

__global__ void k_reduce(const float* __restrict__ rw, const float* __restrict__ rb,
                         float* __restrict__ ws){
  int o = blockIdx.x, t = threadIdx.x;
  const float* hp = ws + HP;
  float sq = 0.f;
  for (int i=t;i<16384;i+=128){ float v = hp[i]; sq += v*v; }
  for (int ofs=32;ofs;ofs>>=1) sq += __shfl_down(sq, ofs);
  __shared__ float rr2[2];
  if ((t & 63) == 0) rr2[t>>6] = sq;
  __syncthreads();
  float g = sqrtf(rr2[0] + rr2[1]) + 1e-8f;
  float acc = rb[o];
  for (int c=0;c<128;++c) acc += rw[o*161 + c] * __fdiv_rn(hp[c*128 + t], g);
  float delta = __fdiv_rn(2.0f, 127.0f);
  float p = __fadd_rn(-1.0f, __fmul_rn((float)t, delta));
  acc += rw[o*161 + 128] * p;
  float sc = 1.0f;
  const float PIF = (float)M_PI;
#pragma unroll
  for (int i=0;i<16;++i){
    float f = __fmul_rn(__fmul_rn(p, sc), PIF);
    acc += rw[o*161 + 129 + 2*i] * sinf(f);
    acc += rw[o*161 + 130 + 2*i] * cosf(f);
    sc = sc * 2.0f;
  }
  ws[HA + o*128 + t] = acc;
}

// dilated conv layer: full input tile LDS-staged
__global__ void k_dil(float* __restrict__ ws, int l, int d, int inoff, int outoff){
  __shared__ float xin[16384];
  int o = blockIdx.x, t = threadIdx.x;
  const float* in = ws + inoff;
  for (int idx=t; idx<16384; idx+=128) xin[idx] = in[idx];
  __syncthreads();
  const float* Wo = ws + WC + (l*128 + o)*384;
  float acc = xin[o*128 + t] + ws[WBC + l*128 + o];
  for (int c=0;c<128;++c){
    float v0 = (t-d >= 0)  ? xin[c*128 + t - d] : 0.f;
    float v1 = xin[c*128 + t];
    float v2 = (t+d < 128) ? xin[c*128 + t + d] : 0.f;
    acc += Wo[c*3]*v0 + Wo[c*3+1]*v1 + Wo[c*3+2]*v2;
  }
  ws[outoff + o*128 + t] = acc >= 0.f ? acc : 0.2f*acc;
}

// topk + encoded (selection only)
__global__ void k_topk(float* __restrict__ ws, float* __restrict__ out){
  const float* h = ws + HB;
  int t = threadIdx.x;
  __shared__ float nt[128], nt0[128];
  __shared__ int idxs[16];
  __shared__ float r2[2];
  __shared__ float wv[2]; __shared__ int wi[2];
  float colsq = 0.f;
  for (int c=0;c<128;++c){ float v = h[c*128 + t]; colsq += v*v; }
  float s = colsq;
  for (int o=32;o;o>>=1) s += __shfl_down(s, o);
  if ((t & 63) == 0) r2[t>>6] = s;
  __syncthreads();
  float g2 = sqrtf(r2[0] + r2[1]) + 1e-8f;
  float sq2 = 0.f;
  for (int c=0;c<128;++c){ float v = __fdiv_rn(h[c*128 + t], g2); sq2 += v*v; }
  float ntv = sqrtf(sq2);
  nt[t] = ntv; nt0[t] = ntv;
  __syncthreads();
  for (int j=0;j<16;++j){
    float v = nt[t]; int bi = t;
    for (int o=32;o;o>>=1){
      float ov = __shfl_down(v, o); int oi = __shfl_down(bi, o);
      if (ov > v || (ov == v && oi < bi)){ v = ov; bi = oi; }
    }
    if ((t & 63) == 0){ wv[t>>6] = v; wi[t>>6] = bi; }
    __syncthreads();
    if (t == 0){
      int win = (wv[1] > wv[0] || (wv[1] == wv[0] && wi[1] < wi[0])) ? wi[1] : wi[0];
      idxs[j] = win; nt[win] = -3.0e38f;
    }
    __syncthreads();
  }
  if (t < 16) out[O_IDX + t] = (float)idxs[t];
  for (int j=0;j<16;++j){
    int ij = idxs[j];
    float hv = __fdiv_rn(h[t*128 + ij], g2);
    float enc = __fdiv_rn(hv, nt0[ij] + 1e-8f);
    out[O_ENC + j*128 + t] = enc;
    ws[EWS + j*128 + t] = enc;
  }
}

// time/transfer linears: 32 blocks x 1024 (8-way c-split + LDS reduce)
__global__ void k_tt(float* __restrict__ ws, const float* __restrict__ ttb,
                     const float* __restrict__ trb, float* __restrict__ out){
  int kind = blockIdx.x >> 4, j = blockIdx.x & 15;
  int tid = threadIdx.x;
  int o = tid & 127, cg = tid >> 7;     // 8 c-groups
  __shared__ float er[128];
  __shared__ float part[8][128];
  if (tid < 128) er[tid] = ws[EWS + j*128 + tid];
  __syncthreads();
  const float* Wt = ws + (kind ? WT_TR : WT_TT);
  float acc = 0.f;
  for (int c=cg; c<128; c+=8) acc += er[c] * Wt[c*128 + o];
  part[cg][o] = acc;
  __syncthreads();
  if (tid < 128){
    float a = kind ? trb[tid] : ttb[tid];
#pragma unroll
    for (int g=0; g<8; ++g) a += part[g][tid];
    out[(kind ? O_TR : O_TIME) + j*128 + tid] = a;
    ws[(kind ? TRANSO : TIMEO) + j*128 + tid] = a;
  }
}

// ================= decoder stacks (fused across pos/env/tfu) =================

__global__ void k_lin3(float* __restrict__ ws, const float* __restrict__ plb,
                       const float* __restrict__ elb, const float* __restrict__ tlb){
  int b = blockIdx.x, tid = threadIdx.x;
  int stack = b >> 4, e = b & 15;
  int zoff  = (stack == 0) ? TIMEO : TRANSO;
  int ltoff = (stack == 0) ? LT_POS : (stack == 1) ? LT_ENV : LT_TFU;
  int R     = (stack == 2) ? 1024 : 512;
  int start = (stack == 2) ? 8 : 4;
  int dst   = (stack == 0) ? PA : (stack == 1) ? BUFA : TA;
  const float* lb = (stack == 0) ? plb : (stack == 1) ? elb : tlb;
  __shared__ float z[128];
  if (tid < 128) z[tid] = ws[zoff + e*128 + tid];
  __syncthreads();
  if (tid < (start<<7)){
    int s = tid >> 7, c = tid & 127;
    int r = c*start + s;
    float acc = lb[r];
    const float* lt = ws + ltoff;
    for (int k=0;k<128;++k) acc += z[k] * lt[k*R + r];
    ws[dst + e*(start<<7) + tid] = acc;   // (e, s, c) layout
  }
}

// convT (k=4, stride2): weights LDS-staged; per-cc xs values register-cached
static __device__ __forceinline__ void convT32_dev(float* __restrict__ ws, const float* __restrict__ bias,
                                                   int srcoff, int dstoff, int wtoff, int Lin,
                                                   int e, int jt, float* xs, float* wl){
  int j0 = jt*32, o = threadIdx.x;
  int s_lo = (j0 >> 1) - 1;
  const float* in = ws + srcoff + e*Lin*128;
  for (int idx=o; idx<18*128; idx+=128){
    int si = idx >> 7, c = idx & 127, s = s_lo + si;
    xs[idx] = (s >= 0 && s < Lin) ? in[s*128 + c] : 0.f;
  }
  float acc[32];
#pragma unroll
  for (int jj=0;jj<32;++jj) acc[jj] = bias[o];
  const float* wt = ws + wtoff;
  for (int cb=0; cb<128; cb+=16){
    __syncthreads();
    for (int idx=o; idx<8192; idx+=128) wl[idx] = wt[(cb<<9) + idx];
    __syncthreads();
#pragma unroll
    for (int cc=0; cc<16; ++cc){
      int c = cb + cc;
      float w0 = wl[((cc<<2)+0)*128 + o];
      float w1 = wl[((cc<<2)+1)*128 + o];
      float w2 = wl[((cc<<2)+2)*128 + o];
      float w3 = wl[((cc<<2)+3)*128 + o];
      float xr[18];
#pragma unroll
      for (int s=0;s<18;++s) xr[s] = xs[(s<<7) + c];   // 18 reads, not 96
#pragma unroll
      for (int jj=0;jj<32;++jj){
        if ((jj & 1) == 0){
          acc[jj] += xr[jj>>1]*w3 + xr[(jj>>1)+1]*w1;
        } else {
          acc[jj] += xr[(jj+1)>>1]*w2 + xr[((jj+1)>>1)+1]*w0;
        }
      }
    }
  }
  int Lout = Lin*2;
  float* outp = ws + dstoff + e*Lout*128;
#pragma unroll
  for (int jj=0;jj<32;++jj){
    if (j0+jj < Lout){
      float v = acc[jj];
      outp[(j0+jj)*128 + o] = v >= 0.f ? v : 0.2f*v;
    }
  }
}

// conv3 on nearest-2x-upsampled input: weights LDS-staged; per-cc xs register-cached
static __device__ __forceinline__ void conv3up32_dev(float* __restrict__ ws, const float* __restrict__ bias,
                                                     int srcoff, int dstoff, int wtoff, int Lin,
                                                     int e, int jt, float* xs, float* wl){
  int j0 = jt*32, o = threadIdx.x;
  int fs = (j0 >> 1) - 1;
  const float* in = ws + srcoff + e*Lin*128;
  for (int idx=o; idx<18*128; idx+=128){
    int si = idx >> 7, c = idx & 127, s = fs + si;
    xs[idx] = (s >= 0 && s < Lin) ? in[s*128 + c] : 0.f;
  }
  float acc[32];
#pragma unroll
  for (int jj=0;jj<32;++jj) acc[jj] = bias[o];
  const float* wt = ws + wtoff;
  for (int cb=0; cb<128; cb+=16){
    __syncthreads();
    for (int idx=o; idx<6144; idx+=128) wl[idx] = wt[cb*384 + idx];
    __syncthreads();
#pragma unroll
    for (int cc=0; cc<16; ++cc){
      int c = cb + cc;
      float w0 = wl[(cc*3+0)*128 + o];
      float w1 = wl[(cc*3+1)*128 + o];
      float w2 = wl[(cc*3+2)*128 + o];
      float xr[18];
#pragma unroll
      for (int s=0;s<18;++s) xr[s] = xs[(s<<7) + c];   // 18 reads, not 96
#pragma unroll
      for (int jj=0;jj<32;++jj){
        acc[jj] += xr[((jj-1)>>1)+1]*w0
                 + xr[((jj  )>>1)+1]*w1
                 + xr[((jj+1)>>1)+1]*w2;
      }
    }
  }
  int Lout = Lin*2;
  float* outp = ws + dstoff + e*Lout*128;
#pragma unroll
  for (int jj=0;jj<32;++jj){
    if (j0+jj < Lout){
      float v = acc[jj];
      outp[(j0+jj)*128 + o] = v >= 0.f ? v : 0.2f*v;
    }
  }
}

__global__ __launch_bounds__(128)
void k_layer(float* __restrict__ ws, const float* __restrict__ pbias,
             const float* __restrict__ ebias, const float* __restrict__ tbias,
             int c1, int c2,
             int pLin, int pWt, int pBo, int pNJ, int pSrc, int pDst,
             int eLin, int eWt, int eBo, int eNJ, int eSrc, int eDst,
             int tLin, int tWt, int tBo, int tNJ, int tSrc, int tDst){
  __shared__ float xs[18*128];
  __shared__ float wl[8192];
  int b = blockIdx.x;
  if (b < c1){
    int e = b / pNJ, jt = b - e*pNJ;
    convT32_dev(ws, pbias + pBo, pSrc, pDst, pWt, pLin, e, jt, xs, wl);
  } else if (b < c2){
    int bl = b - c1; int e = bl / eNJ, jt = bl - e*eNJ;
    conv3up32_dev(ws, ebias + eBo, eSrc, eDst, eWt, eLin, e, jt, xs, wl);
  } else {
    int bl = b - c2; int e = bl / tNJ, jt = bl - e*tNJ;
    conv3up32_dev(ws, tbias + tBo, tSrc, tDst, tWt, tLin, e, jt, xs, wl);
  }
}

// fused epilogues: blocks 0..15 out_pos, 16..79 out_env, 80..143 out_tfu ; 256 threads
__global__ void k_outs(float* __restrict__ ws,
                       const float* __restrict__ pw, const float* __restrict__ pb,
                       const float* __restrict__ ew, const float* __restrict__ eb,
                       const float* __restrict__ tw, const float* __restrict__ tb_,
                       float* __restrict__ out){
  __shared__ float xs[16384];
  int b = blockIdx.x, tid = threadIdx.x;
  if (b < 16){
    int e = b;
    const float* in = ws + PB + e*16384;
    for (int idx=tid; idx<16384; idx+=256){
      int q = idx >> 7, c = idx & 127;
      xs[(q<<7) + ((c+q)&127)] = in[idx];
    }
    __syncthreads();
    float acc = pb[0];
    if (tid < 128){
      int j = tid;
      for (int c=0;c<128;++c){
#pragma unroll
        for (int k=0;k<3;++k){
          int q = j + k - 1;
          if (q >= 0 && q < 128) acc += xs[(q<<7) + ((c+q)&127)] * pw[c*3 + k];
        }
      }
    }
    __syncthreads();
    xs[tid] = (tid < 128) ? acc : -3.0e38f;
    __syncthreads();
    for (int s=128; s>=1; s>>=1){ if (tid < s) xs[tid] = fmaxf(xs[tid], xs[tid+s]); __syncthreads(); }
    float m = xs[0];
    __syncthreads();
    float ex = (tid < 128) ? expf(__fsub_rn(acc, m)) : 0.f;
    xs[tid] = ex;
    __syncthreads();
    for (int s=128; s>=1; s>>=1){ if (tid < s) xs[tid] += xs[tid+s]; __syncthreads(); }
    if (tid < 128) ws[PE + e*128 + tid] = __fdiv_rn(ex, xs[0]);
  } else if (b < 80){
    int idx2 = b - 16; int e = idx2 >> 2, b0 = (idx2 & 3) << 6;
    const float* in = ws + BUFA + e*32768;
    for (int idx=tid; idx<8448; idx+=256){
      int qs = idx >> 7, c = idx & 127, q = b0 - 1 + qs;
      xs[(qs<<7) + ((c+qs)&127)] = (q >= 0 && q < 256) ? in[q*128 + c] : 0.f;
    }
    __syncthreads();
    int part = tid >> 6, bb = tid & 63;
    float acc = (part == 0) ? eb[0] : 0.f;
    for (int c2=0;c2<32;++c2){
      int c = part*32 + c2;
#pragma unroll
      for (int k=0;k<3;++k){
        int qs = bb + k;
        acc += xs[(qs<<7) + ((c+qs)&127)] * ew[c*3 + k];
      }
    }
    xs[8448 + tid] = acc;
    __syncthreads();
    if (tid < 64){
      float a = xs[8448+tid] + xs[8448+64+tid] + xs[8448+128+tid] + xs[8448+192+tid];
      a = fmaxf(a, 0.f);
      out[O_ENV + e*256 + b0 + tid] = a;
      ws[ENVO + e*256 + b0 + tid] = a;
    }
  } else {
    // out_tfu: 64 blocks = (event e, rr-group rg of 8 rows); all-LDS inner loop
    int b2 = b - 80; int e = b2 >> 2, rg = b2 & 3;
    float* tws = xs + 8448;              // 3072 floats
    const float* in = ws + TB + e*8192;
    for (int idx=tid; idx<8448; idx+=256){
      int qs = idx >> 7, c = idx & 127, q = -1 + qs;
      xs[(qs<<7) + ((c+qs)&127)] = (q >= 0 && q < 64) ? in[q*128 + c] : 0.f;
    }
    for (int idx=tid; idx<3072; idx+=256) tws[idx] = tw[rg*3072 + idx];
    __syncthreads();
    int rl0 = tid >> 6, bb = tid & 63;
    for (int rl=rl0; rl<8; rl+=4){
      int rr = rg*8 + rl;
      float acc = tb_[rr];
      for (int c=0;c<128;++c){
#pragma unroll
        for (int k=0;k<3;++k){
          int qs = bb + k;
          acc += xs[(qs<<7) + ((c+qs)&127)] * tws[rl*384 + c*3 + k];
        }
      }
      ws[TFQ + e*2048 + rr*64 + bb] = acc;
    }
  }
}

// ================= synthesis =================

// fused: blocks 0..2047 resonance-K (bf16, with inline argmax), blocks 2048..4095 envs
__global__ void k_envK(float* __restrict__ ws, const float* __restrict__ noise){
  int b = blockIdx.x, tid = threadIdx.x;
  if (b < 2048){
    int e = b >> 7, F = b & 127;
    int t = (F << 8) + tid;
    __shared__ float ampl[64];
    if (tid < 64){
      const float* tf = ws + TFQ + e*2048;
      float best = tf[tid]; int bi = 0;
      for (int r=1;r<32;++r){ float v = tf[r*64 + tid]; if (v > best){ best = v; bi = r; } }
      float d = __fadd_rn(0.5f, __fmul_rn((float)bi, __fdiv_rn(__fsub_rn(0.9999f, 0.5f), 31.0f)));
      ampl[tid] = (float)pow((double)d, (double)F);
    }
    __syncthreads();
    float acc = 0.f;
    for (int band=0;band<64;++band) acc += ws[SINES + band*NSAMP + t] * ampl[band];
    ((unsigned short*)(ws + KB))[e*34816 + 2048 + t] = f2bf(acc * (1.0f/(64.0f*65536.0f)));
  } else {
    int idx = (b - 2048)*256 + tid;
    int e = idx >> 15, tau = idx & 32767;
    float cf = __fsub_rn(__fdiv_rn(__fmul_rn(__fadd_rn((float)tau, 0.5f), 256.0f), 32768.0f), 0.5f);
    float c = fminf(fmaxf(cf, 0.0f), 255.0f);
    int i0 = (int)floorf(c);
    int i1 = min(i0 + 1, 255);
    float w = __fsub_rn(c, (float)i0);
    float e0 = ws[ENVO + e*256 + i0], e1 = ws[ENVO + e*256 + i1];
    float val = __fadd_rn(__fmul_rn(e0, __fsub_rn(1.0f, w)), __fmul_rn(e1, w));
    ws[ENVS + e*NSAMP + tau] = val * noise[tau];
  }
}

// impulse-comb conv; writes reversed bf16 copies (CRB0/CRB1) for the MFMA stage
__global__ void k_c(float* __restrict__ ws){
  int e = blockIdx.x >> 5, seg = blockIdx.x & 31;
  int t = (seg << 10) + threadIdx.x;
  __shared__ float pl[128];
  if (threadIdx.x < 128) pl[threadIdx.x] = ws[PE + e*128 + threadIdx.x];
  __syncthreads();
  const float* ev = ws + ENVS + e*NSAMP;
  int kub = min(127, (seg << 2) + 3);
  float acc = 0.f;
  for (int k=0;k<=kub;++k){
    int u = t - (k << 8);
    if (u >= 0) acc += pl[k] * ev[u];
  }
  unsigned short hv = f2bf(acc);
  ((unsigned short*)(ws + CRB0))[e*32832 + 32768 - t] = hv;
  ((unsigned short*)(ws + CRB1))[e*32832 + 32767 - t] = hv;
}

// Toeplitz conv via MFMA 32x32x16 bf16; 16 KB LDS two-phase reduction, no atomics.
__global__ __launch_bounds__(256, 4)
void k_bigmfma(float* __restrict__ ws){
  int b = blockIdx.x;
  int w = threadIdx.x >> 6;
  int lane = threadIdx.x & 63;
  int e = b / 72;
  int r = b - e*72;
  int T2 = 0, cum = 0;
  while (cum + ((T2+2)>>1) <= r){ cum += (T2+2)>>1; T2++; }
  int qb = r - cum;
  int nseg = 2*(T2+1);
  int seg = qb*4 + w;
  int t0 = T2 << 11;
  int il = lane & 31, h = lane >> 5;
  __shared__ float red[2][2048];
  f32x16 acc0 = {}; f32x16 acc1 = {};
  if (seg < nseg){
    int u0 = -1984 + (seg << 10);
    const unsigned short* Kp  = (const unsigned short*)(ws + KB)   + e*34816 + 2048;
    const unsigned short* C0p = (const unsigned short*)(ws + CRB0) + e*32832;
    const unsigned short* C1p = (const unsigned short*)(ws + CRB1) + e*32832;
    int bB  = u0 + (il << 6) + (h << 3);
    int bA0 = 32768 - t0 + u0 - (il << 1) + (h << 3);
    int bA1 = bA0 - 2;
#pragma unroll 2
    for (int q = 0; q < 64; ++q){
      union { f32x4 v; bf16x8 s; } a0u, a1u, bu;
      a0u.v = *(const f32x4*)(C0p + bA0);
      a1u.v = *(const f32x4*)(C1p + bA1);
      bu.v  = *(const f32x4*)(Kp  + bB);
      acc0 = __builtin_amdgcn_mfma_f32_32x32x16_bf16(a0u.s, bu.s, acc0, 0, 0, 0);
      acc1 = __builtin_amdgcn_mfma_f32_32x32x16_bf16(a1u.s, bu.s, acc1, 0, 0, 0);
      bA0 += 16; bA1 += 16; bB += 16;
    }
  }
  int wl = w & 1;
  if (w < 2){
#pragma unroll
    for (int rr = 0; rr < 16; ++rr){
      int row = (rr & 3) + ((rr >> 2) << 3) + (h << 2);
      red[wl][(row << 6) + il]      = acc0[rr];
      red[wl][(row << 6) + 32 + il] = acc1[rr];
    }
  }
  __syncthreads();
  if (w >= 2){
#pragma unroll
    for (int rr = 0; rr < 16; ++rr){
      int row = (rr & 3) + ((rr >> 2) << 3) + (h << 2);
      red[wl][(row << 6) + il]      += acc0[rr];
      red[wl][(row << 6) + 32 + il] += acc1[rr];
    }
  }
  __syncthreads();
  float* slab = ws + SLAB + b*2048;
  int tid = threadIdx.x;
#pragma unroll
  for (int jj = 0; jj < 8; ++jj){
    int pos = tid*8 + jj;                // pos = il2*64 + (2*row + p)
    int il2 = pos >> 6, x = pos & 63;
    int idx = ((x >> 1) << 6) + ((x & 1) << 5) + il2;
    slab[pos] = red[0][idx] + red[1][idx];
  }
}

__global__ void k_final(const float* __restrict__ ws, float* __restrict__ out){
  int t = blockIdx.x*1024 + threadIdx.x;
  int T2 = t >> 11, pos = t & 2047;
  int cum = 0;
  for (int j=0;j<T2;++j) cum += (j+2)>>1;
  int nb = (T2+2)>>1;
  float s = 0.f;
  for (int e=0;e<16;++e){
    const float* sl = ws + SLAB + (e*72 + cum)*2048 + pos;
    for (int q=0;q<nb;++q) s += sl[q*2048];
  }
  out[t] = s;
}

// ================= launcher =================

extern "C" void kernel_launch(void* const* d_in, const int* in_sizes, int n_in,
                              void* d_out, int out_size, void* d_ws, size_t ws_size,
                              hipStream_t stream){
  const float* x         = (const float*)d_in[0];
  const float* noise     = (const float*)d_in[1];
  const float* fb_w      = (const float*)d_in[2];
  const float* reduce_w  = (const float*)d_in[3];
  const float* reduce_b  = (const float*)d_in[4];
  const float* dl_dw     = (const float*)d_in[5];
  const float* dl_db     = (const float*)d_in[6];
  const float* dl_pw     = (const float*)d_in[7];
  const float* dl_pb     = (const float*)d_in[8];
  const float* tt_w      = (const float*)d_in[9];
  const float* tt_b      = (const float*)d_in[10];
  const float* tr_w      = (const float*)d_in[11];
  const float* tr_b      = (const float*)d_in[12];
  const float* pos_lin_w = (const float*)d_in[13];
  const float* pos_lin_b = (const float*)d_in[14];
  const float* pos_up_w  = (const float*)d_in[15];
  const float* pos_up_b  = (const float*)d_in[16];
  const float* pos_out_w = (const float*)d_in[17];
  const float* pos_out_b = (const float*)d_in[18];
  const float* env_lin_w = (const float*)d_in[19];
  const float* env_lin_b = (const float*)d_in[20];
  const float* env_up_w  = (const float*)d_in[21];
  const float* env_up_b  = (const float*)d_in[22];
  const float* env_out_w = (const float*)d_in[23];
  const float* env_out_b = (const float*)d_in[24];
  const float* tfu_lin_w = (const float*)d_in[25];
  const float* tfu_lin_b = (const float*)d_in[26];
  const float* tfu_up_w  = (const float*)d_in[27];
  const float* tfu_up_b  = (const float*)d_in[28];
  const float* tfu_out_w = (const float*)d_in[29];
  const float* tfu_out_b = (const float*)d_in[30];
  float* out = (float*)d_out;
  float* ws  = (float*)d_ws;

  k_setup<<<3201, 1024, 0, stream>>>(x, pos_up_w, env_up_w, tfu_up_w, tt_w, tr_w,
                                     pos_lin_w, env_lin_w, tfu_lin_w,
                                     dl_dw, dl_db, dl_pw, dl_pb, ws);
  k_fbpool<<<4096, 512, 0, stream>>>(fb_w, ws);
  k_reduce<<<128, 128, 0, stream>>>(reduce_w, reduce_b, ws);
  const int DIL[5] = {1, 3, 9, 27, 1};
  int src = HA, dst = HB;
  for (int l=0;l<5;++l){
    k_dil<<<128, 128, 0, stream>>>(ws, l, DIL[l], src, dst);
    int tmp = src; src = dst; dst = tmp;
  }
  k_topk<<<1, 128, 0, stream>>>(ws, out);
  k_tt<<<32, 1024, 0, stream>>>(ws, tt_b, tr_b, out);
  k_lin3<<<48, 1024, 0, stream>>>(ws, pos_lin_b, env_lin_b, tfu_lin_b);

  // fused decoder layers (pos convT | env conv3 | tfu conv3)
  k_layer<<<48, 128, 0, stream>>>(ws, pos_up_b, env_up_b, tfu_up_b, 16, 32,
      4,  WT_POS + 0,      0,   1, PA,   PB,
      4,  WT_ENV + 0,      0,   1, BUFA, BUFB,
      8,  WT_TFU + 0,      0,   1, TA,   TB);
  k_layer<<<48, 128, 0, stream>>>(ws, pos_up_b, env_up_b, tfu_up_b, 16, 32,
      8,  WT_POS + 65536,  128, 1, PB,   PA,
      8,  WT_ENV + 49152,  128, 1, BUFB, BUFA,
      16, WT_TFU + 49152,  128, 1, TB,   TA);
  k_layer<<<64, 128, 0, stream>>>(ws, pos_up_b, env_up_b, tfu_up_b, 16, 32,
      16, WT_POS + 131072, 256, 1, PA,   PB,
      16, WT_ENV + 98304,  256, 1, BUFA, BUFB,
      32, WT_TFU + 98304,  256, 2, TA,   TB);
  k_layer<<<64, 128, 0, stream>>>(ws, pos_up_b, env_up_b, tfu_up_b, 32, 64,
      32, WT_POS + 196608, 384, 2, PB,   PA,
      32, WT_ENV + 147456, 384, 2, BUFB, BUFA,
      1,  0,               0,   1, 0,    0);
  k_layer<<<128, 128, 0, stream>>>(ws, pos_up_b, env_up_b, tfu_up_b, 64, 128,
      64, WT_POS + 262144, 512, 4, PA,   PB,
      64, WT_ENV + 196608, 512, 4, BUFA, BUFB,
      1,  0,               0,   1, 0,    0);
  k_layer<<<128, 128, 0, stream>>>(ws, pos_up_b, env_up_b, tfu_up_b, 0, 128,
      1,  0,               0,   1, 0,    0,
      128, WT_ENV + 245760, 640, 8, BUFB, BUFA,
      1,  0,               0,   1, 0,    0);

  k_outs<<<144, 256, 0, stream>>>(ws, pos_out_w, pos_out_b, env_out_w, env_out_b,
                                  tfu_out_w, tfu_out_b, out);

  k_envK<<<4096, 256, 0, stream>>>(ws, noise);
  k_c<<<512, 1024, 0, stream>>>(ws);
  k_bigmfma<<<1152, 256, 0, stream>>>(ws);
  k_final<<<32, 1024, 0, stream>>>(ws, out);
}

// Round 8
// 749.623 us; speedup vs baseline: 1.1973x; 1.1973x over previous
//
#include <hip/hip_runtime.h>
#include <math.h>

// ---------------- constants ----------------
#define NSAMP 32768
#define NFRM  128

// ---- ws layout (float offsets) ----
static constexpr int S_OFF  = 0;
static constexpr int HP     = 32772;
static constexpr int NSQ    = HP + 16384;
static constexpr int HA     = NSQ + 16;
static constexpr int HB     = HA + 16384;
static constexpr int TFQ    = HA;                  // tf scores (overlays HA+HB, dead after topk)
static constexpr int WC     = HB + 16384;
static constexpr int WBC    = WC + 245760;
static constexpr int EWS    = WBC + 640;
static constexpr int TIMEO  = EWS + 2048;
static constexpr int TRANSO = TIMEO + 2048;
static constexpr int PE     = TRANSO + 2048;
static constexpr int RSEL   = PE + 2048;
static constexpr int ENVO   = RSEL + 1024;
static constexpr int BUFA   = ENVO + 4096;
static constexpr int BUFB   = BUFA + 524288;
static constexpr int WT     = BUFB + 524288;
static constexpr int WT_POS = WT;                  // 327680  [l][(c*4+k)*128+o]
static constexpr int WT_ENV = WT + 327680;         // 294912  [l][(c*3+k)*128+o]
static constexpr int WT_TFU = WT + 622592;         // 147456
static constexpr int WT_TT  = WT + 770048;
static constexpr int WT_TR  = WT + 786432;
static constexpr int LT_POS = WT + 802816;
static constexpr int LT_ENV = WT + 868352;
static constexpr int LT_TFU = WT + 933888;
static constexpr int SINES  = WT + 1064960;        // 2097152 (64 x 32768)
static constexpr int ENVS   = SINES + 2097152;
static constexpr int SLAB   = SINES;               // overlays SINES+ENVS
static constexpr int CRB0   = ENVS + 524288;
static constexpr int CRB1   = CRB0 + 262656;
static constexpr int KB     = CRB1 + 262656;
static constexpr int PA     = KB + 278528;
static constexpr int PB     = PA + 262144;
static constexpr int TA     = PB + 262144;
static constexpr int TB     = TA + 131072;

// ---- output offsets ----
static constexpr int O_IDX  = 32768;
static constexpr int O_ENC  = 32784;
static constexpr int O_ENV  = 34832;
static constexpr int O_TIME = 38928;
static constexpr int O_TR   = 40976;

typedef short bf16x8 __attribute__((ext_vector_type(8)));
typedef float f32x4  __attribute__((ext_vector_type(4)));
typedef float f32x16 __attribute__((ext_vector_type(16)));

static __device__ __forceinline__ unsigned short f2bf(float f){
  unsigned int u = __float_as_uint(f);
  unsigned int r = (u + 0x7FFFu + ((u >> 16) & 1u)) >> 16;
  return (unsigned short)r;
}

// ================= fused setup =================
__global__ void k_setup(const float* __restrict__ x,
                        const float* __restrict__ posw, const float* __restrict__ envw,
                        const float* __restrict__ tfuw, const float* __restrict__ ttw,
                        const float* __restrict__ trw,  const float* __restrict__ lpw,
                        const float* __restrict__ lew,  const float* __restrict__ ltw,
                        const float* __restrict__ dw,   const float* __restrict__ db,
                        const float* __restrict__ pw,   const float* __restrict__ pb2,
                        float* __restrict__ ws){
  __shared__ float ps[1024];
  int b = blockIdx.x, tid = threadIdx.x;
  if (b == 0){
    float* S = ws + S_OFF;
    float v[32];
    const float4* x4 = (const float4*)(x + tid*32);
    float s = 0.f;
#pragma unroll
    for (int i=0;i<8;++i){
      float4 q = x4[i];
      v[4*i]=q.x; v[4*i+1]=q.y; v[4*i+2]=q.z; v[4*i+3]=q.w;
      s += q.x+q.y+q.z+q.w;
    }
    ps[tid] = s; __syncthreads();
    for (int ofs=1; ofs<1024; ofs<<=1){
      float add = (tid>=ofs)? ps[tid-ofs] : 0.f;
      __syncthreads();
      ps[tid] += add;
      __syncthreads();
    }
    float run = ps[tid] - s;
#pragma unroll
    for (int i=0;i<32;++i){ S[tid*32+i] = run; run += v[i]; }
    if (tid==1023) S[32768] = ps[1023];
  } else if (b < 1041){
    int i = (b-1)*1024 + tid;
    float v;
    if (i < 327680){
      int l = i>>16, r = i & 65535, o = r & 127, ck = r>>7, c = ck>>2, k = ck&3;
      v = posw[(l<<16) + (((o<<7)+c)<<2) + k];
    } else if (i < 622592){
      int i2 = i - 327680; int l = i2/49152, r = i2 - l*49152, o = r&127, ck = r>>7;
      int c = ck/3, k = ck - 3*c;
      v = envw[l*49152 + ((o<<7)+c)*3 + k];
    } else if (i < 770048){
      int i2 = i - 622592; int l = i2/49152, r = i2 - l*49152, o = r&127, ck = r>>7;
      int c = ck/3, k = ck - 3*c;
      v = tfuw[l*49152 + ((o<<7)+c)*3 + k];
    } else if (i < 786432){
      int i2 = i - 770048; int o = i2 & 127, c = i2 >> 7;
      v = ttw[(o<<7) + c];
    } else if (i < 802816){
      int i2 = i - 786432; int o = i2 & 127, c = i2 >> 7;
      v = trw[(o<<7) + c];
    } else if (i < 868352){
      int i2 = i - 802816; int r = i2 & 511, k = i2 >> 9;
      v = lpw[(r<<7) + k];
    } else if (i < 933888){
      int i2 = i - 868352; int r = i2 & 511, k = i2 >> 9;
      v = lew[(r<<7) + k];
    } else {
      int i2 = i - 933888; int r = i2 & 1023, k = i2 >> 10;
      v = ltw[(r<<7) + k];
    }
    ws[WT + i] = v;
  } else if (b < 1121){
    int idx = (b-1041)*1024 + tid;
    if (idx < 81920){
      int l = idx >> 14, r = idx & 16383, o = r >> 7, c = r & 127;
      float a0=0.f, a1=0.f, a2=0.f;
      for (int m=0;m<128;++m){
        float p = pw[(l*128 + o)*128 + m];
        const float* dp = dw + ((l*128 + m)*128 + c)*3;
        a0 += p*dp[0]; a1 += p*dp[1]; a2 += p*dp[2];
      }
      float* W = ws + WC + ((l*128 + o)*128 + c)*3;
      W[0]=a0; W[1]=a1; W[2]=a2;
      if (c==0){
        float bb = pb2[l*128 + o];
        for (int m=0;m<128;++m) bb += pw[(l*128 + o)*128 + m] * db[l*128 + m];
        ws[WBC + l*128 + o] = bb;
      }
    }
  } else if (b < 3169){
    int b2 = b - 1121;
    int band = b2 >> 5;
    int t = ((b2 & 31) << 10) + tid;
    if (tid == 0){
      float l0 = __fdiv_rn((float)log(20.0),   (float)log(10.0));
      float l1 = __fdiv_rn((float)log(9922.5), (float)log(10.0));
      float dl = __fdiv_rn(__fsub_rn(l1, l0), 63.0f);
      float lb = __fadd_rn(l0, __fmul_rn((float)band, dl));
      float freq = (float)pow(10.0, (double)lb);
      ps[0] = __fmul_rn((float)(2.0*M_PI), freq);
    }
    __syncthreads();
    float w = ps[0];
    float tn = __fdiv_rn((float)t, 22050.0f);
    ws[SINES + band*NSAMP + t] = sinf(__fmul_rn(w, tn));
  } else {
    int i = (b-3169)*1024 + tid;
    {
      int e = i >> 11, r = i & 2047;
      ((unsigned short*)(ws + KB))[e*34816 + r] = 0;
    }
    if (i < 16*128){
      int e = i >> 7, r = i & 127;
      if (r < 64) ((unsigned short*)(ws + CRB0))[e*32832 + (r==0 ? 0 : 32768 + r)] = 0;
      else        ((unsigned short*)(ws + CRB1))[e*32832 + 32768 + (r-64)] = 0;
    }
  }
}

// ================= front-end =================

__global__ void k_fbpool(const float* __restrict__ fbw, float* __restrict__ ws){
  const float* S = ws + S_OFF;
  int c = blockIdx.x >> 5, j0 = (blockIdx.x & 31) << 2;
  int jj = threadIdx.x >> 7, kk = threadIdx.x & 127;
  int j = j0 + jj;
  int i0 = max(0, 256*j - 256), i1 = min(32767, 256*j + 255);
  float acc = 0.f;
#pragma unroll
  for (int m=0;m<4;++m){
    int k = kk + (m<<7);
    int hi = min(max(i1 + k - 255, 0), 32768);
    int lo = min(max(i0 + k - 256, 0), 32768);
    acc += fbw[c*512 + k] * (S[hi] - S[lo]);
  }
  for (int o=32;o;o>>=1) acc += __shfl_down(acc, o);
  __shared__ float red[8];
  if ((threadIdx.x & 63) == 0) red[threadIdx.x>>6] = acc;
  __syncthreads();
  if (threadIdx.x < 4)
    ws[HP + c*128 + j0 + threadIdx.x] = (red[2*threadIdx.x] + red[2*threadIdx.x+1]) * (1.0f/512.0f);
}

__global__ void k_reduce(const float* __restrict__ rw, const float* __restrict__ rb,
                         float* __restrict__ ws){
  int o = blockIdx.x, t = threadIdx.x;
  const float* hp = ws + HP;
  float sq = 0.f;
  for (int i=t;i<16384;i+=128){ float v = hp[i]; sq += v*v; }
  for (int ofs=32;ofs;ofs>>=1) sq += __shfl_down(sq, ofs);
  __shared__ float rr2[2];
  if ((t & 63) == 0) rr2[t>>6] = sq;
  __syncthreads();
  float g = sqrtf(rr2[0] + rr2[1]) + 1e-8f;
  float acc = rb[o];
  for (int c=0;c<128;++c) acc += rw[o*161 + c] * __fdiv_rn(hp[c*128 + t], g);
  float delta = __fdiv_rn(2.0f, 127.0f);
  float p = __fadd_rn(-1.0f, __fmul_rn((float)t, delta));
  acc += rw[o*161 + 128] * p;
  float sc = 1.0f;
  const float PIF = (float)M_PI;
#pragma unroll
  for (int i=0;i<16;++i){
    float f = __fmul_rn(__fmul_rn(p, sc), PIF);
    acc += rw[o*161 + 129 + 2*i] * sinf(f);
    acc += rw[o*161 + 130 + 2*i] * cosf(f);
    sc = sc * 2.0f;
  }
  ws[HA + o*128 + t] = acc;
}

__global__ void k_dil(float* __restrict__ ws, int l, int d, int inoff, int outoff){
  __shared__ float xin[16384];
  int o = blockIdx.x, t = threadIdx.x;
  const float* in = ws + inoff;
  for (int idx=t; idx<16384; idx+=128) xin[idx] = in[idx];
  __syncthreads();
  const float* Wo = ws + WC + (l*128 + o)*384;
  float acc = xin[o*128 + t] + ws[WBC + l*128 + o];
  for (int c=0;c<128;++c){
    float v0 = (t-d >= 0)  ? xin[c*128 + t - d] : 0.f;
    float v1 = xin[c*128 + t];
    float v2 = (t+d < 128) ? xin[c*128 + t + d] : 0.f;
    acc += Wo[c*3]*v0 + Wo[c*3+1]*v1 + Wo[c*3+2]*v2;
  }
  ws[outoff + o*128 + t] = acc >= 0.f ? acc : 0.2f*acc;
}

__global__ void k_topk(float* __restrict__ ws, float* __restrict__ out){
  const float* h = ws + HB;
  int t = threadIdx.x;
  __shared__ float nt[128], nt0[128];
  __shared__ int idxs[16];
  __shared__ float r2[2];
  __shared__ float wv[2]; __shared__ int wi[2];
  float colsq = 0.f;
  for (int c=0;c<128;++c){ float v = h[c*128 + t]; colsq += v*v; }
  float s = colsq;
  for (int o=32;o;o>>=1) s += __shfl_down(s, o);
  if ((t & 63) == 0) r2[t>>6] = s;
  __syncthreads();
  float g2 = sqrtf(r2[0] + r2[1]) + 1e-8f;
  float sq2 = 0.f;
  for (int c=0;c<128;++c){ float v = __fdiv_rn(h[c*128 + t], g2); sq2 += v*v; }
  float ntv = sqrtf(sq2);
  nt[t] = ntv; nt0[t] = ntv;
  __syncthreads();
  for (int j=0;j<16;++j){
    float v = nt[t]; int bi = t;
    for (int o=32;o;o>>=1){
      float ov = __shfl_down(v, o); int oi = __shfl_down(bi, o);
      if (ov > v || (ov == v && oi < bi)){ v = ov; bi = oi; }
    }
    if ((t & 63) == 0){ wv[t>>6] = v; wi[t>>6] = bi; }
    __syncthreads();
    if (t == 0){
      int win = (wv[1] > wv[0] || (wv[1] == wv[0] && wi[1] < wi[0])) ? wi[1] : wi[0];
      idxs[j] = win; nt[win] = -3.0e38f;
    }
    __syncthreads();
  }
  if (t < 16) out[O_IDX + t] = (float)idxs[t];
  for (int j=0;j<16;++j){
    int ij = idxs[j];
    float hv = __fdiv_rn(h[t*128 + ij], g2);
    float enc = __fdiv_rn(hv, nt0[ij] + 1e-8f);
    out[O_ENC + j*128 + t] = enc;
    ws[EWS + j*128 + t] = enc;
  }
}

__global__ void k_tt(float* __restrict__ ws, const float* __restrict__ ttb,
                     const float* __restrict__ trb, float* __restrict__ out){
  int kind = blockIdx.x >> 4, j = blockIdx.x & 15;
  int tid = threadIdx.x;
  int o = tid & 127, cg = tid >> 7;
  __shared__ float er[128];
  __shared__ float part[8][128];
  if (tid < 128) er[tid] = ws[EWS + j*128 + tid];
  __syncthreads();
  const float* Wt = ws + (kind ? WT_TR : WT_TT);
  float acc = 0.f;
  for (int c=cg; c<128; c+=8) acc += er[c] * Wt[c*128 + o];
  part[cg][o] = acc;
  __syncthreads();
  if (tid < 128){
    float a = kind ? trb[tid] : ttb[tid];
#pragma unroll
    for (int g=0; g<8; ++g) a += part[g][tid];
    out[(kind ? O_TR : O_TIME) + j*128 + tid] = a;
    ws[(kind ? TRANSO : TIMEO) + j*128 + tid] = a;
  }
}

// ================= decoder stacks =================

__global__ void k_lin3(float* __restrict__ ws, const float* __restrict__ plb,
                       const float* __restrict__ elb, const float* __restrict__ tlb){
  int b = blockIdx.x, tid = threadIdx.x;
  int stack = b >> 4, e = b & 15;
  int zoff  = (stack == 0) ? TIMEO : TRANSO;
  int ltoff = (stack == 0) ? LT_POS : (stack == 1) ? LT_ENV : LT_TFU;
  int R     = (stack == 2) ? 1024 : 512;
  int start = (stack == 2) ? 8 : 4;
  int dst   = (stack == 0) ? PA : (stack == 1) ? BUFA : TA;
  const float* lb = (stack == 0) ? plb : (stack == 1) ? elb : tlb;
  __shared__ float z[128];
  if (tid < 128) z[tid] = ws[zoff + e*128 + tid];
  __syncthreads();
  if (tid < (start<<7)){
    int s = tid >> 7, c = tid & 127;
    int r = c*start + s;
    float acc = lb[r];
    const float* lt = ws + ltoff;
    for (int k=0;k<128;++k) acc += z[k] * lt[k*R + r];
    ws[dst + e*(start<<7) + tid] = acc;   // (e, s, c) layout
  }
}

// convT (k=4, stride2), JT=8: acc[8], xr[6], weights LDS-chunked
static __device__ __forceinline__ void convT8_dev(float* __restrict__ ws, const float* __restrict__ bias,
                                                  int srcoff, int dstoff, int wtoff, int Lin,
                                                  int e, int jt, float* xs, float* wl){
  int j0 = jt*8, o = threadIdx.x;
  int s_lo = (j0 >> 1) - 1;
  const float* in = ws + srcoff + e*Lin*128;
  for (int idx=o; idx<6*128; idx+=128){
    int si = idx >> 7, c = idx & 127, s = s_lo + si;
    xs[idx] = (s >= 0 && s < Lin) ? in[s*128 + c] : 0.f;
  }
  float acc[8];
#pragma unroll
  for (int jj=0;jj<8;++jj) acc[jj] = bias[o];
  const float* wt = ws + wtoff;
#pragma unroll 1
  for (int cb=0; cb<128; cb+=16){
    __syncthreads();
    for (int idx=o; idx<8192; idx+=128) wl[idx] = wt[(cb<<9) + idx];
    __syncthreads();
#pragma unroll
    for (int cc=0; cc<16; ++cc){
      int c = cb + cc;
      float w0 = wl[((cc<<2)+0)*128 + o];
      float w1 = wl[((cc<<2)+1)*128 + o];
      float w2 = wl[((cc<<2)+2)*128 + o];
      float w3 = wl[((cc<<2)+3)*128 + o];
      float xr[6];
#pragma unroll
      for (int s=0;s<6;++s) xr[s] = xs[(s<<7) + c];
#pragma unroll
      for (int jj=0;jj<8;++jj){
        if ((jj & 1) == 0){
          acc[jj] += xr[jj>>1]*w3 + xr[(jj>>1)+1]*w1;
        } else {
          acc[jj] += xr[(jj+1)>>1]*w2 + xr[((jj+1)>>1)+1]*w0;
        }
      }
    }
  }
  float* outp = ws + dstoff + e*(Lin*2)*128;
#pragma unroll
  for (int jj=0;jj<8;++jj){
    float v = acc[jj];
    outp[(j0+jj)*128 + o] = v >= 0.f ? v : 0.2f*v;
  }
}

// conv3 on nearest-2x-upsampled input, JT=8: acc[8], xr[6], weights LDS-chunked
static __device__ __forceinline__ void conv3up8_dev(float* __restrict__ ws, const float* __restrict__ bias,
                                                    int srcoff, int dstoff, int wtoff, int Lin,
                                                    int e, int jt, float* xs, float* wl){
  int j0 = jt*8, o = threadIdx.x;
  int fs = (j0 >> 1) - 1;
  const float* in = ws + srcoff + e*Lin*128;
  for (int idx=o; idx<6*128; idx+=128){
    int si = idx >> 7, c = idx & 127, s = fs + si;
    xs[idx] = (s >= 0 && s < Lin) ? in[s*128 + c] : 0.f;
  }
  float acc[8];
#pragma unroll
  for (int jj=0;jj<8;++jj) acc[jj] = bias[o];
  const float* wt = ws + wtoff;
#pragma unroll 1
  for (int cb=0; cb<128; cb+=16){
    __syncthreads();
    for (int idx=o; idx<6144; idx+=128) wl[idx] = wt[cb*384 + idx];
    __syncthreads();
#pragma unroll
    for (int cc=0; cc<16; ++cc){
      int c = cb + cc;
      float w0 = wl[(cc*3+0)*128 + o];
      float w1 = wl[(cc*3+1)*128 + o];
      float w2 = wl[(cc*3+2)*128 + o];
      float xr[6];
#pragma unroll
      for (int s=0;s<6;++s) xr[s] = xs[(s<<7) + c];
#pragma unroll
      for (int jj=0;jj<8;++jj){
        acc[jj] += xr[((jj-1)>>1)+1]*w0
                 + xr[((jj  )>>1)+1]*w1
                 + xr[((jj+1)>>1)+1]*w2;
      }
    }
  }
  float* outp = ws + dstoff + e*(Lin*2)*128;
#pragma unroll
  for (int jj=0;jj<8;++jj){
    float v = acc[jj];
    outp[(j0+jj)*128 + o] = v >= 0.f ? v : 0.2f*v;
  }
}

__global__ __launch_bounds__(128, 4)
void k_layer(float* __restrict__ ws, const float* __restrict__ pbias,
             const float* __restrict__ ebias, const float* __restrict__ tbias,
             int c1, int c2,
             int pLin, int pWt, int pBo, int pNJ, int pSrc, int pDst,
             int eLin, int eWt, int eBo, int eNJ, int eSrc, int eDst,
             int tLin, int tWt, int tBo, int tNJ, int tSrc, int tDst){
  __shared__ float xs[6*128];
  __shared__ float wl[8192];
  int b = blockIdx.x;
  if (b < c1){
    int e = b / pNJ, jt = b - e*pNJ;
    convT8_dev(ws, pbias + pBo, pSrc, pDst, pWt, pLin, e, jt, xs, wl);
  } else if (b < c2){
    int bl = b - c1; int e = bl / eNJ, jt = bl - e*eNJ;
    conv3up8_dev(ws, ebias + eBo, eSrc, eDst, eWt, eLin, e, jt, xs, wl);
  } else {
    int bl = b - c2; int e = bl / tNJ, jt = bl - e*tNJ;
    conv3up8_dev(ws, tbias + tBo, tSrc, tDst, tWt, tLin, e, jt, xs, wl);
  }
}

// fused epilogues: blocks 0..15 out_pos, 16..79 out_env, 80..143 out_tfu ; 256 threads
__global__ void k_outs(float* __restrict__ ws,
                       const float* __restrict__ pw, const float* __restrict__ pb,
                       const float* __restrict__ ew, const float* __restrict__ eb,
                       const float* __restrict__ tw, const float* __restrict__ tb_,
                       float* __restrict__ out){
  __shared__ float xs[16384];
  int b = blockIdx.x, tid = threadIdx.x;
  if (b < 16){
    int e = b;
    const float* in = ws + PB + e*16384;
    for (int idx=tid; idx<16384; idx+=256){
      int q = idx >> 7, c = idx & 127;
      xs[(q<<7) + ((c+q)&127)] = in[idx];
    }
    __syncthreads();
    float acc = pb[0];
    if (tid < 128){
      int j = tid;
      for (int c=0;c<128;++c){
#pragma unroll
        for (int k=0;k<3;++k){
          int q = j + k - 1;
          if (q >= 0 && q < 128) acc += xs[(q<<7) + ((c+q)&127)] * pw[c*3 + k];
        }
      }
    }
    __syncthreads();
    xs[tid] = (tid < 128) ? acc : -3.0e38f;
    __syncthreads();
    for (int s=128; s>=1; s>>=1){ if (tid < s) xs[tid] = fmaxf(xs[tid], xs[tid+s]); __syncthreads(); }
    float m = xs[0];
    __syncthreads();
    float ex = (tid < 128) ? expf(__fsub_rn(acc, m)) : 0.f;
    xs[tid] = ex;
    __syncthreads();
    for (int s=128; s>=1; s>>=1){ if (tid < s) xs[tid] += xs[tid+s]; __syncthreads(); }
    if (tid < 128) ws[PE + e*128 + tid] = __fdiv_rn(ex, xs[0]);
  } else if (b < 80){
    int idx2 = b - 16; int e = idx2 >> 2, b0 = (idx2 & 3) << 6;
    const float* in = ws + BUFA + e*32768;
    for (int idx=tid; idx<8448; idx+=256){
      int qs = idx >> 7, c = idx & 127, q = b0 - 1 + qs;
      xs[(qs<<7) + ((c+qs)&127)] = (q >= 0 && q < 256) ? in[q*128 + c] : 0.f;
    }
    __syncthreads();
    int part = tid >> 6, bb = tid & 63;
    float acc = (part == 0) ? eb[0] : 0.f;
    for (int c2=0;c2<32;++c2){
      int c = part*32 + c2;
#pragma unroll
      for (int k=0;k<3;++k){
        int qs = bb + k;
        acc += xs[(qs<<7) + ((c+qs)&127)] * ew[c*3 + k];
      }
    }
    xs[8448 + tid] = acc;
    __syncthreads();
    if (tid < 64){
      float a = xs[8448+tid] + xs[8448+64+tid] + xs[8448+128+tid] + xs[8448+192+tid];
      a = fmaxf(a, 0.f);
      out[O_ENV + e*256 + b0 + tid] = a;
      ws[ENVO + e*256 + b0 + tid] = a;
    }
  } else {
    int b2 = b - 80; int e = b2 >> 2, rg = b2 & 3;
    float* tws = xs + 8448;
    const float* in = ws + TB + e*8192;
    for (int idx=tid; idx<8448; idx+=256){
      int qs = idx >> 7, c = idx & 127, q = -1 + qs;
      xs[(qs<<7) + ((c+qs)&127)] = (q >= 0 && q < 64) ? in[q*128 + c] : 0.f;
    }
    for (int idx=tid; idx<3072; idx+=256) tws[idx] = tw[rg*3072 + idx];
    __syncthreads();
    int rl0 = tid >> 6, bb = tid & 63;
    for (int rl=rl0; rl<8; rl+=4){
      int rr = rg*8 + rl;
      float acc = tb_[rr];
      for (int c=0;c<128;++c){
#pragma unroll
        for (int k=0;k<3;++k){
          int qs = bb + k;
          acc += xs[(qs<<7) + ((c+qs)&127)] * tws[rl*384 + c*3 + k];
        }
      }
      ws[TFQ + e*2048 + rr*64 + bb] = acc;
    }
  }
}

// ================= synthesis =================

__global__ void k_envK(float* __restrict__ ws, const float* __restrict__ noise){
  int b = blockIdx.x, tid = threadIdx.x;
  if (b < 2048){
    int e = b >> 7, F = b & 127;
    int t = (F << 8) + tid;
    __shared__ float ampl[64];
    if (tid < 64){
      const float* tf = ws + TFQ + e*2048;
      float best = tf[tid]; int bi = 0;
      for (int r=1;r<32;++r){ float v = tf[r*64 + tid]; if (v > best){ best = v; bi = r; } }
      float d = __fadd_rn(0.5f, __fmul_rn((float)bi, __fdiv_rn(__fsub_rn(0.9999f, 0.5f), 31.0f)));
      ampl[tid] = (float)pow((double)d, (double)F);
    }
    __syncthreads();
    float acc = 0.f;
    for (int band=0;band<64;++band) acc += ws[SINES + band*NSAMP + t] * ampl[band];
    ((unsigned short*)(ws + KB))[e*34816 + 2048 + t] = f2bf(acc * (1.0f/(64.0f*65536.0f)));
  } else {
    int idx = (b - 2048)*256 + tid;
    int e = idx >> 15, tau = idx & 32767;
    float cf = __fsub_rn(__fdiv_rn(__fmul_rn(__fadd_rn((float)tau, 0.5f), 256.0f), 32768.0f), 0.5f);
    float c = fminf(fmaxf(cf, 0.0f), 255.0f);
    int i0 = (int)floorf(c);
    int i1 = min(i0 + 1, 255);
    float w = __fsub_rn(c, (float)i0);
    float e0 = ws[ENVO + e*256 + i0], e1 = ws[ENVO + e*256 + i1];
    float val = __fadd_rn(__fmul_rn(e0, __fsub_rn(1.0f, w)), __fmul_rn(e1, w));
    ws[ENVS + e*NSAMP + tau] = val * noise[tau];
  }
}

__global__ void k_c(float* __restrict__ ws){
  int e = blockIdx.x >> 5, seg = blockIdx.x & 31;
  int t = (seg << 10) + threadIdx.x;
  __shared__ float pl[128];
  if (threadIdx.x < 128) pl[threadIdx.x] = ws[PE + e*128 + threadIdx.x];
  __syncthreads();
  const float* ev = ws + ENVS + e*NSAMP;
  int kub = min(127, (seg << 2) + 3);
  float acc = 0.f;
  for (int k=0;k<=kub;++k){
    int u = t - (k << 8);
    if (u >= 0) acc += pl[k] * ev[u];
  }
  unsigned short hv = f2bf(acc);
  ((unsigned short*)(ws + CRB0))[e*32832 + 32768 - t] = hv;
  ((unsigned short*)(ws + CRB1))[e*32832 + 32767 - t] = hv;
}

// Toeplitz conv via MFMA 32x32x16 bf16; 16 KB LDS two-phase reduction, no atomics.
__global__ __launch_bounds__(256, 4)
void k_bigmfma(float* __restrict__ ws){
  int b = blockIdx.x;
  int w = threadIdx.x >> 6;
  int lane = threadIdx.x & 63;
  int e = b / 72;
  int r = b - e*72;
  int T2 = 0, cum = 0;
  while (cum + ((T2+2)>>1) <= r){ cum += (T2+2)>>1; T2++; }
  int qb = r - cum;
  int nseg = 2*(T2+1);
  int seg = qb*4 + w;
  int t0 = T2 << 11;
  int il = lane & 31, h = lane >> 5;
  __shared__ float red[2][2048];
  f32x16 acc0 = {}; f32x16 acc1 = {};
  if (seg < nseg){
    int u0 = -1984 + (seg << 10);
    const unsigned short* Kp  = (const unsigned short*)(ws + KB)   + e*34816 + 2048;
    const unsigned short* C0p = (const unsigned short*)(ws + CRB0) + e*32832;
    const unsigned short* C1p = (const unsigned short*)(ws + CRB1) + e*32832;
    int bB  = u0 + (il << 6) + (h << 3);
    int bA0 = 32768 - t0 + u0 - (il << 1) + (h << 3);
    int bA1 = bA0 - 2;
#pragma unroll 2
    for (int q = 0; q < 64; ++q){
      union { f32x4 v; bf16x8 s; } a0u, a1u, bu;
      a0u.v = *(const f32x4*)(C0p + bA0);
      a1u.v = *(const f32x4*)(C1p + bA1);
      bu.v  = *(const f32x4*)(Kp  + bB);
      acc0 = __builtin_amdgcn_mfma_f32_32x32x16_bf16(a0u.s, bu.s, acc0, 0, 0, 0);
      acc1 = __builtin_amdgcn_mfma_f32_32x32x16_bf16(a1u.s, bu.s, acc1, 0, 0, 0);
      bA0 += 16; bA1 += 16; bB += 16;
    }
  }
  int wl = w & 1;
  if (w < 2){
#pragma unroll
    for (int rr = 0; rr < 16; ++rr){
      int row = (rr & 3) + ((rr >> 2) << 3) + (h << 2);
      red[wl][(row << 6) + il]      = acc0[rr];
      red[wl][(row << 6) + 32 + il] = acc1[rr];
    }
  }
  __syncthreads();
  if (w >= 2){
#pragma unroll
    for (int rr = 0; rr < 16; ++rr){
      int row = (rr & 3) + ((rr >> 2) << 3) + (h << 2);
      red[wl][(row << 6) + il]      += acc0[rr];
      red[wl][(row << 6) + 32 + il] += acc1[rr];
    }
  }
  __syncthreads();
  float* slab = ws + SLAB + b*2048;
  int tid = threadIdx.x;
#pragma unroll
  for (int jj = 0; jj < 8; ++jj){
    int pos = tid*8 + jj;
    int il2 = pos >> 6, x = pos & 63;
    int idx = ((x >> 1) << 6) + ((x & 1) << 5) + il2;
    slab[pos] = red[0][idx] + red[1][idx];
  }
}

__global__ void k_final(const float* __restrict__ ws, float* __restrict__ out){
  int t = blockIdx.x*1024 + threadIdx.x;
  int T2 = t >> 11, pos = t & 2047;
  int cum = 0;
  for (int j=0;j<T2;++j) cum += (j+2)>>1;
  int nb = (T2+2)>>1;
  float s = 0.f;
  for (int e=0;e<16;++e){
    const float* sl = ws + SLAB + (e*72 + cum)*2048 + pos;
    for (int q=0;q<nb;++q) s += sl[q*2048];
  }
  out[t] = s;
}

// ================= launcher =================

extern "C" void kernel_launch(void* const* d_in, const int* in_sizes, int n_in,
                              void* d_out, int out_size, void* d_ws, size_t ws_size,
                              hipStream_t stream){
  const float* x         = (const float*)d_in[0];
  const float* noise     = (const float*)d_in[1];
  const float* fb_w      = (const float*)d_in[2];
  const float* reduce_w  = (const float*)d_in[3];
  const float* reduce_b  = (const float*)d_in[4];
  const float* dl_dw     = (const float*)d_in[5];
  const float* dl_db     = (const float*)d_in[6];
  const float* dl_pw     = (const float*)d_in[7];
  const float* dl_pb     = (const float*)d_in[8];
  const float* tt_w      = (const float*)d_in[9];
  const float* tt_b      = (const float*)d_in[10];
  const float* tr_w      = (const float*)d_in[11];
  const float* tr_b      = (const float*)d_in[12];
  const float* pos_lin_w = (const float*)d_in[13];
  const float* pos_lin_b = (const float*)d_in[14];
  const float* pos_up_w  = (const float*)d_in[15];
  const float* pos_up_b  = (const float*)d_in[16];
  const float* pos_out_w = (const float*)d_in[17];
  const float* pos_out_b = (const float*)d_in[18];
  const float* env_lin_w = (const float*)d_in[19];
  const float* env_lin_b = (const float*)d_in[20];
  const float* env_up_w  = (const float*)d_in[21];
  const float* env_up_b  = (const float*)d_in[22];
  const float* env_out_w = (const float*)d_in[23];
  const float* env_out_b = (const float*)d_in[24];
  const float* tfu_lin_w = (const float*)d_in[25];
  const float* tfu_lin_b = (const float*)d_in[26];
  const float* tfu_up_w  = (const float*)d_in[27];
  const float* tfu_up_b  = (const float*)d_in[28];
  const float* tfu_out_w = (const float*)d_in[29];
  const float* tfu_out_b = (const float*)d_in[30];
  float* out = (float*)d_out;
  float* ws  = (float*)d_ws;

  k_setup<<<3201, 1024, 0, stream>>>(x, pos_up_w, env_up_w, tfu_up_w, tt_w, tr_w,
                                     pos_lin_w, env_lin_w, tfu_lin_w,
                                     dl_dw, dl_db, dl_pw, dl_pb, ws);
  k_fbpool<<<4096, 512, 0, stream>>>(fb_w, ws);
  k_reduce<<<128, 128, 0, stream>>>(reduce_w, reduce_b, ws);
  const int DIL[5] = {1, 3, 9, 27, 1};
  int src = HA, dst = HB;
  for (int l=0;l<5;++l){
    k_dil<<<128, 128, 0, stream>>>(ws, l, DIL[l], src, dst);
    int tmp = src; src = dst; dst = tmp;
  }
  k_topk<<<1, 128, 0, stream>>>(ws, out);
  k_tt<<<32, 1024, 0, stream>>>(ws, tt_b, tr_b, out);
  k_lin3<<<48, 1024, 0, stream>>>(ws, pos_lin_b, env_lin_b, tfu_lin_b);

  // fused decoder layers, JT=8 blocks (pos convT | env conv3 | tfu conv3)
  k_layer<<<64, 128, 0, stream>>>(ws, pos_up_b, env_up_b, tfu_up_b, 16, 32,
      4,  WT_POS + 0,      0,   1, PA,   PB,
      4,  WT_ENV + 0,      0,   1, BUFA, BUFB,
      8,  WT_TFU + 0,      0,   2, TA,   TB);
  k_layer<<<128, 128, 0, stream>>>(ws, pos_up_b, env_up_b, tfu_up_b, 32, 64,
      8,  WT_POS + 65536,  128, 2, PB,   PA,
      8,  WT_ENV + 49152,  128, 2, BUFB, BUFA,
      16, WT_TFU + 49152,  128, 4, TB,   TA);
  k_layer<<<256, 128, 0, stream>>>(ws, pos_up_b, env_up_b, tfu_up_b, 64, 128,
      16, WT_POS + 131072, 256, 4, PA,   PB,
      16, WT_ENV + 98304,  256, 4, BUFA, BUFB,
      32, WT_TFU + 98304,  256, 8, TA,   TB);
  k_layer<<<256, 128, 0, stream>>>(ws, pos_up_b, env_up_b, tfu_up_b, 128, 256,
      32, WT_POS + 196608, 384, 8, PB,   PA,
      32, WT_ENV + 147456, 384, 8, BUFB, BUFA,
      1,  0,               0,   1, 0,    0);
  k_layer<<<512, 128, 0, stream>>>(ws, pos_up_b, env_up_b, tfu_up_b, 256, 512,
      64, WT_POS + 262144, 512, 16, PA,   PB,
      64, WT_ENV + 196608, 512, 16, BUFA, BUFB,
      1,  0,               0,   1, 0,    0);
  k_layer<<<512, 128, 0, stream>>>(ws, pos_up_b, env_up_b, tfu_up_b, 0, 512,
      1,  0,               0,   1, 0,    0,
      128, WT_ENV + 245760, 640, 32, BUFB, BUFA,
      1,  0,               0,   1, 0,    0);

  k_outs<<<144, 256, 0, stream>>>(ws, pos_out_w, pos_out_b, env_out_w, env_out_b,
                                  tfu_out_w, tfu_out_b, out);

  k_envK<<<4096, 256, 0, stream>>>(ws, noise);
  k_c<<<512, 1024, 0, stream>>>(ws);
  k_bigmfma<<<1152, 256, 0, stream>>>(ws);
  k_final<<<32, 1024, 0, stream>>>(ws, out);
}

// Round 9
// 669.891 us; speedup vs baseline: 1.3398x; 1.1190x over previous
//
#include <hip/hip_runtime.h>
#include <math.h>

// ---------------- constants ----------------
#define NSAMP 32768
#define NFRM  128

// ---- ws layout (float offsets) ----
static constexpr int S_OFF  = 0;
static constexpr int HP     = 32772;
static constexpr int NSQ    = HP + 16384;
static constexpr int HA     = NSQ + 16;
static constexpr int HB     = HA + 16384;
static constexpr int TFQ    = HA;                  // tf scores (overlays HA+HB, dead after topk)
static constexpr int WC     = HB + 16384;
static constexpr int WBC    = WC + 245760;
static constexpr int EWS    = WBC + 640;
static constexpr int TIMEO  = EWS + 2048;
static constexpr int TRANSO = TIMEO + 2048;
static constexpr int PE     = TRANSO + 2048;
static constexpr int RSEL   = PE + 2048;
static constexpr int ENVO   = RSEL + 1024;
static constexpr int BUFA   = ENVO + 4096;
static constexpr int BUFB   = BUFA + 524288;
static constexpr int WT     = BUFB + 524288;
static constexpr int WT_POS = WT;                  // 327680  [l][(c*4+k)*128+o]
static constexpr int WT_ENV = WT + 327680;         // 294912  [l][(c*3+k)*128+o]
static constexpr int WT_TFU = WT + 622592;         // 147456
static constexpr int WT_TT  = WT + 770048;
static constexpr int WT_TR  = WT + 786432;
static constexpr int LT_POS = WT + 802816;
static constexpr int LT_ENV = WT + 868352;
static constexpr int LT_TFU = WT + 933888;
static constexpr int SINES  = WT + 1064960;        // 2097152 (64 x 32768)
static constexpr int ENVS   = SINES + 2097152;
static constexpr int SLAB   = SINES;               // overlays SINES+ENVS
static constexpr int CRB0   = ENVS + 524288;
static constexpr int CRB1   = CRB0 + 262656;
static constexpr int KB     = CRB1 + 262656;
static constexpr int PA     = KB + 278528;
static constexpr int PB     = PA + 262144;
static constexpr int TA     = PB + 262144;
static constexpr int TB     = TA + 131072;

// ---- output offsets ----
static constexpr int O_IDX  = 32768;
static constexpr int O_ENC  = 32784;
static constexpr int O_ENV  = 34832;
static constexpr int O_TIME = 38928;
static constexpr int O_TR   = 40976;

typedef short bf16x8 __attribute__((ext_vector_type(8)));
typedef float f32x4  __attribute__((ext_vector_type(4)));
typedef float f32x16 __attribute__((ext_vector_type(16)));

static __device__ __forceinline__ unsigned short f2bf(float f){
  unsigned int u = __float_as_uint(f);
  unsigned int r = (u + 0x7FFFu + ((u >> 16) & 1u)) >> 16;
  return (unsigned short)r;
}

// ================= fused setup =================
__global__ void k_setup(const float* __restrict__ x,
                        const float* __restrict__ posw, const float* __restrict__ envw,
                        const float* __restrict__ tfuw, const float* __restrict__ ttw,
                        const float* __restrict__ trw,  const float* __restrict__ lpw,
                        const float* __restrict__ lew,  const float* __restrict__ ltw,
                        const float* __restrict__ dw,   const float* __restrict__ db,
                        const float* __restrict__ pw,   const float* __restrict__ pb2,
                        float* __restrict__ ws){
  __shared__ float ps[1024];
  int b = blockIdx.x, tid = threadIdx.x;
  if (b == 0){
    float* S = ws + S_OFF;
    float v[32];
    const float4* x4 = (const float4*)(x + tid*32);
    float s = 0.f;
#pragma unroll
    for (int i=0;i<8;++i){
      float4 q = x4[i];
      v[4*i]=q.x; v[4*i+1]=q.y; v[4*i+2]=q.z; v[4*i+3]=q.w;
      s += q.x+q.y+q.z+q.w;
    }
    ps[tid] = s; __syncthreads();
    for (int ofs=1; ofs<1024; ofs<<=1){
      float add = (tid>=ofs)? ps[tid-ofs] : 0.f;
      __syncthreads();
      ps[tid] += add;
      __syncthreads();
    }
    float run = ps[tid] - s;
#pragma unroll
    for (int i=0;i<32;++i){ S[tid*32+i] = run; run += v[i]; }
    if (tid==1023) S[32768] = ps[1023];
  } else if (b < 1041){
    int i = (b-1)*1024 + tid;
    float v;
    if (i < 327680){
      int l = i>>16, r = i & 65535, o = r & 127, ck = r>>7, c = ck>>2, k = ck&3;
      v = posw[(l<<16) + (((o<<7)+c)<<2) + k];
    } else if (i < 622592){
      int i2 = i - 327680; int l = i2/49152, r = i2 - l*49152, o = r&127, ck = r>>7;
      int c = ck/3, k = ck - 3*c;
      v = envw[l*49152 + ((o<<7)+c)*3 + k];
    } else if (i < 770048){
      int i2 = i - 622592; int l = i2/49152, r = i2 - l*49152, o = r&127, ck = r>>7;
      int c = ck/3, k = ck - 3*c;
      v = tfuw[l*49152 + ((o<<7)+c)*3 + k];
    } else if (i < 786432){
      int i2 = i - 770048; int o = i2 & 127, c = i2 >> 7;
      v = ttw[(o<<7) + c];
    } else if (i < 802816){
      int i2 = i - 786432; int o = i2 & 127, c = i2 >> 7;
      v = trw[(o<<7) + c];
    } else if (i < 868352){
      int i2 = i - 802816; int r = i2 & 511, k = i2 >> 9;
      v = lpw[(r<<7) + k];
    } else if (i < 933888){
      int i2 = i - 868352; int r = i2 & 511, k = i2 >> 9;
      v = lew[(r<<7) + k];
    } else {
      int i2 = i - 933888; int r = i2 & 1023, k = i2 >> 10;
      v = ltw[(r<<7) + k];
    }
    ws[WT + i] = v;
  } else if (b < 1121){
    int idx = (b-1041)*1024 + tid;
    if (idx < 81920){
      int l = idx >> 14, r = idx & 16383, o = r >> 7, c = r & 127;
      float a0=0.f, a1=0.f, a2=0.f;
      for (int m=0;m<128;++m){
        float p = pw[(l*128 + o)*128 + m];
        const float* dp = dw + ((l*128 + m)*128 + c)*3;
        a0 += p*dp[0]; a1 += p*dp[1]; a2 += p*dp[2];
      }
      float* W = ws + WC + ((l*128 + o)*128 + c)*3;
      W[0]=a0; W[1]=a1; W[2]=a2;
      if (c==0){
        float bb = pb2[l*128 + o];
        for (int m=0;m<128;++m) bb += pw[(l*128 + o)*128 + m] * db[l*128 + m];
        ws[WBC + l*128 + o] = bb;
      }
    }
  } else if (b < 3169){
    int b2 = b - 1121;
    int band = b2 >> 5;
    int t = ((b2 & 31) << 10) + tid;
    if (tid == 0){
      float l0 = __fdiv_rn((float)log(20.0),   (float)log(10.0));
      float l1 = __fdiv_rn((float)log(9922.5), (float)log(10.0));
      float dl = __fdiv_rn(__fsub_rn(l1, l0), 63.0f);
      float lb = __fadd_rn(l0, __fmul_rn((float)band, dl));
      float freq = (float)pow(10.0, (double)lb);
      ps[0] = __fmul_rn((float)(2.0*M_PI), freq);
    }
    __syncthreads();
    float w = ps[0];
    float tn = __fdiv_rn((float)t, 22050.0f);
    ws[SINES + band*NSAMP + t] = sinf(__fmul_rn(w, tn));
  } else {
    int i = (b-3169)*1024 + tid;
    {
      int e = i >> 11, r = i & 2047;
      ((unsigned short*)(ws + KB))[e*34816 + r] = 0;
    }
    if (i < 16*128){
      int e = i >> 7, r = i & 127;
      if (r < 64) ((unsigned short*)(ws + CRB0))[e*32832 + (r==0 ? 0 : 32768 + r)] = 0;
      else        ((unsigned short*)(ws + CRB1))[e*32832 + 32768 + (r-64)] = 0;
    }
  }
}

// ================= front-end =================

__global__ void k_fbpool(const float* __restrict__ fbw, float* __restrict__ ws){
  const float* S = ws + S_OFF;
  int c = blockIdx.x >> 5, j0 = (blockIdx.x & 31) << 2;
  int jj = threadIdx.x >> 7, kk = threadIdx.x & 127;
  int j = j0 + jj;
  int i0 = max(0, 256*j - 256), i1 = min(32767, 256*j + 255);
  float acc = 0.f;
#pragma unroll
  for (int m=0;m<4;++m){
    int k = kk + (m<<7);
    int hi = min(max(i1 + k - 255, 0), 32768);
    int lo = min(max(i0 + k - 256, 0), 32768);
    acc += fbw[c*512 + k] * (S[hi] - S[lo]);
  }
  for (int o=32;o;o>>=1) acc += __shfl_down(acc, o);
  __shared__ float red[8];
  if ((threadIdx.x & 63) == 0) red[threadIdx.x>>6] = acc;
  __syncthreads();
  if (threadIdx.x < 4)
    ws[HP + c*128 + j0 + threadIdx.x] = (red[2*threadIdx.x] + red[2*threadIdx.x+1]) * (1.0f/512.0f);
}

__global__ void k_reduce(const float* __restrict__ rw, const float* __restrict__ rb,
                         float* __restrict__ ws){
  int o = blockIdx.x, t = threadIdx.x;
  const float* hp = ws + HP;
  float sq = 0.f;
  for (int i=t;i<16384;i+=128){ float v = hp[i]; sq += v*v; }
  for (int ofs=32;ofs;ofs>>=1) sq += __shfl_down(sq, ofs);
  __shared__ float rr2[2];
  if ((t & 63) == 0) rr2[t>>6] = sq;
  __syncthreads();
  float g = sqrtf(rr2[0] + rr2[1]) + 1e-8f;
  float acc = rb[o];
  for (int c=0;c<128;++c) acc += rw[o*161 + c] * __fdiv_rn(hp[c*128 + t], g);
  float delta = __fdiv_rn(2.0f, 127.0f);
  float p = __fadd_rn(-1.0f, __fmul_rn((float)t, delta));
  acc += rw[o*161 + 128] * p;
  float sc = 1.0f;
  const float PIF = (float)M_PI;
#pragma unroll
  for (int i=0;i<16;++i){
    float f = __fmul_rn(__fmul_rn(p, sc), PIF);
    acc += rw[o*161 + 129 + 2*i] * sinf(f);
    acc += rw[o*161 + 130 + 2*i] * cosf(f);
    sc = sc * 2.0f;
  }
  ws[HA + o*128 + t] = acc;
}

__global__ void k_dil(float* __restrict__ ws, int l, int d, int inoff, int outoff){
  __shared__ float xin[16384];
  int o = blockIdx.x, t = threadIdx.x;
  const float* in = ws + inoff;
  for (int idx=t; idx<16384; idx+=128) xin[idx] = in[idx];
  __syncthreads();
  const float* Wo = ws + WC + (l*128 + o)*384;
  float acc = xin[o*128 + t] + ws[WBC + l*128 + o];
  for (int c=0;c<128;++c){
    float v0 = (t-d >= 0)  ? xin[c*128 + t - d] : 0.f;
    float v1 = xin[c*128 + t];
    float v2 = (t+d < 128) ? xin[c*128 + t + d] : 0.f;
    acc += Wo[c*3]*v0 + Wo[c*3+1]*v1 + Wo[c*3+2]*v2;
  }
  ws[outoff + o*128 + t] = acc >= 0.f ? acc : 0.2f*acc;
}

// topk + encoded: 1024 threads, LDS-staged h (swizzled), split reductions
__global__ void k_topk(float* __restrict__ ws, float* __restrict__ out){
  const float* h = ws + HB;
  int tid = threadIdx.x;
  int g = tid >> 7, t = tid & 127;
  __shared__ float xs[16384];
  __shared__ float part[1024];
  __shared__ float nt[128], nt0[128], csh[128];
  __shared__ int idxs[16];
  __shared__ float gsh[1];
  __shared__ float wv[2]; __shared__ int wi[2];
  for (int idx=tid; idx<16384; idx+=1024){
    int c = idx >> 7, tt = idx & 127;
    xs[(c<<7) + ((tt+c)&127)] = h[idx];
  }
  __syncthreads();
  // raw column sumsq (8-way split)
  float p = 0.f;
  for (int c=g; c<128; c+=8){ float v = xs[(c<<7) + ((t+c)&127)]; p += v*v; }
  part[tid] = p;
  __syncthreads();
  if (tid < 128){
    float cs = 0.f;
#pragma unroll
    for (int gg=0; gg<8; ++gg) cs += part[(gg<<7) + tid];
    csh[tid] = cs;
  }
  __syncthreads();
  if (tid < 64){
    float s = csh[tid] + csh[tid+64];
    for (int o=32;o;o>>=1) s += __shfl_down(s, o);
    if (tid == 0) gsh[0] = sqrtf(s) + 1e-8f;
  }
  __syncthreads();
  float g2 = gsh[0];
  // normalized column norms (elementwise fdiv, 8-way split)
  float p2 = 0.f;
  for (int c=g; c<128; c+=8){ float v = __fdiv_rn(xs[(c<<7) + ((t+c)&127)], g2); p2 += v*v; }
  part[tid] = p2;
  __syncthreads();
  if (tid < 128){
    float cs = 0.f;
#pragma unroll
    for (int gg=0; gg<8; ++gg) cs += part[(gg<<7) + tid];
    float ntv = sqrtf(cs);
    nt[tid] = ntv; nt0[tid] = ntv;
  }
  __syncthreads();
  for (int j=0;j<16;++j){
    if (tid < 128){
      float v = nt[t]; int bi = t;
      for (int o=32;o;o>>=1){
        float ov = __shfl_down(v, o); int oi = __shfl_down(bi, o);
        if (ov > v || (ov == v && oi < bi)){ v = ov; bi = oi; }
      }
      if ((t & 63) == 0){ wv[t>>6] = v; wi[t>>6] = bi; }
    }
    __syncthreads();
    if (tid == 0){
      int win = (wv[1] > wv[0] || (wv[1] == wv[0] && wi[1] < wi[0])) ? wi[1] : wi[0];
      idxs[j] = win; nt[win] = -3.0e38f;
    }
    __syncthreads();
  }
  if (tid < 16) out[O_IDX + tid] = (float)idxs[tid];
  for (int pos=tid; pos<2048; pos+=1024){
    int j = pos >> 7, ch = pos & 127;
    int ij = idxs[j];
    float hv = __fdiv_rn(xs[(ch<<7) + ((ij+ch)&127)], g2);
    float enc = __fdiv_rn(hv, nt0[ij] + 1e-8f);
    out[O_ENC + pos] = enc;
    ws[EWS + pos] = enc;
  }
}

__global__ void k_tt(float* __restrict__ ws, const float* __restrict__ ttb,
                     const float* __restrict__ trb, float* __restrict__ out){
  int kind = blockIdx.x >> 4, j = blockIdx.x & 15;
  int tid = threadIdx.x;
  int o = tid & 127, cg = tid >> 7;
  __shared__ float er[128];
  __shared__ float part[8][128];
  if (tid < 128) er[tid] = ws[EWS + j*128 + tid];
  __syncthreads();
  const float* Wt = ws + (kind ? WT_TR : WT_TT);
  float acc = 0.f;
  for (int c=cg; c<128; c+=8) acc += er[c] * Wt[c*128 + o];
  part[cg][o] = acc;
  __syncthreads();
  if (tid < 128){
    float a = kind ? trb[tid] : ttb[tid];
#pragma unroll
    for (int g=0; g<8; ++g) a += part[g][tid];
    out[(kind ? O_TR : O_TIME) + j*128 + tid] = a;
    ws[(kind ? TRANSO : TIMEO) + j*128 + tid] = a;
  }
}

// ================= decoder stacks =================

__global__ void k_lin3(float* __restrict__ ws, const float* __restrict__ plb,
                       const float* __restrict__ elb, const float* __restrict__ tlb){
  int b = blockIdx.x, tid = threadIdx.x;
  int stack = b >> 4, e = b & 15;
  int zoff  = (stack == 0) ? TIMEO : TRANSO;
  int ltoff = (stack == 0) ? LT_POS : (stack == 1) ? LT_ENV : LT_TFU;
  int R     = (stack == 2) ? 1024 : 512;
  int start = (stack == 2) ? 8 : 4;
  int dst   = (stack == 0) ? PA : (stack == 1) ? BUFA : TA;
  const float* lb = (stack == 0) ? plb : (stack == 1) ? elb : tlb;
  __shared__ float z[128];
  if (tid < 128) z[tid] = ws[zoff + e*128 + tid];
  __syncthreads();
  if (tid < (start<<7)){
    int s = tid >> 7, c = tid & 127;
    int r = c*start + s;
    float acc = lb[r];
    const float* lt = ws + ltoff;
    for (int k=0;k<128;++k) acc += z[k] * lt[k*R + r];
    ws[dst + e*(start<<7) + tid] = acc;   // (e, s, c) layout
  }
}

// convT (k=4, stride2), JT=8
static __device__ __forceinline__ void convT8_dev(float* __restrict__ ws, const float* __restrict__ bias,
                                                  int srcoff, int dstoff, int wtoff, int Lin,
                                                  int e, int jt, float* xs, float* wl){
  int j0 = jt*8, o = threadIdx.x;
  int s_lo = (j0 >> 1) - 1;
  const float* in = ws + srcoff + e*Lin*128;
  for (int idx=o; idx<6*128; idx+=128){
    int si = idx >> 7, c = idx & 127, s = s_lo + si;
    xs[idx] = (s >= 0 && s < Lin) ? in[s*128 + c] : 0.f;
  }
  float acc[8];
#pragma unroll
  for (int jj=0;jj<8;++jj) acc[jj] = bias[o];
  const float* wt = ws + wtoff;
#pragma unroll 1
  for (int cb=0; cb<128; cb+=16){
    __syncthreads();
    for (int idx=o; idx<8192; idx+=128) wl[idx] = wt[(cb<<9) + idx];
    __syncthreads();
#pragma unroll
    for (int cc=0; cc<16; ++cc){
      int c = cb + cc;
      float w0 = wl[((cc<<2)+0)*128 + o];
      float w1 = wl[((cc<<2)+1)*128 + o];
      float w2 = wl[((cc<<2)+2)*128 + o];
      float w3 = wl[((cc<<2)+3)*128 + o];
      float xr[6];
#pragma unroll
      for (int s=0;s<6;++s) xr[s] = xs[(s<<7) + c];
#pragma unroll
      for (int jj=0;jj<8;++jj){
        if ((jj & 1) == 0){
          acc[jj] += xr[jj>>1]*w3 + xr[(jj>>1)+1]*w1;
        } else {
          acc[jj] += xr[(jj+1)>>1]*w2 + xr[((jj+1)>>1)+1]*w0;
        }
      }
    }
  }
  float* outp = ws + dstoff + e*(Lin*2)*128;
#pragma unroll
  for (int jj=0;jj<8;++jj){
    float v = acc[jj];
    outp[(j0+jj)*128 + o] = v >= 0.f ? v : 0.2f*v;
  }
}

// conv3 on nearest-2x-upsampled input, JT=8
static __device__ __forceinline__ void conv3up8_dev(float* __restrict__ ws, const float* __restrict__ bias,
                                                    int srcoff, int dstoff, int wtoff, int Lin,
                                                    int e, int jt, float* xs, float* wl){
  int j0 = jt*8, o = threadIdx.x;
  int fs = (j0 >> 1) - 1;
  const float* in = ws + srcoff + e*Lin*128;
  for (int idx=o; idx<6*128; idx+=128){
    int si = idx >> 7, c = idx & 127, s = fs + si;
    xs[idx] = (s >= 0 && s < Lin) ? in[s*128 + c] : 0.f;
  }
  float acc[8];
#pragma unroll
  for (int jj=0;jj<8;++jj) acc[jj] = bias[o];
  const float* wt = ws + wtoff;
#pragma unroll 1
  for (int cb=0; cb<128; cb+=16){
    __syncthreads();
    for (int idx=o; idx<6144; idx+=128) wl[idx] = wt[cb*384 + idx];
    __syncthreads();
#pragma unroll
    for (int cc=0; cc<16; ++cc){
      int c = cb + cc;
      float w0 = wl[(cc*3+0)*128 + o];
      float w1 = wl[(cc*3+1)*128 + o];
      float w2 = wl[(cc*3+2)*128 + o];
      float xr[6];
#pragma unroll
      for (int s=0;s<6;++s) xr[s] = xs[(s<<7) + c];
#pragma unroll
      for (int jj=0;jj<8;++jj){
        acc[jj] += xr[((jj-1)>>1)+1]*w0
                 + xr[((jj  )>>1)+1]*w1
                 + xr[((jj+1)>>1)+1]*w2;
      }
    }
  }
  float* outp = ws + dstoff + e*(Lin*2)*128;
#pragma unroll
  for (int jj=0;jj<8;++jj){
    float v = acc[jj];
    outp[(j0+jj)*128 + o] = v >= 0.f ? v : 0.2f*v;
  }
}

__global__ __launch_bounds__(128, 4)
void k_layer(float* __restrict__ ws, const float* __restrict__ pbias,
             const float* __restrict__ ebias, const float* __restrict__ tbias,
             int c1, int c2,
             int pLin, int pWt, int pBo, int pNJ, int pSrc, int pDst,
             int eLin, int eWt, int eBo, int eNJ, int eSrc, int eDst,
             int tLin, int tWt, int tBo, int tNJ, int tSrc, int tDst){
  __shared__ float xs[6*128];
  __shared__ float wl[8192];
  int b = blockIdx.x;
  if (b < c1){
    int e = b / pNJ, jt = b - e*pNJ;
    convT8_dev(ws, pbias + pBo, pSrc, pDst, pWt, pLin, e, jt, xs, wl);
  } else if (b < c2){
    int bl = b - c1; int e = bl / eNJ, jt = bl - e*eNJ;
    conv3up8_dev(ws, ebias + eBo, eSrc, eDst, eWt, eLin, e, jt, xs, wl);
  } else {
    int bl = b - c2; int e = bl / tNJ, jt = bl - e*tNJ;
    conv3up8_dev(ws, tbias + tBo, tSrc, tDst, tWt, tLin, e, jt, xs, wl);
  }
}

// fused epilogues: blocks 0..15 out_pos, 16..79 out_env, 80..143 out_tfu ; 256 threads
__global__ void k_outs(float* __restrict__ ws,
                       const float* __restrict__ pw, const float* __restrict__ pb,
                       const float* __restrict__ ew, const float* __restrict__ eb,
                       const float* __restrict__ tw, const float* __restrict__ tb_,
                       float* __restrict__ out){
  __shared__ float xs[16384];
  int b = blockIdx.x, tid = threadIdx.x;
  if (b < 16){
    int e = b;
    const float* in = ws + PB + e*16384;
    for (int idx=tid; idx<16384; idx+=256){
      int q = idx >> 7, c = idx & 127;
      xs[(q<<7) + ((c+q)&127)] = in[idx];
    }
    __syncthreads();
    float acc = pb[0];
    if (tid < 128){
      int j = tid;
      for (int c=0;c<128;++c){
#pragma unroll
        for (int k=0;k<3;++k){
          int q = j + k - 1;
          if (q >= 0 && q < 128) acc += xs[(q<<7) + ((c+q)&127)] * pw[c*3 + k];
        }
      }
    }
    __syncthreads();
    xs[tid] = (tid < 128) ? acc : -3.0e38f;
    __syncthreads();
    for (int s=128; s>=1; s>>=1){ if (tid < s) xs[tid] = fmaxf(xs[tid], xs[tid+s]); __syncthreads(); }
    float m = xs[0];
    __syncthreads();
    float ex = (tid < 128) ? expf(__fsub_rn(acc, m)) : 0.f;
    xs[tid] = ex;
    __syncthreads();
    for (int s=128; s>=1; s>>=1){ if (tid < s) xs[tid] += xs[tid+s]; __syncthreads(); }
    if (tid < 128) ws[PE + e*128 + tid] = __fdiv_rn(ex, xs[0]);
  } else if (b < 80){
    int idx2 = b - 16; int e = idx2 >> 2, b0 = (idx2 & 3) << 6;
    const float* in = ws + BUFA + e*32768;
    for (int idx=tid; idx<8448; idx+=256){
      int qs = idx >> 7, c = idx & 127, q = b0 - 1 + qs;
      xs[(qs<<7) + ((c+qs)&127)] = (q >= 0 && q < 256) ? in[q*128 + c] : 0.f;
    }
    __syncthreads();
    int part = tid >> 6, bb = tid & 63;
    float acc = (part == 0) ? eb[0] : 0.f;
    for (int c2=0;c2<32;++c2){
      int c = part*32 + c2;
#pragma unroll
      for (int k=0;k<3;++k){
        int qs = bb + k;
        acc += xs[(qs<<7) + ((c+qs)&127)] * ew[c*3 + k];
      }
    }
    xs[8448 + tid] = acc;
    __syncthreads();
    if (tid < 64){
      float a = xs[8448+tid] + xs[8448+64+tid] + xs[8448+128+tid] + xs[8448+192+tid];
      a = fmaxf(a, 0.f);
      out[O_ENV + e*256 + b0 + tid] = a;
      ws[ENVO + e*256 + b0 + tid] = a;
    }
  } else {
    int b2 = b - 80; int e = b2 >> 2, rg = b2 & 3;
    float* tws = xs + 8448;
    const float* in = ws + TB + e*8192;
    for (int idx=tid; idx<8448; idx+=256){
      int qs = idx >> 7, c = idx & 127, q = -1 + qs;
      xs[(qs<<7) + ((c+qs)&127)] = (q >= 0 && q < 64) ? in[q*128 + c] : 0.f;
    }
    for (int idx=tid; idx<3072; idx+=256) tws[idx] = tw[rg*3072 + idx];
    __syncthreads();
    int rl0 = tid >> 6, bb = tid & 63;
    for (int rl=rl0; rl<8; rl+=4){
      int rr = rg*8 + rl;
      float acc = tb_[rr];
      for (int c=0;c<128;++c){
#pragma unroll
        for (int k=0;k<3;++k){
          int qs = bb + k;
          acc += xs[(qs<<7) + ((c+qs)&127)] * tws[rl*384 + c*3 + k];
        }
      }
      ws[TFQ + e*2048 + rr*64 + bb] = acc;
    }
  }
}

// ================= synthesis =================

__global__ void k_envK(float* __restrict__ ws, const float* __restrict__ noise){
  int b = blockIdx.x, tid = threadIdx.x;
  if (b < 2048){
    int e = b >> 7, F = b & 127;
    int t = (F << 8) + tid;
    __shared__ float ampl[64];
    if (tid < 64){
      const float* tf = ws + TFQ + e*2048;
      float best = tf[tid]; int bi = 0;
      for (int r=1;r<32;++r){ float v = tf[r*64 + tid]; if (v > best){ best = v; bi = r; } }
      float d = __fadd_rn(0.5f, __fmul_rn((float)bi, __fdiv_rn(__fsub_rn(0.9999f, 0.5f), 31.0f)));
      ampl[tid] = (float)pow((double)d, (double)F);
    }
    __syncthreads();
    float acc = 0.f;
    for (int band=0;band<64;++band) acc += ws[SINES + band*NSAMP + t] * ampl[band];
    ((unsigned short*)(ws + KB))[e*34816 + 2048 + t] = f2bf(acc * (1.0f/(64.0f*65536.0f)));
  } else {
    int idx = (b - 2048)*256 + tid;
    int e = idx >> 15, tau = idx & 32767;
    float cf = __fsub_rn(__fdiv_rn(__fmul_rn(__fadd_rn((float)tau, 0.5f), 256.0f), 32768.0f), 0.5f);
    float c = fminf(fmaxf(cf, 0.0f), 255.0f);
    int i0 = (int)floorf(c);
    int i1 = min(i0 + 1, 255);
    float w = __fsub_rn(c, (float)i0);
    float e0 = ws[ENVO + e*256 + i0], e1 = ws[ENVO + e*256 + i1];
    float val = __fadd_rn(__fmul_rn(e0, __fsub_rn(1.0f, w)), __fmul_rn(e1, w));
    ws[ENVS + e*NSAMP + tau] = val * noise[tau];
  }
}

__global__ void k_c(float* __restrict__ ws){
  int e = blockIdx.x >> 5, seg = blockIdx.x & 31;
  int t = (seg << 10) + threadIdx.x;
  __shared__ float pl[128];
  if (threadIdx.x < 128) pl[threadIdx.x] = ws[PE + e*128 + threadIdx.x];
  __syncthreads();
  const float* ev = ws + ENVS + e*NSAMP;
  int kub = min(127, (seg << 2) + 3);
  float acc = 0.f;
  for (int k=0;k<=kub;++k){
    int u = t - (k << 8);
    if (u >= 0) acc += pl[k] * ev[u];
  }
  unsigned short hv = f2bf(acc);
  ((unsigned short*)(ws + CRB0))[e*32832 + 32768 - t] = hv;
  ((unsigned short*)(ws + CRB1))[e*32832 + 32767 - t] = hv;
}

// Toeplitz conv via MFMA 32x32x16 bf16; K operand LDS-staged (padded, conflict-free),
// red buffer aliases the staging pool; no atomics.
__global__ __launch_bounds__(256, 4)
void k_bigmfma(float* __restrict__ ws){
  int b = blockIdx.x;
  int w = threadIdx.x >> 6;
  int lane = threadIdx.x & 63;
  int e = b / 72;
  int r = b - e*72;
  int T2 = 0, cum = 0;
  while (cum + ((T2+2)>>1) <= r){ cum += (T2+2)>>1; T2++; }
  int qb = r - cum;
  int nseg = 2*(T2+1);
  int seg = qb*4 + w;
  int t0 = T2 << 11;
  int il = lane & 31, h = lane >> 5;
  __shared__ __align__(16) float pool[4096];        // 16 KB: K stage, then red
  unsigned short* ks = (unsigned short*)pool;
  int wmax = nseg - 1 - qb*4; if (wmax > 3) wmax = 3;
  int U0 = -1984 + (qb << 12);
  int kcnt = wmax*1024 + 3008;
  const unsigned short* Kp = (const unsigned short*)(ws + KB) + e*34816 + 2048;
  {
    const unsigned short* src = Kp + U0;
    for (int i = threadIdx.x*8; i < kcnt; i += 2048){
      f32x4 v = *(const f32x4*)(src + i);
      *(f32x4*)(ks + i + ((i>>6)<<3)) = v;          // padded: +8 ushorts per 64
    }
  }
  __syncthreads();
  f32x16 acc0 = {}; f32x16 acc1 = {};
  if (seg < nseg){
    int u0 = -1984 + (seg << 10);
    const unsigned short* C0p = (const unsigned short*)(ws + CRB0) + e*32832;
    const unsigned short* C1p = (const unsigned short*)(ws + CRB1) + e*32832;
    int ku  = (u0 - U0) + (il << 6) + (h << 3);
    int bA0 = 32768 - t0 + u0 - (il << 1) + (h << 3);
    int bA1 = bA0 - 2;
#pragma unroll 2
    for (int q = 0; q < 64; ++q){
      union { f32x4 v; bf16x8 s; } a0u, a1u, bu;
      a0u.v = *(const f32x4*)(C0p + bA0);
      a1u.v = *(const f32x4*)(C1p + bA1);
      int pa = ku + ((ku>>6)<<3);
      bu.v  = *(const f32x4*)(ks + pa);
      acc0 = __builtin_amdgcn_mfma_f32_32x32x16_bf16(a0u.s, bu.s, acc0, 0, 0, 0);
      acc1 = __builtin_amdgcn_mfma_f32_32x32x16_bf16(a1u.s, bu.s, acc1, 0, 0, 0);
      bA0 += 16; bA1 += 16; ku += 16;
    }
  }
  __syncthreads();                                   // K stage dead; reuse as red
  float* red = pool;
  int wl = w & 1;
  if (w < 2){
#pragma unroll
    for (int rr = 0; rr < 16; ++rr){
      int row = (rr & 3) + ((rr >> 2) << 3) + (h << 2);
      red[(wl<<11) + (row << 6) + il]      = acc0[rr];
      red[(wl<<11) + (row << 6) + 32 + il] = acc1[rr];
    }
  }
  __syncthreads();
  if (w >= 2){
#pragma unroll
    for (int rr = 0; rr < 16; ++rr){
      int row = (rr & 3) + ((rr >> 2) << 3) + (h << 2);
      red[(wl<<11) + (row << 6) + il]      += acc0[rr];
      red[(wl<<11) + (row << 6) + 32 + il] += acc1[rr];
    }
  }
  __syncthreads();
  float* slab = ws + SLAB + b*2048;
  int tid = threadIdx.x;
#pragma unroll
  for (int jj = 0; jj < 8; ++jj){
    int pos = tid*8 + jj;
    int il2 = pos >> 6, x = pos & 63;
    int idx = ((x >> 1) << 6) + ((x & 1) << 5) + il2;
    slab[pos] = red[idx] + red[2048 + idx];
  }
}

__global__ void k_final(const float* __restrict__ ws, float* __restrict__ out){
  int t = blockIdx.x*1024 + threadIdx.x;
  int T2 = t >> 11, pos = t & 2047;
  int cum = 0;
  for (int j=0;j<T2;++j) cum += (j+2)>>1;
  int nb = (T2+2)>>1;
  float s = 0.f;
  for (int e=0;e<16;++e){
    const float* sl = ws + SLAB + (e*72 + cum)*2048 + pos;
    for (int q=0;q<nb;++q) s += sl[q*2048];
  }
  out[t] = s;
}

// ================= launcher =================

extern "C" void kernel_launch(void* const* d_in, const int* in_sizes, int n_in,
                              void* d_out, int out_size, void* d_ws, size_t ws_size,
                              hipStream_t stream){
  const float* x         = (const float*)d_in[0];
  const float* noise     = (const float*)d_in[1];
  const float* fb_w      = (const float*)d_in[2];
  const float* reduce_w  = (const float*)d_in[3];
  const float* reduce_b  = (const float*)d_in[4];
  const float* dl_dw     = (const float*)d_in[5];
  const float* dl_db     = (const float*)d_in[6];
  const float* dl_pw     = (const float*)d_in[7];
  const float* dl_pb     = (const float*)d_in[8];
  const float* tt_w      = (const float*)d_in[9];
  const float* tt_b      = (const float*)d_in[10];
  const float* tr_w      = (const float*)d_in[11];
  const float* tr_b      = (const float*)d_in[12];
  const float* pos_lin_w = (const float*)d_in[13];
  const float* pos_lin_b = (const float*)d_in[14];
  const float* pos_up_w  = (const float*)d_in[15];
  const float* pos_up_b  = (const float*)d_in[16];
  const float* pos_out_w = (const float*)d_in[17];
  const float* pos_out_b = (const float*)d_in[18];
  const float* env_lin_w = (const float*)d_in[19];
  const float* env_lin_b = (const float*)d_in[20];
  const float* env_out_w = (const float*)d_in[23];
  const float* env_out_b = (const float*)d_in[24];
  const float* env_up_w  = (const float*)d_in[21];
  const float* env_up_b  = (const float*)d_in[22];
  const float* tfu_lin_w = (const float*)d_in[25];
  const float* tfu_lin_b = (const float*)d_in[26];
  const float* tfu_up_w  = (const float*)d_in[27];
  const float* tfu_up_b  = (const float*)d_in[28];
  const float* tfu_out_w = (const float*)d_in[29];
  const float* tfu_out_b = (const float*)d_in[30];
  float* out = (float*)d_out;
  float* ws  = (float*)d_ws;

  k_setup<<<3201, 1024, 0, stream>>>(x, pos_up_w, env_up_w, tfu_up_w, tt_w, tr_w,
                                     pos_lin_w, env_lin_w, tfu_lin_w,
                                     dl_dw, dl_db, dl_pw, dl_pb, ws);
  k_fbpool<<<4096, 512, 0, stream>>>(fb_w, ws);
  k_reduce<<<128, 128, 0, stream>>>(reduce_w, reduce_b, ws);
  const int DIL[5] = {1, 3, 9, 27, 1};
  int src = HA, dst = HB;
  for (int l=0;l<5;++l){
    k_dil<<<128, 128, 0, stream>>>(ws, l, DIL[l], src, dst);
    int tmp = src; src = dst; dst = tmp;
  }
  k_topk<<<1, 1024, 0, stream>>>(ws, out);
  k_tt<<<32, 1024, 0, stream>>>(ws, tt_b, tr_b, out);
  k_lin3<<<48, 1024, 0, stream>>>(ws, pos_lin_b, env_lin_b, tfu_lin_b);

  // fused decoder layers, JT=8 blocks (pos convT | env conv3 | tfu conv3)
  k_layer<<<64, 128, 0, stream>>>(ws, pos_up_b, env_up_b, tfu_up_b, 16, 32,
      4,  WT_POS + 0,      0,   1, PA,   PB,
      4,  WT_ENV + 0,      0,   1, BUFA, BUFB,
      8,  WT_TFU + 0,      0,   2, TA,   TB);
  k_layer<<<128, 128, 0, stream>>>(ws, pos_up_b, env_up_b, tfu_up_b, 32, 64,
      8,  WT_POS + 65536,  128, 2, PB,   PA,
      8,  WT_ENV + 49152,  128, 2, BUFB, BUFA,
      16, WT_TFU + 49152,  128, 4, TB,   TA);
  k_layer<<<256, 128, 0, stream>>>(ws, pos_up_b, env_up_b, tfu_up_b, 64, 128,
      16, WT_POS + 131072, 256, 4, PA,   PB,
      16, WT_ENV + 98304,  256, 4, BUFA, BUFB,
      32, WT_TFU + 98304,  256, 8, TA,   TB);
  k_layer<<<256, 128, 0, stream>>>(ws, pos_up_b, env_up_b, tfu_up_b, 128, 256,
      32, WT_POS + 196608, 384, 8, PB,   PA,
      32, WT_ENV + 147456, 384, 8, BUFB, BUFA,
      1,  0,               0,   1, 0,    0);
  k_layer<<<512, 128, 0, stream>>>(ws, pos_up_b, env_up_b, tfu_up_b, 256, 512,
      64, WT_POS + 262144, 512, 16, PA,   PB,
      64, WT_ENV + 196608, 512, 16, BUFA, BUFB,
      1,  0,               0,   1, 0,    0);
  k_layer<<<512, 128, 0, stream>>>(ws, pos_up_b, env_up_b, tfu_up_b, 0, 512,
      1,  0,               0,   1, 0,    0,
      128, WT_ENV + 245760, 640, 32, BUFB, BUFA,
      1,  0,               0,   1, 0,    0);

  k_outs<<<144, 256, 0, stream>>>(ws, pos_out_w, pos_out_b, env_out_w, env_out_b,
                                  tfu_out_w, tfu_out_b, out);

  k_envK<<<4096, 256, 0, stream>>>(ws, noise);
  k_c<<<512, 1024, 0, stream>>>(ws);
  k_bigmfma<<<1152, 256, 0, stream>>>(ws);
  k_final<<<32, 1024, 0, stream>>>(ws, out);
}

// Round 10
// 616.611 us; speedup vs baseline: 1.4556x; 1.0864x over previous
//
#include <hip/hip_runtime.h>
#include <math.h>

// ---------------- constants ----------------
#define NSAMP 32768
#define NFRM  128

// ---- ws layout (float offsets) ----
static constexpr int S_OFF  = 0;
static constexpr int HP     = 32772;
static constexpr int NSQ    = HP + 16384;
static constexpr int HA     = NSQ + 16;
static constexpr int HB     = HA + 16384;
static constexpr int TFQ    = HA;                  // tf scores (overlays HA+HB, dead after topk)
static constexpr int WC     = HB + 16384;
static constexpr int WBC    = WC + 245760;
static constexpr int EWS    = WBC + 640;
static constexpr int TIMEO  = EWS + 2048;
static constexpr int TRANSO = TIMEO + 2048;
static constexpr int PE     = TRANSO + 2048;
static constexpr int RSEL   = PE + 2048;
static constexpr int ENVO   = RSEL + 1024;
static constexpr int BUFA   = ENVO + 4096;
static constexpr int BUFB   = BUFA + 524288;
static constexpr int WT     = BUFB + 524288;
static constexpr int WT_POS = WT;                  // 327680  [l][(c*4+k)*128+o]
static constexpr int WT_ENV = WT + 327680;         // 294912  [l][(c*3+k)*128+o]
static constexpr int WT_TFU = WT + 622592;         // 147456
static constexpr int WT_TT  = WT + 770048;
static constexpr int WT_TR  = WT + 786432;
static constexpr int LT_POS = WT + 802816;         // 65536  [s][k][c]  (s<4)
static constexpr int LT_ENV = WT + 868352;         // 65536  [s][k][c]  (s<4)
static constexpr int LT_TFU = WT + 933888;         // 131072 [s][k][c]  (s<8)
static constexpr int SINES  = WT + 1064960;        // 2097152 (64 x 32768)
static constexpr int ENVS   = SINES + 2097152;
static constexpr int SLAB   = SINES;               // overlays SINES+ENVS
static constexpr int CRB0   = ENVS + 524288;
static constexpr int CRB1   = CRB0 + 262656;
static constexpr int KB     = CRB1 + 262656;
static constexpr int PA     = KB + 278528;
static constexpr int PB     = PA + 262144;
static constexpr int TA     = PB + 262144;
static constexpr int TB     = TA + 131072;

// ---- output offsets ----
static constexpr int O_IDX  = 32768;
static constexpr int O_ENC  = 32784;
static constexpr int O_ENV  = 34832;
static constexpr int O_TIME = 38928;
static constexpr int O_TR   = 40976;

typedef short bf16x8 __attribute__((ext_vector_type(8)));
typedef float f32x4  __attribute__((ext_vector_type(4)));
typedef float f32x16 __attribute__((ext_vector_type(16)));

static __device__ __forceinline__ unsigned short f2bf(float f){
  unsigned int u = __float_as_uint(f);
  unsigned int r = (u + 0x7FFFu + ((u >> 16) & 1u)) >> 16;
  return (unsigned short)r;
}

// ================= fused setup =================
__global__ void k_setup(const float* __restrict__ x,
                        const float* __restrict__ posw, const float* __restrict__ envw,
                        const float* __restrict__ tfuw, const float* __restrict__ ttw,
                        const float* __restrict__ trw,  const float* __restrict__ lpw,
                        const float* __restrict__ lew,  const float* __restrict__ ltw,
                        const float* __restrict__ dw,   const float* __restrict__ db,
                        const float* __restrict__ pw,   const float* __restrict__ pb2,
                        float* __restrict__ ws){
  __shared__ float ps[1024];
  int b = blockIdx.x, tid = threadIdx.x;
  if (b == 0){
    float* S = ws + S_OFF;
    float v[32];
    const float4* x4 = (const float4*)(x + tid*32);
    float s = 0.f;
#pragma unroll
    for (int i=0;i<8;++i){
      float4 q = x4[i];
      v[4*i]=q.x; v[4*i+1]=q.y; v[4*i+2]=q.z; v[4*i+3]=q.w;
      s += q.x+q.y+q.z+q.w;
    }
    ps[tid] = s; __syncthreads();
    for (int ofs=1; ofs<1024; ofs<<=1){
      float add = (tid>=ofs)? ps[tid-ofs] : 0.f;
      __syncthreads();
      ps[tid] += add;
      __syncthreads();
    }
    float run = ps[tid] - s;
#pragma unroll
    for (int i=0;i<32;++i){ S[tid*32+i] = run; run += v[i]; }
    if (tid==1023) S[32768] = ps[1023];
  } else if (b < 1041){
    int i = (b-1)*1024 + tid;
    float v;
    if (i < 327680){
      int l = i>>16, r = i & 65535, o = r & 127, ck = r>>7, c = ck>>2, k = ck&3;
      v = posw[(l<<16) + (((o<<7)+c)<<2) + k];
    } else if (i < 622592){
      int i2 = i - 327680; int l = i2/49152, r = i2 - l*49152, o = r&127, ck = r>>7;
      int c = ck/3, k = ck - 3*c;
      v = envw[l*49152 + ((o<<7)+c)*3 + k];
    } else if (i < 770048){
      int i2 = i - 622592; int l = i2/49152, r = i2 - l*49152, o = r&127, ck = r>>7;
      int c = ck/3, k = ck - 3*c;
      v = tfuw[l*49152 + ((o<<7)+c)*3 + k];
    } else if (i < 786432){
      int i2 = i - 770048; int o = i2 & 127, c = i2 >> 7;
      v = ttw[(o<<7) + c];
    } else if (i < 802816){
      int i2 = i - 786432; int o = i2 & 127, c = i2 >> 7;
      v = trw[(o<<7) + c];
    } else if (i < 868352){
      // pos_lin -> [s][k][c], r = c*4+s
      int i2 = i - 802816; int s = i2 >> 14, k = (i2 >> 7) & 127, c = i2 & 127;
      v = lpw[(((c<<2)+s)<<7) + k];
    } else if (i < 933888){
      // env_lin -> [s][k][c]
      int i2 = i - 868352; int s = i2 >> 14, k = (i2 >> 7) & 127, c = i2 & 127;
      v = lew[(((c<<2)+s)<<7) + k];
    } else {
      // tfu_lin -> [s][k][c], r = c*8+s
      int i2 = i - 933888; int s = i2 >> 14, k = (i2 >> 7) & 127, c = i2 & 127;
      v = ltw[(((c<<3)+s)<<7) + k];
    }
    ws[WT + i] = v;
  } else if (b < 1121){
    int idx = (b-1041)*1024 + tid;
    if (idx < 81920){
      int l = idx >> 14, r = idx & 16383, o = r >> 7, c = r & 127;
      float a0=0.f, a1=0.f, a2=0.f;
      for (int m=0;m<128;++m){
        float p = pw[(l*128 + o)*128 + m];
        const float* dp = dw + ((l*128 + m)*128 + c)*3;
        a0 += p*dp[0]; a1 += p*dp[1]; a2 += p*dp[2];
      }
      float* W = ws + WC + ((l*128 + o)*128 + c)*3;
      W[0]=a0; W[1]=a1; W[2]=a2;
      if (c==0){
        float bb = pb2[l*128 + o];
        for (int m=0;m<128;++m) bb += pw[(l*128 + o)*128 + m] * db[l*128 + m];
        ws[WBC + l*128 + o] = bb;
      }
    }
  } else if (b < 3169){
    int b2 = b - 1121;
    int band = b2 >> 5;
    int t = ((b2 & 31) << 10) + tid;
    if (tid == 0){
      float l0 = __fdiv_rn((float)log(20.0),   (float)log(10.0));
      float l1 = __fdiv_rn((float)log(9922.5), (float)log(10.0));
      float dl = __fdiv_rn(__fsub_rn(l1, l0), 63.0f);
      float lb = __fadd_rn(l0, __fmul_rn((float)band, dl));
      float freq = (float)pow(10.0, (double)lb);
      ps[0] = __fmul_rn((float)(2.0*M_PI), freq);
    }
    __syncthreads();
    float w = ps[0];
    float tn = __fdiv_rn((float)t, 22050.0f);
    ws[SINES + band*NSAMP + t] = sinf(__fmul_rn(w, tn));
  } else {
    int i = (b-3169)*1024 + tid;
    {
      int e = i >> 11, r = i & 2047;
      ((unsigned short*)(ws + KB))[e*34816 + r] = 0;
    }
    if (i < 16*128){
      int e = i >> 7, r = i & 127;
      if (r < 64) ((unsigned short*)(ws + CRB0))[e*32832 + (r==0 ? 0 : 32768 + r)] = 0;
      else        ((unsigned short*)(ws + CRB1))[e*32832 + 32768 + (r-64)] = 0;
    }
  }
}

// ================= front-end =================

__global__ void k_fbpool(const float* __restrict__ fbw, float* __restrict__ ws){
  const float* S = ws + S_OFF;
  int c = blockIdx.x >> 5, j0 = (blockIdx.x & 31) << 2;
  int jj = threadIdx.x >> 7, kk = threadIdx.x & 127;
  int j = j0 + jj;
  int i0 = max(0, 256*j - 256), i1 = min(32767, 256*j + 255);
  float acc = 0.f;
#pragma unroll
  for (int m=0;m<4;++m){
    int k = kk + (m<<7);
    int hi = min(max(i1 + k - 255, 0), 32768);
    int lo = min(max(i0 + k - 256, 0), 32768);
    acc += fbw[c*512 + k] * (S[hi] - S[lo]);
  }
  for (int o=32;o;o>>=1) acc += __shfl_down(acc, o);
  __shared__ float red[8];
  if ((threadIdx.x & 63) == 0) red[threadIdx.x>>6] = acc;
  __syncthreads();
  if (threadIdx.x < 4)
    ws[HP + c*128 + j0 + threadIdx.x] = (red[2*threadIdx.x] + red[2*threadIdx.x+1]) * (1.0f/512.0f);
}

__global__ void k_reduce(const float* __restrict__ rw, const float* __restrict__ rb,
                         float* __restrict__ ws){
  int o = blockIdx.x, t = threadIdx.x;
  const float* hp = ws + HP;
  float sq = 0.f;
  for (int i=t;i<16384;i+=128){ float v = hp[i]; sq += v*v; }
  for (int ofs=32;ofs;ofs>>=1) sq += __shfl_down(sq, ofs);
  __shared__ float rr2[2];
  if ((t & 63) == 0) rr2[t>>6] = sq;
  __syncthreads();
  float g = sqrtf(rr2[0] + rr2[1]) + 1e-8f;
  float acc = rb[o];
  for (int c=0;c<128;++c) acc += rw[o*161 + c] * __fdiv_rn(hp[c*128 + t], g);
  float delta = __fdiv_rn(2.0f, 127.0f);
  float p = __fadd_rn(-1.0f, __fmul_rn((float)t, delta));
  acc += rw[o*161 + 128] * p;
  float sc = 1.0f;
  const float PIF = (float)M_PI;
#pragma unroll
  for (int i=0;i<16;++i){
    float f = __fmul_rn(__fmul_rn(p, sc), PIF);
    acc += rw[o*161 + 129 + 2*i] * sinf(f);
    acc += rw[o*161 + 130 + 2*i] * cosf(f);
    sc = sc * 2.0f;
  }
  ws[HA + o*128 + t] = acc;
}

__global__ void k_dil(float* __restrict__ ws, int l, int d, int inoff, int outoff){
  __shared__ float xin[16384];
  int o = blockIdx.x, t = threadIdx.x;
  const float* in = ws + inoff;
  for (int idx=t; idx<16384; idx+=128) xin[idx] = in[idx];
  __syncthreads();
  const float* Wo = ws + WC + (l*128 + o)*384;
  float acc = xin[o*128 + t] + ws[WBC + l*128 + o];
  for (int c=0;c<128;++c){
    float v0 = (t-d >= 0)  ? xin[c*128 + t - d] : 0.f;
    float v1 = xin[c*128 + t];
    float v2 = (t+d < 128) ? xin[c*128 + t + d] : 0.f;
    acc += Wo[c*3]*v0 + Wo[c*3+1]*v1 + Wo[c*3+2]*v2;
  }
  ws[outoff + o*128 + t] = acc >= 0.f ? acc : 0.2f*acc;
}

// topk + encoded: 1024 threads, LDS-staged h (swizzled), split reductions
__global__ void k_topk(float* __restrict__ ws, float* __restrict__ out){
  const float* h = ws + HB;
  int tid = threadIdx.x;
  int g = tid >> 7, t = tid & 127;
  __shared__ float xs[16384];
  __shared__ float part[1024];
  __shared__ float nt[128], nt0[128], csh[128];
  __shared__ int idxs[16];
  __shared__ float gsh[1];
  __shared__ float wv[2]; __shared__ int wi[2];
  for (int idx=tid; idx<16384; idx+=1024){
    int c = idx >> 7, tt = idx & 127;
    xs[(c<<7) + ((tt+c)&127)] = h[idx];
  }
  __syncthreads();
  float p = 0.f;
  for (int c=g; c<128; c+=8){ float v = xs[(c<<7) + ((t+c)&127)]; p += v*v; }
  part[tid] = p;
  __syncthreads();
  if (tid < 128){
    float cs = 0.f;
#pragma unroll
    for (int gg=0; gg<8; ++gg) cs += part[(gg<<7) + tid];
    csh[tid] = cs;
  }
  __syncthreads();
  if (tid < 64){
    float s = csh[tid] + csh[tid+64];
    for (int o=32;o;o>>=1) s += __shfl_down(s, o);
    if (tid == 0) gsh[0] = sqrtf(s) + 1e-8f;
  }
  __syncthreads();
  float g2 = gsh[0];
  float p2 = 0.f;
  for (int c=g; c<128; c+=8){ float v = __fdiv_rn(xs[(c<<7) + ((t+c)&127)], g2); p2 += v*v; }
  part[tid] = p2;
  __syncthreads();
  if (tid < 128){
    float cs = 0.f;
#pragma unroll
    for (int gg=0; gg<8; ++gg) cs += part[(gg<<7) + tid];
    float ntv = sqrtf(cs);
    nt[tid] = ntv; nt0[tid] = ntv;
  }
  __syncthreads();
  for (int j=0;j<16;++j){
    if (tid < 128){
      float v = nt[t]; int bi = t;
      for (int o=32;o;o>>=1){
        float ov = __shfl_down(v, o); int oi = __shfl_down(bi, o);
        if (ov > v || (ov == v && oi < bi)){ v = ov; bi = oi; }
      }
      if ((t & 63) == 0){ wv[t>>6] = v; wi[t>>6] = bi; }
    }
    __syncthreads();
    if (tid == 0){
      int win = (wv[1] > wv[0] || (wv[1] == wv[0] && wi[1] < wi[0])) ? wi[1] : wi[0];
      idxs[j] = win; nt[win] = -3.0e38f;
    }
    __syncthreads();
  }
  if (tid < 16) out[O_IDX + tid] = (float)idxs[tid];
  for (int pos=tid; pos<2048; pos+=1024){
    int j = pos >> 7, ch = pos & 127;
    int ij = idxs[j];
    float hv = __fdiv_rn(xs[(ch<<7) + ((ij+ch)&127)], g2);
    float enc = __fdiv_rn(hv, nt0[ij] + 1e-8f);
    out[O_ENC + pos] = enc;
    ws[EWS + pos] = enc;
  }
}

__global__ void k_tt(float* __restrict__ ws, const float* __restrict__ ttb,
                     const float* __restrict__ trb, float* __restrict__ out){
  int kind = blockIdx.x >> 4, j = blockIdx.x & 15;
  int tid = threadIdx.x;
  int o = tid & 127, cg = tid >> 7;
  __shared__ float er[128];
  __shared__ float part[8][128];
  if (tid < 128) er[tid] = ws[EWS + j*128 + tid];
  __syncthreads();
  const float* Wt = ws + (kind ? WT_TR : WT_TT);
  float acc = 0.f;
  for (int c=cg; c<128; c+=8) acc += er[c] * Wt[c*128 + o];
  part[cg][o] = acc;
  __syncthreads();
  if (tid < 128){
    float a = kind ? trb[tid] : ttb[tid];
#pragma unroll
    for (int g=0; g<8; ++g) a += part[g][tid];
    out[(kind ? O_TR : O_TIME) + j*128 + tid] = a;
    ws[(kind ? TRANSO : TIMEO) + j*128 + tid] = a;
  }
}

// ================= decoder stacks =================

// fused linears: block = (stack, e, s); 1024 threads = 8 kg x 128 c; LT is [s][k][c]
__global__ void k_lin3(float* __restrict__ ws, const float* __restrict__ plb,
                       const float* __restrict__ elb, const float* __restrict__ tlb){
  int b = blockIdx.x, tid = threadIdx.x;
  int kg = tid >> 7, c = tid & 127;
  int e, s, start, ltoff, zoff, dst;
  const float* lb;
  if (b < 64){
    e = b >> 2; s = b & 3; start = 4; ltoff = LT_POS; zoff = TIMEO; dst = PA; lb = plb;
  } else if (b < 128){
    int b2 = b - 64; e = b2 >> 2; s = b2 & 3; start = 4; ltoff = LT_ENV; zoff = TRANSO; dst = BUFA; lb = elb;
  } else {
    int b2 = b - 128; e = b2 >> 3; s = b2 & 7; start = 8; ltoff = LT_TFU; zoff = TRANSO; dst = TA; lb = tlb;
  }
  __shared__ float z[128];
  __shared__ float part[8][128];
  if (tid < 128) z[tid] = ws[zoff + e*128 + tid];
  __syncthreads();
  const float* lt = ws + ltoff + (s << 14);
  float acc = 0.f;
  for (int k=kg; k<128; k+=8) acc += z[k] * lt[(k<<7) + c];
  part[kg][c] = acc;
  __syncthreads();
  if (tid < 128){
    float a = lb[tid*start + s];
#pragma unroll
    for (int g=0; g<8; ++g) a += part[g][tid];
    ws[dst + e*(start<<7) + (s<<7) + tid] = a;   // (e, s, c) layout
  }
}

// convT (k=4, stride2), JT=8
static __device__ __forceinline__ void convT8_dev(float* __restrict__ ws, const float* __restrict__ bias,
                                                  int srcoff, int dstoff, int wtoff, int Lin,
                                                  int e, int jt, float* xs, float* wl){
  int j0 = jt*8, o = threadIdx.x;
  int s_lo = (j0 >> 1) - 1;
  const float* in = ws + srcoff + e*Lin*128;
  for (int idx=o; idx<6*128; idx+=128){
    int si = idx >> 7, c = idx & 127, s = s_lo + si;
    xs[idx] = (s >= 0 && s < Lin) ? in[s*128 + c] : 0.f;
  }
  float acc[8];
#pragma unroll
  for (int jj=0;jj<8;++jj) acc[jj] = bias[o];
  const float* wt = ws + wtoff;
#pragma unroll 1
  for (int cb=0; cb<128; cb+=16){
    __syncthreads();
    for (int idx=o; idx<8192; idx+=128) wl[idx] = wt[(cb<<9) + idx];
    __syncthreads();
#pragma unroll
    for (int cc=0; cc<16; ++cc){
      int c = cb + cc;
      float w0 = wl[((cc<<2)+0)*128 + o];
      float w1 = wl[((cc<<2)+1)*128 + o];
      float w2 = wl[((cc<<2)+2)*128 + o];
      float w3 = wl[((cc<<2)+3)*128 + o];
      float xr[6];
#pragma unroll
      for (int s=0;s<6;++s) xr[s] = xs[(s<<7) + c];
#pragma unroll
      for (int jj=0;jj<8;++jj){
        if ((jj & 1) == 0){
          acc[jj] += xr[jj>>1]*w3 + xr[(jj>>1)+1]*w1;
        } else {
          acc[jj] += xr[(jj+1)>>1]*w2 + xr[((jj+1)>>1)+1]*w0;
        }
      }
    }
  }
  float* outp = ws + dstoff + e*(Lin*2)*128;
#pragma unroll
  for (int jj=0;jj<8;++jj){
    float v = acc[jj];
    outp[(j0+jj)*128 + o] = v >= 0.f ? v : 0.2f*v;
  }
}

// conv3 on nearest-2x-upsampled input, JT=8
static __device__ __forceinline__ void conv3up8_dev(float* __restrict__ ws, const float* __restrict__ bias,
                                                    int srcoff, int dstoff, int wtoff, int Lin,
                                                    int e, int jt, float* xs, float* wl){
  int j0 = jt*8, o = threadIdx.x;
  int fs = (j0 >> 1) - 1;
  const float* in = ws + srcoff + e*Lin*128;
  for (int idx=o; idx<6*128; idx+=128){
    int si = idx >> 7, c = idx & 127, s = fs + si;
    xs[idx] = (s >= 0 && s < Lin) ? in[s*128 + c] : 0.f;
  }
  float acc[8];
#pragma unroll
  for (int jj=0;jj<8;++jj) acc[jj] = bias[o];
  const float* wt = ws + wtoff;
#pragma unroll 1
  for (int cb=0; cb<128; cb+=16){
    __syncthreads();
    for (int idx=o; idx<6144; idx+=128) wl[idx] = wt[cb*384 + idx];
    __syncthreads();
#pragma unroll
    for (int cc=0; cc<16; ++cc){
      int c = cb + cc;
      float w0 = wl[(cc*3+0)*128 + o];
      float w1 = wl[(cc*3+1)*128 + o];
      float w2 = wl[(cc*3+2)*128 + o];
      float xr[6];
#pragma unroll
      for (int s=0;s<6;++s) xr[s] = xs[(s<<7) + c];
#pragma unroll
      for (int jj=0;jj<8;++jj){
        acc[jj] += xr[((jj-1)>>1)+1]*w0
                 + xr[((jj  )>>1)+1]*w1
                 + xr[((jj+1)>>1)+1]*w2;
      }
    }
  }
  float* outp = ws + dstoff + e*(Lin*2)*128;
#pragma unroll
  for (int jj=0;jj<8;++jj){
    float v = acc[jj];
    outp[(j0+jj)*128 + o] = v >= 0.f ? v : 0.2f*v;
  }
}

__global__ __launch_bounds__(128, 4)
void k_layer(float* __restrict__ ws, const float* __restrict__ pbias,
             const float* __restrict__ ebias, const float* __restrict__ tbias,
             int c1, int c2,
             int pLin, int pWt, int pBo, int pNJ, int pSrc, int pDst,
             int eLin, int eWt, int eBo, int eNJ, int eSrc, int eDst,
             int tLin, int tWt, int tBo, int tNJ, int tSrc, int tDst){
  __shared__ float xs[6*128];
  __shared__ float wl[8192];
  int b = blockIdx.x;
  if (b < c1){
    int e = b / pNJ, jt = b - e*pNJ;
    convT8_dev(ws, pbias + pBo, pSrc, pDst, pWt, pLin, e, jt, xs, wl);
  } else if (b < c2){
    int bl = b - c1; int e = bl / eNJ, jt = bl - e*eNJ;
    conv3up8_dev(ws, ebias + eBo, eSrc, eDst, eWt, eLin, e, jt, xs, wl);
  } else {
    int bl = b - c2; int e = bl / tNJ, jt = bl - e*tNJ;
    conv3up8_dev(ws, tbias + tBo, tSrc, tDst, tWt, tLin, e, jt, xs, wl);
  }
}

// fused epilogues: blocks 0..15 out_pos, 16..79 out_env, 80..143 out_tfu ; 256 threads
__global__ void k_outs(float* __restrict__ ws,
                       const float* __restrict__ pw, const float* __restrict__ pb,
                       const float* __restrict__ ew, const float* __restrict__ eb,
                       const float* __restrict__ tw, const float* __restrict__ tb_,
                       float* __restrict__ out){
  __shared__ float xs[16384];
  int b = blockIdx.x, tid = threadIdx.x;
  if (b < 16){
    int e = b;
    const float* in = ws + PB + e*16384;
    for (int idx=tid; idx<16384; idx+=256){
      int q = idx >> 7, c = idx & 127;
      xs[(q<<7) + ((c+q)&127)] = in[idx];
    }
    __syncthreads();
    float acc = pb[0];
    if (tid < 128){
      int j = tid;
      for (int c=0;c<128;++c){
#pragma unroll
        for (int k=0;k<3;++k){
          int q = j + k - 1;
          if (q >= 0 && q < 128) acc += xs[(q<<7) + ((c+q)&127)] * pw[c*3 + k];
        }
      }
    }
    __syncthreads();
    xs[tid] = (tid < 128) ? acc : -3.0e38f;
    __syncthreads();
    for (int s=128; s>=1; s>>=1){ if (tid < s) xs[tid] = fmaxf(xs[tid], xs[tid+s]); __syncthreads(); }
    float m = xs[0];
    __syncthreads();
    float ex = (tid < 128) ? expf(__fsub_rn(acc, m)) : 0.f;
    xs[tid] = ex;
    __syncthreads();
    for (int s=128; s>=1; s>>=1){ if (tid < s) xs[tid] += xs[tid+s]; __syncthreads(); }
    if (tid < 128) ws[PE + e*128 + tid] = __fdiv_rn(ex, xs[0]);
  } else if (b < 80){
    int idx2 = b - 16; int e = idx2 >> 2, b0 = (idx2 & 3) << 6;
    const float* in = ws + BUFA + e*32768;
    for (int idx=tid; idx<8448; idx+=256){
      int qs = idx >> 7, c = idx & 127, q = b0 - 1 + qs;
      xs[(qs<<7) + ((c+qs)&127)] = (q >= 0 && q < 256) ? in[q*128 + c] : 0.f;
    }
    __syncthreads();
    int part = tid >> 6, bb = tid & 63;
    float acc = (part == 0) ? eb[0] : 0.f;
    for (int c2=0;c2<32;++c2){
      int c = part*32 + c2;
#pragma unroll
      for (int k=0;k<3;++k){
        int qs = bb + k;
        acc += xs[(qs<<7) + ((c+qs)&127)] * ew[c*3 + k];
      }
    }
    xs[8448 + tid] = acc;
    __syncthreads();
    if (tid < 64){
      float a = xs[8448+tid] + xs[8448+64+tid] + xs[8448+128+tid] + xs[8448+192+tid];
      a = fmaxf(a, 0.f);
      out[O_ENV + e*256 + b0 + tid] = a;
      ws[ENVO + e*256 + b0 + tid] = a;
    }
  } else {
    int b2 = b - 80; int e = b2 >> 2, rg = b2 & 3;
    float* tws = xs + 8448;
    const float* in = ws + TB + e*8192;
    for (int idx=tid; idx<8448; idx+=256){
      int qs = idx >> 7, c = idx & 127, q = -1 + qs;
      xs[(qs<<7) + ((c+qs)&127)] = (q >= 0 && q < 64) ? in[q*128 + c] : 0.f;
    }
    for (int idx=tid; idx<3072; idx+=256) tws[idx] = tw[rg*3072 + idx];
    __syncthreads();
    int rl0 = tid >> 6, bb = tid & 63;
    for (int rl=rl0; rl<8; rl+=4){
      int rr = rg*8 + rl;
      float acc = tb_[rr];
      for (int c=0;c<128;++c){
#pragma unroll
        for (int k=0;k<3;++k){
          int qs = bb + k;
          acc += xs[(qs<<7) + ((c+qs)&127)] * tws[rl*384 + c*3 + k];
        }
      }
      ws[TFQ + e*2048 + rr*64 + bb] = acc;
    }
  }
}

// ================= synthesis =================

__global__ void k_envK(float* __restrict__ ws, const float* __restrict__ noise){
  int b = blockIdx.x, tid = threadIdx.x;
  if (b < 2048){
    int e = b >> 7, F = b & 127;
    int t = (F << 8) + tid;
    __shared__ float ampl[64];
    if (tid < 64){
      const float* tf = ws + TFQ + e*2048;
      float best = tf[tid]; int bi = 0;
      for (int r=1;r<32;++r){ float v = tf[r*64 + tid]; if (v > best){ best = v; bi = r; } }
      float d = __fadd_rn(0.5f, __fmul_rn((float)bi, __fdiv_rn(__fsub_rn(0.9999f, 0.5f), 31.0f)));
      ampl[tid] = (float)pow((double)d, (double)F);
    }
    __syncthreads();
    float acc = 0.f;
    for (int band=0;band<64;++band) acc += ws[SINES + band*NSAMP + t] * ampl[band];
    ((unsigned short*)(ws + KB))[e*34816 + 2048 + t] = f2bf(acc * (1.0f/(64.0f*65536.0f)));
  } else {
    int idx = (b - 2048)*256 + tid;
    int e = idx >> 15, tau = idx & 32767;
    float cf = __fsub_rn(__fdiv_rn(__fmul_rn(__fadd_rn((float)tau, 0.5f), 256.0f), 32768.0f), 0.5f);
    float c = fminf(fmaxf(cf, 0.0f), 255.0f);
    int i0 = (int)floorf(c);
    int i1 = min(i0 + 1, 255);
    float w = __fsub_rn(c, (float)i0);
    float e0 = ws[ENVO + e*256 + i0], e1 = ws[ENVO + e*256 + i1];
    float val = __fadd_rn(__fmul_rn(e0, __fsub_rn(1.0f, w)), __fmul_rn(e1, w));
    ws[ENVS + e*NSAMP + tau] = val * noise[tau];
  }
}

__global__ void k_c(float* __restrict__ ws){
  int e = blockIdx.x >> 5, seg = blockIdx.x & 31;
  int t = (seg << 10) + threadIdx.x;
  __shared__ float pl[128];
  if (threadIdx.x < 128) pl[threadIdx.x] = ws[PE + e*128 + threadIdx.x];
  __syncthreads();
  const float* ev = ws + ENVS + e*NSAMP;
  int kub = min(127, (seg << 2) + 3);
  float acc = 0.f;
  for (int k=0;k<=kub;++k){
    int u = t - (k << 8);
    if (u >= 0) acc += pl[k] * ev[u];
  }
  unsigned short hv = f2bf(acc);
  ((unsigned short*)(ws + CRB0))[e*32832 + 32768 - t] = hv;
  ((unsigned short*)(ws + CRB1))[e*32832 + 32767 - t] = hv;
}

// Toeplitz conv via MFMA 32x32x16 bf16; K operand LDS-staged (padded, conflict-free),
// red buffer aliases the staging pool; no atomics.
__global__ __launch_bounds__(256, 4)
void k_bigmfma(float* __restrict__ ws){
  int b = blockIdx.x;
  int w = threadIdx.x >> 6;
  int lane = threadIdx.x & 63;
  int e = b / 72;
  int r = b - e*72;
  int T2 = 0, cum = 0;
  while (cum + ((T2+2)>>1) <= r){ cum += (T2+2)>>1; T2++; }
  int qb = r - cum;
  int nseg = 2*(T2+1);
  int seg = qb*4 + w;
  int t0 = T2 << 11;
  int il = lane & 31, h = lane >> 5;
  __shared__ __align__(16) float pool[4096];        // 16 KB: K stage, then red
  unsigned short* ks = (unsigned short*)pool;
  int wmax = nseg - 1 - qb*4; if (wmax > 3) wmax = 3;
  int U0 = -1984 + (qb << 12);
  int kcnt = wmax*1024 + 3008;
  const unsigned short* Kp = (const unsigned short*)(ws + KB) + e*34816 + 2048;
  {
    const unsigned short* src = Kp + U0;
    for (int i = threadIdx.x*8; i < kcnt; i += 2048){
      f32x4 v = *(const f32x4*)(src + i);
      *(f32x4*)(ks + i + ((i>>6)<<3)) = v;          // padded: +8 ushorts per 64
    }
  }
  __syncthreads();
  f32x16 acc0 = {}; f32x16 acc1 = {};
  if (seg < nseg){
    int u0 = -1984 + (seg << 10);
    const unsigned short* C0p = (const unsigned short*)(ws + CRB0) + e*32832;
    const unsigned short* C1p = (const unsigned short*)(ws + CRB1) + e*32832;
    int ku  = (u0 - U0) + (il << 6) + (h << 3);
    int bA0 = 32768 - t0 + u0 - (il << 1) + (h << 3);
    int bA1 = bA0 - 2;
#pragma unroll 2
    for (int q = 0; q < 64; ++q){
      union { f32x4 v; bf16x8 s; } a0u, a1u, bu;
      a0u.v = *(const f32x4*)(C0p + bA0);
      a1u.v = *(const f32x4*)(C1p + bA1);
      int pa = ku + ((ku>>6)<<3);
      bu.v  = *(const f32x4*)(ks + pa);
      acc0 = __builtin_amdgcn_mfma_f32_32x32x16_bf16(a0u.s, bu.s, acc0, 0, 0, 0);
      acc1 = __builtin_amdgcn_mfma_f32_32x32x16_bf16(a1u.s, bu.s, acc1, 0, 0, 0);
      bA0 += 16; bA1 += 16; ku += 16;
    }
  }
  __syncthreads();                                   // K stage dead; reuse as red
  float* red = pool;
  int wl = w & 1;
  if (w < 2){
#pragma unroll
    for (int rr = 0; rr < 16; ++rr){
      int row = (rr & 3) + ((rr >> 2) << 3) + (h << 2);
      red[(wl<<11) + (row << 6) + il]      = acc0[rr];
      red[(wl<<11) + (row << 6) + 32 + il] = acc1[rr];
    }
  }
  __syncthreads();
  if (w >= 2){
#pragma unroll
    for (int rr = 0; rr < 16; ++rr){
      int row = (rr & 3) + ((rr >> 2) << 3) + (h << 2);
      red[(wl<<11) + (row << 6) + il]      += acc0[rr];
      red[(wl<<11) + (row << 6) + 32 + il] += acc1[rr];
    }
  }
  __syncthreads();
  float* slab = ws + SLAB + b*2048;
  int tid = threadIdx.x;
#pragma unroll
  for (int jj = 0; jj < 8; ++jj){
    int pos = tid*8 + jj;
    int il2 = pos >> 6, x = pos & 63;
    int idx = ((x >> 1) << 6) + ((x & 1) << 5) + il2;
    slab[pos] = red[idx] + red[2048 + idx];
  }
}

__global__ void k_final(const float* __restrict__ ws, float* __restrict__ out){
  int t = blockIdx.x*1024 + threadIdx.x;
  int T2 = t >> 11, pos = t & 2047;
  int cum = 0;
  for (int j=0;j<T2;++j) cum += (j+2)>>1;
  int nb = (T2+2)>>1;
  float s = 0.f;
  for (int e=0;e<16;++e){
    const float* sl = ws + SLAB + (e*72 + cum)*2048 + pos;
    for (int q=0;q<nb;++q) s += sl[q*2048];
  }
  out[t] = s;
}

// ================= launcher =================

extern "C" void kernel_launch(void* const* d_in, const int* in_sizes, int n_in,
                              void* d_out, int out_size, void* d_ws, size_t ws_size,
                              hipStream_t stream){
  const float* x         = (const float*)d_in[0];
  const float* noise     = (const float*)d_in[1];
  const float* fb_w      = (const float*)d_in[2];
  const float* reduce_w  = (const float*)d_in[3];
  const float* reduce_b  = (const float*)d_in[4];
  const float* dl_dw     = (const float*)d_in[5];
  const float* dl_db     = (const float*)d_in[6];
  const float* dl_pw     = (const float*)d_in[7];
  const float* dl_pb     = (const float*)d_in[8];
  const float* tt_w      = (const float*)d_in[9];
  const float* tt_b      = (const float*)d_in[10];
  const float* tr_w      = (const float*)d_in[11];
  const float* tr_b      = (const float*)d_in[12];
  const float* pos_lin_w = (const float*)d_in[13];
  const float* pos_lin_b = (const float*)d_in[14];
  const float* pos_up_w  = (const float*)d_in[15];
  const float* pos_up_b  = (const float*)d_in[16];
  const float* pos_out_w = (const float*)d_in[17];
  const float* pos_out_b = (const float*)d_in[18];
  const float* env_lin_w = (const float*)d_in[19];
  const float* env_lin_b = (const float*)d_in[20];
  const float* env_up_w  = (const float*)d_in[21];
  const float* env_up_b  = (const float*)d_in[22];
  const float* env_out_w = (const float*)d_in[23];
  const float* env_out_b = (const float*)d_in[24];
  const float* tfu_lin_w = (const float*)d_in[25];
  const float* tfu_lin_b = (const float*)d_in[26];
  const float* tfu_up_w  = (const float*)d_in[27];
  const float* tfu_up_b  = (const float*)d_in[28];
  const float* tfu_out_w = (const float*)d_in[29];
  const float* tfu_out_b = (const float*)d_in[30];
  float* out = (float*)d_out;
  float* ws  = (float*)d_ws;

  k_setup<<<3201, 1024, 0, stream>>>(x, pos_up_w, env_up_w, tfu_up_w, tt_w, tr_w,
                                     pos_lin_w, env_lin_w, tfu_lin_w,
                                     dl_dw, dl_db, dl_pw, dl_pb, ws);
  k_fbpool<<<4096, 512, 0, stream>>>(fb_w, ws);
  k_reduce<<<128, 128, 0, stream>>>(reduce_w, reduce_b, ws);
  const int DIL[5] = {1, 3, 9, 27, 1};
  int src = HA, dst = HB;
  for (int l=0;l<5;++l){
    k_dil<<<128, 128, 0, stream>>>(ws, l, DIL[l], src, dst);
    int tmp = src; src = dst; dst = tmp;
  }
  k_topk<<<1, 1024, 0, stream>>>(ws, out);
  k_tt<<<32, 1024, 0, stream>>>(ws, tt_b, tr_b, out);
  k_lin3<<<256, 1024, 0, stream>>>(ws, pos_lin_b, env_lin_b, tfu_lin_b);

  // fused decoder layers, JT=8 blocks (pos convT | env conv3 | tfu conv3)
  k_layer<<<64, 128, 0, stream>>>(ws, pos_up_b, env_up_b, tfu_up_b, 16, 32,
      4,  WT_POS + 0,      0,   1, PA,   PB,
      4,  WT_ENV + 0,      0,   1, BUFA, BUFB,
      8,  WT_TFU + 0,      0,   2, TA,   TB);
  k_layer<<<128, 128, 0, stream>>>(ws, pos_up_b, env_up_b, tfu_up_b, 32, 64,
      8,  WT_POS + 65536,  128, 2, PB,   PA,
      8,  WT_ENV + 49152,  128, 2, BUFB, BUFA,
      16, WT_TFU + 49152,  128, 4, TB,   TA);
  k_layer<<<256, 128, 0, stream>>>(ws, pos_up_b, env_up_b, tfu_up_b, 64, 128,
      16, WT_POS + 131072, 256, 4, PA,   PB,
      16, WT_ENV + 98304,  256, 4, BUFA, BUFB,
      32, WT_TFU + 98304,  256, 8, TA,   TB);
  k_layer<<<256, 128, 0, stream>>>(ws, pos_up_b, env_up_b, tfu_up_b, 128, 256,
      32, WT_POS + 196608, 384, 8, PB,   PA,
      32, WT_ENV + 147456, 384, 8, BUFB, BUFA,
      1,  0,               0,   1, 0,    0);
  k_layer<<<512, 128, 0, stream>>>(ws, pos_up_b, env_up_b, tfu_up_b, 256, 512,
      64, WT_POS + 262144, 512, 16, PA,   PB,
      64, WT_ENV + 196608, 512, 16, BUFA, BUFB,
      1,  0,               0,   1, 0,    0);
  k_layer<<<512, 128, 0, stream>>>(ws, pos_up_b, env_up_b, tfu_up_b, 0, 512,
      1,  0,               0,   1, 0,    0,
      128, WT_ENV + 245760, 640, 32, BUFB, BUFA,
      1,  0,               0,   1, 0,    0);

  k_outs<<<144, 256, 0, stream>>>(ws, pos_out_w, pos_out_b, env_out_w, env_out_b,
                                  tfu_out_w, tfu_out_b, out);

  k_envK<<<4096, 256, 0, stream>>>(ws, noise);
  k_c<<<512, 1024, 0, stream>>>(ws);
  k_bigmfma<<<1152, 256, 0, stream>>>(ws);
  k_final<<<32, 1024, 0, stream>>>(ws, out);
}

// Round 11
// 558.877 us; speedup vs baseline: 1.6060x; 1.1033x over previous
//
#include <hip/hip_runtime.h>
#include <math.h>

// ---------------- constants ----------------
#define NSAMP 32768
#define NFRM  128

// ---- ws layout (float offsets) ----
static constexpr int S_OFF  = 0;
static constexpr int HP     = 32772;
static constexpr int NSQ    = HP + 16384;
static constexpr int HA     = NSQ + 16;
static constexpr int HB     = HA + 16384;
static constexpr int TFQ    = HA;                  // tf scores (overlays HA+HB, dead after topk)
static constexpr int WC     = HB + 16384;
static constexpr int WBC    = WC + 245760;
static constexpr int EWS    = WBC + 640;
static constexpr int TIMEO  = EWS + 2048;
static constexpr int TRANSO = TIMEO + 2048;
static constexpr int PE     = TRANSO + 2048;
static constexpr int RSEL   = PE + 2048;
static constexpr int ENVO   = RSEL + 1024;
static constexpr int BUFA   = ENVO + 4096;
static constexpr int BUFB   = BUFA + 524288;
static constexpr int WT     = BUFB + 524288;
static constexpr int WT_POS = WT;                  // 327680  [l][(c*4+k)*128+o]
static constexpr int WT_ENV = WT + 327680;         // 294912  [l][(c*3+k)*128+o]
static constexpr int WT_TFU = WT + 622592;         // 147456
static constexpr int WT_TT  = WT + 770048;
static constexpr int WT_TR  = WT + 786432;
static constexpr int LT_POS = WT + 802816;         // 65536  [s][k][c]  (s<4)
static constexpr int LT_ENV = WT + 868352;         // 65536  [s][k][c]  (s<4)
static constexpr int LT_TFU = WT + 933888;         // 131072 [s][k][c]  (s<8)
static constexpr int SINES  = WT + 1064960;        // 2097152 (64 x 32768)
static constexpr int ENVS   = SINES + 2097152;
static constexpr int SLAB   = SINES;               // overlays SINES+ENVS
static constexpr int CRB0   = ENVS + 524288;
static constexpr int CRB1   = CRB0 + 262656;
static constexpr int KB     = CRB1 + 262656;
static constexpr int PA     = KB + 278528;
static constexpr int PB     = PA + 262144;
static constexpr int TA     = PB + 262144;
static constexpr int TB     = TA + 131072;

// ---- output offsets ----
static constexpr int O_IDX  = 32768;
static constexpr int O_ENC  = 32784;
static constexpr int O_ENV  = 34832;
static constexpr int O_TIME = 38928;
static constexpr int O_TR   = 40976;

typedef short bf16x8 __attribute__((ext_vector_type(8)));
typedef float f32x4  __attribute__((ext_vector_type(4)));
typedef float f32x16 __attribute__((ext_vector_type(16)));

static __device__ __forceinline__ unsigned short f2bf(float f){
  unsigned int u = __float_as_uint(f);
  unsigned int r = (u + 0x7FFFu + ((u >> 16) & 1u)) >> 16;
  return (unsigned short)r;
}

// ================= fused setup =================
__global__ void k_setup(const float* __restrict__ x,
                        const float* __restrict__ posw, const float* __restrict__ envw,
                        const float* __restrict__ tfuw, const float* __restrict__ ttw,
                        const float* __restrict__ trw,  const float* __restrict__ lpw,
                        const float* __restrict__ lew,  const float* __restrict__ ltw,
                        const float* __restrict__ dw,   const float* __restrict__ db,
                        const float* __restrict__ pw,   const float* __restrict__ pb2,
                        float* __restrict__ ws){
  __shared__ float ps[1024];
  int b = blockIdx.x, tid = threadIdx.x;
  if (b == 0){
    float* S = ws + S_OFF;
    float v[32];
    const float4* x4 = (const float4*)(x + tid*32);
    float s = 0.f;
#pragma unroll
    for (int i=0;i<8;++i){
      float4 q = x4[i];
      v[4*i]=q.x; v[4*i+1]=q.y; v[4*i+2]=q.z; v[4*i+3]=q.w;
      s += q.x+q.y+q.z+q.w;
    }
    ps[tid] = s; __syncthreads();
    for (int ofs=1; ofs<1024; ofs<<=1){
      float add = (tid>=ofs)? ps[tid-ofs] : 0.f;
      __syncthreads();
      ps[tid] += add;
      __syncthreads();
    }
    float run = ps[tid] - s;
#pragma unroll
    for (int i=0;i<32;++i){ S[tid*32+i] = run; run += v[i]; }
    if (tid==1023) S[32768] = ps[1023];
  } else if (b < 1041){
    int i = (b-1)*1024 + tid;
    float v;
    if (i < 327680){
      int l = i>>16, r = i & 65535, o = r & 127, ck = r>>7, c = ck>>2, k = ck&3;
      v = posw[(l<<16) + (((o<<7)+c)<<2) + k];
    } else if (i < 622592){
      int i2 = i - 327680; int l = i2/49152, r = i2 - l*49152, o = r&127, ck = r>>7;
      int c = ck/3, k = ck - 3*c;
      v = envw[l*49152 + ((o<<7)+c)*3 + k];
    } else if (i < 770048){
      int i2 = i - 622592; int l = i2/49152, r = i2 - l*49152, o = r&127, ck = r>>7;
      int c = ck/3, k = ck - 3*c;
      v = tfuw[l*49152 + ((o<<7)+c)*3 + k];
    } else if (i < 786432){
      int i2 = i - 770048; int o = i2 & 127, c = i2 >> 7;
      v = ttw[(o<<7) + c];
    } else if (i < 802816){
      int i2 = i - 786432; int o = i2 & 127, c = i2 >> 7;
      v = trw[(o<<7) + c];
    } else if (i < 868352){
      // pos_lin -> [s][k][c], r = c*4+s
      int i2 = i - 802816; int s = i2 >> 14, k = (i2 >> 7) & 127, c = i2 & 127;
      v = lpw[(((c<<2)+s)<<7) + k];
    } else if (i < 933888){
      // env_lin -> [s][k][c]
      int i2 = i - 868352; int s = i2 >> 14, k = (i2 >> 7) & 127, c = i2 & 127;
      v = lew[(((c<<2)+s)<<7) + k];
    } else {
      // tfu_lin -> [s][k][c], r = c*8+s
      int i2 = i - 933888; int s = i2 >> 14, k = (i2 >> 7) & 127, c = i2 & 127;
      v = ltw[(((c<<3)+s)<<7) + k];
    }
    ws[WT + i] = v;
  } else if (b < 1121){
    int idx = (b-1041)*1024 + tid;
    if (idx < 81920){
      int l = idx >> 14, r = idx & 16383, o = r >> 7, c = r & 127;
      float a0=0.f, a1=0.f, a2=0.f;
      for (int m=0;m<128;++m){
        float p = pw[(l*128 + o)*128 + m];
        const float* dp = dw + ((l*128 + m)*128 + c)*3;
        a0 += p*dp[0]; a1 += p*dp[1]; a2 += p*dp[2];
      }
      float* W = ws + WC + ((l*128 + o)*128 + c)*3;
      W[0]=a0; W[1]=a1; W[2]=a2;
      if (c==0){
        float bb = pb2[l*128 + o];
        for (int m=0;m<128;++m) bb += pw[(l*128 + o)*128 + m] * db[l*128 + m];
        ws[WBC + l*128 + o] = bb;
      }
    }
  } else if (b < 3169){
    int b2 = b - 1121;
    int band = b2 >> 5;
    int t = ((b2 & 31) << 10) + tid;
    if (tid == 0){
      float l0 = __fdiv_rn((float)log(20.0),   (float)log(10.0));
      float l1 = __fdiv_rn((float)log(9922.5), (float)log(10.0));
      float dl = __fdiv_rn(__fsub_rn(l1, l0), 63.0f);
      float lb = __fadd_rn(l0, __fmul_rn((float)band, dl));
      float freq = (float)pow(10.0, (double)lb);
      ps[0] = __fmul_rn((float)(2.0*M_PI), freq);
    }
    __syncthreads();
    float w = ps[0];
    float tn = __fdiv_rn((float)t, 22050.0f);
    ws[SINES + band*NSAMP + t] = sinf(__fmul_rn(w, tn));
  } else {
    int i = (b-3169)*1024 + tid;
    {
      int e = i >> 11, r = i & 2047;
      ((unsigned short*)(ws + KB))[e*34816 + r] = 0;
    }
    if (i < 16*128){
      int e = i >> 7, r = i & 127;
      if (r < 64) ((unsigned short*)(ws + CRB0))[e*32832 + (r==0 ? 0 : 32768 + r)] = 0;
      else        ((unsigned short*)(ws + CRB1))[e*32832 + 32768 + (r-64)] = 0;
    }
  }
}

// ================= front-end =================

__global__ void k_fbpool(const float* __restrict__ fbw, float* __restrict__ ws){
  const float* S = ws + S_OFF;
  int c = blockIdx.x >> 5, j0 = (blockIdx.x & 31) << 2;
  int jj = threadIdx.x >> 7, kk = threadIdx.x & 127;
  int j = j0 + jj;
  int i0 = max(0, 256*j - 256), i1 = min(32767, 256*j + 255);
  float acc = 0.f;
#pragma unroll
  for (int m=0;m<4;++m){
    int k = kk + (m<<7);
    int hi = min(max(i1 + k - 255, 0), 32768);
    int lo = min(max(i0 + k - 256, 0), 32768);
    acc += fbw[c*512 + k] * (S[hi] - S[lo]);
  }
  for (int o=32;o;o>>=1) acc += __shfl_down(acc, o);
  __shared__ float red[8];
  if ((threadIdx.x & 63) == 0) red[threadIdx.x>>6] = acc;
  __syncthreads();
  if (threadIdx.x < 4)
    ws[HP + c*128 + j0 + threadIdx.x] = (red[2*threadIdx.x] + red[2*threadIdx.x+1]) * (1.0f/512.0f);
}

__global__ void k_reduce(const float* __restrict__ rw, const float* __restrict__ rb,
                         float* __restrict__ ws){
  int o = blockIdx.x, t = threadIdx.x;
  const float* hp = ws + HP;
  float sq = 0.f;
  for (int i=t;i<16384;i+=128){ float v = hp[i]; sq += v*v; }
  for (int ofs=32;ofs;ofs>>=1) sq += __shfl_down(sq, ofs);
  __shared__ float rr2[2];
  if ((t & 63) == 0) rr2[t>>6] = sq;
  __syncthreads();
  float g = sqrtf(rr2[0] + rr2[1]) + 1e-8f;
  float acc = rb[o];
  for (int c=0;c<128;++c) acc += rw[o*161 + c] * __fdiv_rn(hp[c*128 + t], g);
  float delta = __fdiv_rn(2.0f, 127.0f);
  float p = __fadd_rn(-1.0f, __fmul_rn((float)t, delta));
  acc += rw[o*161 + 128] * p;
  float sc = 1.0f;
  const float PIF = (float)M_PI;
#pragma unroll
  for (int i=0;i<16;++i){
    float f = __fmul_rn(__fmul_rn(p, sc), PIF);
    acc += rw[o*161 + 129 + 2*i] * sinf(f);
    acc += rw[o*161 + 130 + 2*i] * cosf(f);
    sc = sc * 2.0f;
  }
  ws[HA + o*128 + t] = acc;
}

// dilated conv layer: 256 threads, 2-way c-split, LDS partial reduce
__global__ void k_dil(float* __restrict__ ws, int l, int d, int inoff, int outoff){
  __shared__ float xin[16384];
  __shared__ float pr[256];
  int o = blockIdx.x, tid = threadIdx.x;
  int t = tid & 127, half = tid >> 7;
  const float* in = ws + inoff;
  for (int idx=tid; idx<16384; idx+=256) xin[idx] = in[idx];
  __syncthreads();
  const float* Wo = ws + WC + (l*128 + o)*384 + half*192;
  float acc = (half == 0) ? (xin[o*128 + t] + ws[WBC + l*128 + o]) : 0.f;
  int cbase = half << 6;
  for (int c2=0;c2<64;++c2){
    int c = cbase + c2;
    float v0 = (t-d >= 0)  ? xin[c*128 + t - d] : 0.f;
    float v1 = xin[c*128 + t];
    float v2 = (t+d < 128) ? xin[c*128 + t + d] : 0.f;
    acc += Wo[c2*3]*v0 + Wo[c2*3+1]*v1 + Wo[c2*3+2]*v2;
  }
  pr[half*128 + t] = acc;
  __syncthreads();
  if (tid < 128){
    float a = pr[tid] + pr[128 + tid];
    ws[outoff + o*128 + tid] = a >= 0.f ? a : 0.2f*a;
  }
}

// topk + encoded: 1024 threads, LDS-staged h (swizzled), split reductions
__global__ void k_topk(float* __restrict__ ws, float* __restrict__ out){
  const float* h = ws + HB;
  int tid = threadIdx.x;
  int g = tid >> 7, t = tid & 127;
  __shared__ float xs[16384];
  __shared__ float part[1024];
  __shared__ float nt[128], nt0[128], csh[128];
  __shared__ int idxs[16];
  __shared__ float gsh[1];
  __shared__ float wv[2]; __shared__ int wi[2];
  for (int idx=tid; idx<16384; idx+=1024){
    int c = idx >> 7, tt = idx & 127;
    xs[(c<<7) + ((tt+c)&127)] = h[idx];
  }
  __syncthreads();
  float p = 0.f;
  for (int c=g; c<128; c+=8){ float v = xs[(c<<7) + ((t+c)&127)]; p += v*v; }
  part[tid] = p;
  __syncthreads();
  if (tid < 128){
    float cs = 0.f;
#pragma unroll
    for (int gg=0; gg<8; ++gg) cs += part[(gg<<7) + tid];
    csh[tid] = cs;
  }
  __syncthreads();
  if (tid < 64){
    float s = csh[tid] + csh[tid+64];
    for (int o=32;o;o>>=1) s += __shfl_down(s, o);
    if (tid == 0) gsh[0] = sqrtf(s) + 1e-8f;
  }
  __syncthreads();
  float g2 = gsh[0];
  float p2 = 0.f;
  for (int c=g; c<128; c+=8){ float v = __fdiv_rn(xs[(c<<7) + ((t+c)&127)], g2); p2 += v*v; }
  part[tid] = p2;
  __syncthreads();
  if (tid < 128){
    float cs = 0.f;
#pragma unroll
    for (int gg=0; gg<8; ++gg) cs += part[(gg<<7) + tid];
    float ntv = sqrtf(cs);
    nt[tid] = ntv; nt0[tid] = ntv;
  }
  __syncthreads();
  for (int j=0;j<16;++j){
    if (tid < 128){
      float v = nt[t]; int bi = t;
      for (int o=32;o;o>>=1){
        float ov = __shfl_down(v, o); int oi = __shfl_down(bi, o);
        if (ov > v || (ov == v && oi < bi)){ v = ov; bi = oi; }
      }
      if ((t & 63) == 0){ wv[t>>6] = v; wi[t>>6] = bi; }
    }
    __syncthreads();
    if (tid == 0){
      int win = (wv[1] > wv[0] || (wv[1] == wv[0] && wi[1] < wi[0])) ? wi[1] : wi[0];
      idxs[j] = win; nt[win] = -3.0e38f;
    }
    __syncthreads();
  }
  if (tid < 16) out[O_IDX + tid] = (float)idxs[tid];
  for (int pos=tid; pos<2048; pos+=1024){
    int j = pos >> 7, ch = pos & 127;
    int ij = idxs[j];
    float hv = __fdiv_rn(xs[(ch<<7) + ((ij+ch)&127)], g2);
    float enc = __fdiv_rn(hv, nt0[ij] + 1e-8f);
    out[O_ENC + pos] = enc;
    ws[EWS + pos] = enc;
  }
}

__global__ void k_tt(float* __restrict__ ws, const float* __restrict__ ttb,
                     const float* __restrict__ trb, float* __restrict__ out){
  int kind = blockIdx.x >> 4, j = blockIdx.x & 15;
  int tid = threadIdx.x;
  int o = tid & 127, cg = tid >> 7;
  __shared__ float er[128];
  __shared__ float part[8][128];
  if (tid < 128) er[tid] = ws[EWS + j*128 + tid];
  __syncthreads();
  const float* Wt = ws + (kind ? WT_TR : WT_TT);
  float acc = 0.f;
  for (int c=cg; c<128; c+=8) acc += er[c] * Wt[c*128 + o];
  part[cg][o] = acc;
  __syncthreads();
  if (tid < 128){
    float a = kind ? trb[tid] : ttb[tid];
#pragma unroll
    for (int g=0; g<8; ++g) a += part[g][tid];
    out[(kind ? O_TR : O_TIME) + j*128 + tid] = a;
    ws[(kind ? TRANSO : TIMEO) + j*128 + tid] = a;
  }
}

// ================= decoder stacks =================

// fused linears: block = (stack, e, s); 1024 threads = 8 kg x 128 c; LT is [s][k][c]
__global__ void k_lin3(float* __restrict__ ws, const float* __restrict__ plb,
                       const float* __restrict__ elb, const float* __restrict__ tlb){
  int b = blockIdx.x, tid = threadIdx.x;
  int kg = tid >> 7, c = tid & 127;
  int e, s, start, ltoff, zoff, dst;
  const float* lb;
  if (b < 64){
    e = b >> 2; s = b & 3; start = 4; ltoff = LT_POS; zoff = TIMEO; dst = PA; lb = plb;
  } else if (b < 128){
    int b2 = b - 64; e = b2 >> 2; s = b2 & 3; start = 4; ltoff = LT_ENV; zoff = TRANSO; dst = BUFA; lb = elb;
  } else {
    int b2 = b - 128; e = b2 >> 3; s = b2 & 7; start = 8; ltoff = LT_TFU; zoff = TRANSO; dst = TA; lb = tlb;
  }
  __shared__ float z[128];
  __shared__ float part[8][128];
  if (tid < 128) z[tid] = ws[zoff + e*128 + tid];
  __syncthreads();
  const float* lt = ws + ltoff + (s << 14);
  float acc = 0.f;
  for (int k=kg; k<128; k+=8) acc += z[k] * lt[(k<<7) + c];
  part[kg][c] = acc;
  __syncthreads();
  if (tid < 128){
    float a = lb[tid*start + s];
#pragma unroll
    for (int g=0; g<8; ++g) a += part[g][tid];
    ws[dst + e*(start<<7) + (s<<7) + tid] = a;   // (e, s, c) layout
  }
}

// convT (k=4, stride2), JT=8
static __device__ __forceinline__ void convT8_dev(float* __restrict__ ws, const float* __restrict__ bias,
                                                  int srcoff, int dstoff, int wtoff, int Lin,
                                                  int e, int jt, float* xs, float* wl){
  int j0 = jt*8, o = threadIdx.x;
  int s_lo = (j0 >> 1) - 1;
  const float* in = ws + srcoff + e*Lin*128;
  for (int idx=o; idx<6*128; idx+=128){
    int si = idx >> 7, c = idx & 127, s = s_lo + si;
    xs[idx] = (s >= 0 && s < Lin) ? in[s*128 + c] : 0.f;
  }
  float acc[8];
#pragma unroll
  for (int jj=0;jj<8;++jj) acc[jj] = bias[o];
  const float* wt = ws + wtoff;
#pragma unroll 1
  for (int cb=0; cb<128; cb+=16){
    __syncthreads();
    for (int idx=o; idx<8192; idx+=128) wl[idx] = wt[(cb<<9) + idx];
    __syncthreads();
#pragma unroll
    for (int cc=0; cc<16; ++cc){
      int c = cb + cc;
      float w0 = wl[((cc<<2)+0)*128 + o];
      float w1 = wl[((cc<<2)+1)*128 + o];
      float w2 = wl[((cc<<2)+2)*128 + o];
      float w3 = wl[((cc<<2)+3)*128 + o];
      float xr[6];
#pragma unroll
      for (int s=0;s<6;++s) xr[s] = xs[(s<<7) + c];
#pragma unroll
      for (int jj=0;jj<8;++jj){
        if ((jj & 1) == 0){
          acc[jj] += xr[jj>>1]*w3 + xr[(jj>>1)+1]*w1;
        } else {
          acc[jj] += xr[(jj+1)>>1]*w2 + xr[((jj+1)>>1)+1]*w0;
        }
      }
    }
  }
  float* outp = ws + dstoff + e*(Lin*2)*128;
#pragma unroll
  for (int jj=0;jj<8;++jj){
    float v = acc[jj];
    outp[(j0+jj)*128 + o] = v >= 0.f ? v : 0.2f*v;
  }
}

// conv3 on nearest-2x-upsampled input, JT=8
static __device__ __forceinline__ void conv3up8_dev(float* __restrict__ ws, const float* __restrict__ bias,
                                                    int srcoff, int dstoff, int wtoff, int Lin,
                                                    int e, int jt, float* xs, float* wl){
  int j0 = jt*8, o = threadIdx.x;
  int fs = (j0 >> 1) - 1;
  const float* in = ws + srcoff + e*Lin*128;
  for (int idx=o; idx<6*128; idx+=128){
    int si = idx >> 7, c = idx & 127, s = fs + si;
    xs[idx] = (s >= 0 && s < Lin) ? in[s*128 + c] : 0.f;
  }
  float acc[8];
#pragma unroll
  for (int jj=0;jj<8;++jj) acc[jj] = bias[o];
  const float* wt = ws + wtoff;
#pragma unroll 1
  for (int cb=0; cb<128; cb+=16){
    __syncthreads();
    for (int idx=o; idx<6144; idx+=128) wl[idx] = wt[cb*384 + idx];
    __syncthreads();
#pragma unroll
    for (int cc=0; cc<16; ++cc){
      int c = cb + cc;
      float w0 = wl[(cc*3+0)*128 + o];
      float w1 = wl[(cc*3+1)*128 + o];
      float w2 = wl[(cc*3+2)*128 + o];
      float xr[6];
#pragma unroll
      for (int s=0;s<6;++s) xr[s] = xs[(s<<7) + c];
#pragma unroll
      for (int jj=0;jj<8;++jj){
        acc[jj] += xr[((jj-1)>>1)+1]*w0
                 + xr[((jj  )>>1)+1]*w1
                 + xr[((jj+1)>>1)+1]*w2;
      }
    }
  }
  float* outp = ws + dstoff + e*(Lin*2)*128;
#pragma unroll
  for (int jj=0;jj<8;++jj){
    float v = acc[jj];
    outp[(j0+jj)*128 + o] = v >= 0.f ? v : 0.2f*v;
  }
}

__global__ __launch_bounds__(128, 4)
void k_layer(float* __restrict__ ws, const float* __restrict__ pbias,
             const float* __restrict__ ebias, const float* __restrict__ tbias,
             int c1, int c2,
             int pLin, int pWt, int pBo, int pNJ, int pSrc, int pDst,
             int eLin, int eWt, int eBo, int eNJ, int eSrc, int eDst,
             int tLin, int tWt, int tBo, int tNJ, int tSrc, int tDst){
  __shared__ float xs[6*128];
  __shared__ float wl[8192];
  int b = blockIdx.x;
  if (b < c1){
    int e = b / pNJ, jt = b - e*pNJ;
    convT8_dev(ws, pbias + pBo, pSrc, pDst, pWt, pLin, e, jt, xs, wl);
  } else if (b < c2){
    int bl = b - c1; int e = bl / eNJ, jt = bl - e*eNJ;
    conv3up8_dev(ws, ebias + eBo, eSrc, eDst, eWt, eLin, e, jt, xs, wl);
  } else {
    int bl = b - c2; int e = bl / tNJ, jt = bl - e*tNJ;
    conv3up8_dev(ws, tbias + tBo, tSrc, tDst, tWt, tLin, e, jt, xs, wl);
  }
}

// fused epilogues: blocks 0..15 out_pos, 16..79 out_env, 80..143 out_tfu ; 512 threads
__global__ void k_outs(float* __restrict__ ws,
                       const float* __restrict__ pw, const float* __restrict__ pb,
                       const float* __restrict__ ew, const float* __restrict__ eb,
                       const float* __restrict__ tw, const float* __restrict__ tb_,
                       float* __restrict__ out){
  __shared__ float xs[16384];
  int b = blockIdx.x, tid = threadIdx.x;
  if (b < 16){
    int e = b;
    const float* in = ws + PB + e*16384;
    for (int idx=tid; idx<16384; idx+=512){
      int q = idx >> 7, c = idx & 127;
      xs[(q<<7) + ((c+q)&127)] = in[idx];
    }
    __syncthreads();
    int j = tid & 127, cg = tid >> 7;        // 4-way c-split
    float acc = (cg == 0) ? pb[0] : 0.f;
    int cbase = cg << 5;
    for (int c2=0;c2<32;++c2){
      int c = cbase + c2;
#pragma unroll
      for (int k=0;k<3;++k){
        int q = j + k - 1;
        if (q >= 0 && q < 128) acc += xs[(q<<7) + ((c+q)&127)] * pw[c*3 + k];
      }
    }
    __syncthreads();                          // xs staging dead; reuse
    xs[tid] = acc;
    __syncthreads();
    float a = 0.f;
    if (tid < 128) a = xs[tid] + xs[128+tid] + xs[256+tid] + xs[384+tid];
    __syncthreads();
    xs[tid] = (tid < 128) ? a : -3.0e38f;
    __syncthreads();
    for (int s=256; s>=1; s>>=1){ if (tid < s) xs[tid] = fmaxf(xs[tid], xs[tid+s]); __syncthreads(); }
    float m = xs[0];
    __syncthreads();
    float ex = (tid < 128) ? expf(__fsub_rn(a, m)) : 0.f;
    xs[tid] = ex;
    __syncthreads();
    for (int s=256; s>=1; s>>=1){ if (tid < s) xs[tid] += xs[tid+s]; __syncthreads(); }
    if (tid < 128) ws[PE + e*128 + tid] = __fdiv_rn(ex, xs[0]);
  } else if (b < 80){
    int idx2 = b - 16; int e = idx2 >> 2, b0 = (idx2 & 3) << 6;
    const float* in = ws + BUFA + e*32768;
    for (int idx=tid; idx<8448; idx+=512){
      int qs = idx >> 7, c = idx & 127, q = b0 - 1 + qs;
      xs[(qs<<7) + ((c+qs)&127)] = (q >= 0 && q < 256) ? in[q*128 + c] : 0.f;
    }
    __syncthreads();
    int part = tid >> 6, bb = tid & 63;       // 8-way c-split
    float acc = (part == 0) ? eb[0] : 0.f;
    for (int c2=0;c2<16;++c2){
      int c = part*16 + c2;
#pragma unroll
      for (int k=0;k<3;++k){
        int qs = bb + k;
        acc += xs[(qs<<7) + ((c+qs)&127)] * ew[c*3 + k];
      }
    }
    xs[8448 + tid] = acc;
    __syncthreads();
    if (tid < 64){
      float a = 0.f;
#pragma unroll
      for (int g=0; g<8; ++g) a += xs[8448 + g*64 + tid];
      a = fmaxf(a, 0.f);
      out[O_ENV + e*256 + b0 + tid] = a;
      ws[ENVO + e*256 + b0 + tid] = a;
    }
  } else {
    int b2 = b - 80; int e = b2 >> 2, rg = b2 & 3;
    float* tws = xs + 8448;
    const float* in = ws + TB + e*8192;
    for (int idx=tid; idx<8448; idx+=512){
      int qs = idx >> 7, c = idx & 127, q = -1 + qs;
      xs[(qs<<7) + ((c+qs)&127)] = (q >= 0 && q < 64) ? in[q*128 + c] : 0.f;
    }
    for (int idx=tid; idx<3072; idx+=512) tws[idx] = tw[rg*3072 + idx];
    __syncthreads();
    int rl = tid >> 6, bb = tid & 63;         // 1 row per thread
    int rr = rg*8 + rl;
    float acc = tb_[rr];
    for (int c=0;c<128;++c){
#pragma unroll
      for (int k=0;k<3;++k){
        int qs = bb + k;
        acc += xs[(qs<<7) + ((c+qs)&127)] * tws[rl*384 + c*3 + k];
      }
    }
    ws[TFQ + e*2048 + rr*64 + bb] = acc;
  }
}

// ================= synthesis =================

__global__ void k_envK(float* __restrict__ ws, const float* __restrict__ noise){
  int b = blockIdx.x, tid = threadIdx.x;
  if (b < 2048){
    int e = b >> 7, F = b & 127;
    int t = (F << 8) + tid;
    __shared__ float ampl[64];
    if (tid < 64){
      const float* tf = ws + TFQ + e*2048;
      float best = tf[tid]; int bi = 0;
      for (int r=1;r<32;++r){ float v = tf[r*64 + tid]; if (v > best){ best = v; bi = r; } }
      float d = __fadd_rn(0.5f, __fmul_rn((float)bi, __fdiv_rn(__fsub_rn(0.9999f, 0.5f), 31.0f)));
      ampl[tid] = (float)pow((double)d, (double)F);
    }
    __syncthreads();
    float acc = 0.f;
    for (int band=0;band<64;++band) acc += ws[SINES + band*NSAMP + t] * ampl[band];
    ((unsigned short*)(ws + KB))[e*34816 + 2048 + t] = f2bf(acc * (1.0f/(64.0f*65536.0f)));
  } else {
    int idx = (b - 2048)*256 + tid;
    int e = idx >> 15, tau = idx & 32767;
    float cf = __fsub_rn(__fdiv_rn(__fmul_rn(__fadd_rn((float)tau, 0.5f), 256.0f), 32768.0f), 0.5f);
    float c = fminf(fmaxf(cf, 0.0f), 255.0f);
    int i0 = (int)floorf(c);
    int i1 = min(i0 + 1, 255);
    float w = __fsub_rn(c, (float)i0);
    float e0 = ws[ENVO + e*256 + i0], e1 = ws[ENVO + e*256 + i1];
    float val = __fadd_rn(__fmul_rn(e0, __fsub_rn(1.0f, w)), __fmul_rn(e1, w));
    ws[ENVS + e*NSAMP + tau] = val * noise[tau];
  }
}

__global__ void k_c(float* __restrict__ ws){
  int e = blockIdx.x >> 5, seg = blockIdx.x & 31;
  int t = (seg << 10) + threadIdx.x;
  __shared__ float pl[128];
  if (threadIdx.x < 128) pl[threadIdx.x] = ws[PE + e*128 + threadIdx.x];
  __syncthreads();
  const float* ev = ws + ENVS + e*NSAMP;
  int kub = min(127, (seg << 2) + 3);
  float acc = 0.f;
  for (int k=0;k<=kub;++k){
    int u = t - (k << 8);
    if (u >= 0) acc += pl[k] * ev[u];
  }
  unsigned short hv = f2bf(acc);
  ((unsigned short*)(ws + CRB0))[e*32832 + 32768 - t] = hv;
  ((unsigned short*)(ws + CRB1))[e*32832 + 32767 - t] = hv;
}

// Toeplitz conv via MFMA 32x32x16 bf16; K operand LDS-staged (padded, conflict-free),
// red buffer aliases the staging pool; no atomics.
__global__ __launch_bounds__(256, 4)
void k_bigmfma(float* __restrict__ ws){
  int b = blockIdx.x;
  int w = threadIdx.x >> 6;
  int lane = threadIdx.x & 63;
  int e = b / 72;
  int r = b - e*72;
  int T2 = 0, cum = 0;
  while (cum + ((T2+2)>>1) <= r){ cum += (T2+2)>>1; T2++; }
  int qb = r - cum;
  int nseg = 2*(T2+1);
  int seg = qb*4 + w;
  int t0 = T2 << 11;
  int il = lane & 31, h = lane >> 5;
  __shared__ __align__(16) float pool[4096];        // 16 KB: K stage, then red
  unsigned short* ks = (unsigned short*)pool;
  int wmax = nseg - 1 - qb*4; if (wmax > 3) wmax = 3;
  int U0 = -1984 + (qb << 12);
  int kcnt = wmax*1024 + 3008;
  const unsigned short* Kp = (const unsigned short*)(ws + KB) + e*34816 + 2048;
  {
    const unsigned short* src = Kp + U0;
    for (int i = threadIdx.x*8; i < kcnt; i += 2048){
      f32x4 v = *(const f32x4*)(src + i);
      *(f32x4*)(ks + i + ((i>>6)<<3)) = v;          // padded: +8 ushorts per 64
    }
  }
  __syncthreads();
  f32x16 acc0 = {}; f32x16 acc1 = {};
  if (seg < nseg){
    int u0 = -1984 + (seg << 10);
    const unsigned short* C0p = (const unsigned short*)(ws + CRB0) + e*32832;
    const unsigned short* C1p = (const unsigned short*)(ws + CRB1) + e*32832;
    int ku  = (u0 - U0) + (il << 6) + (h << 3);
    int bA0 = 32768 - t0 + u0 - (il << 1) + (h << 3);
    int bA1 = bA0 - 2;
#pragma unroll 2
    for (int q = 0; q < 64; ++q){
      union { f32x4 v; bf16x8 s; } a0u, a1u, bu;
      a0u.v = *(const f32x4*)(C0p + bA0);
      a1u.v = *(const f32x4*)(C1p + bA1);
      int pa = ku + ((ku>>6)<<3);
      bu.v  = *(const f32x4*)(ks + pa);
      acc0 = __builtin_amdgcn_mfma_f32_32x32x16_bf16(a0u.s, bu.s, acc0, 0, 0, 0);
      acc1 = __builtin_amdgcn_mfma_f32_32x32x16_bf16(a1u.s, bu.s, acc1, 0, 0, 0);
      bA0 += 16; bA1 += 16; ku += 16;
    }
  }
  __syncthreads();                                   // K stage dead; reuse as red
  float* red = pool;
  int wl = w & 1;
  if (w < 2){
#pragma unroll
    for (int rr = 0; rr < 16; ++rr){
      int row = (rr & 3) + ((rr >> 2) << 3) + (h << 2);
      red[(wl<<11) + (row << 6) + il]      = acc0[rr];
      red[(wl<<11) + (row << 6) + 32 + il] = acc1[rr];
    }
  }
  __syncthreads();
  if (w >= 2){
#pragma unroll
    for (int rr = 0; rr < 16; ++rr){
      int row = (rr & 3) + ((rr >> 2) << 3) + (h << 2);
      red[(wl<<11) + (row << 6) + il]      += acc0[rr];
      red[(wl<<11) + (row << 6) + 32 + il] += acc1[rr];
    }
  }
  __syncthreads();
  float* slab = ws + SLAB + b*2048;
  int tid = threadIdx.x;
#pragma unroll
  for (int jj = 0; jj < 8; ++jj){
    int pos = tid*8 + jj;
    int il2 = pos >> 6, x = pos & 63;
    int idx = ((x >> 1) << 6) + ((x & 1) << 5) + il2;
    slab[pos] = red[idx] + red[2048 + idx];
  }
}

__global__ void k_final(const float* __restrict__ ws, float* __restrict__ out){
  int t = blockIdx.x*1024 + threadIdx.x;
  int T2 = t >> 11, pos = t & 2047;
  int cum = 0;
  for (int j=0;j<T2;++j) cum += (j+2)>>1;
  int nb = (T2+2)>>1;
  float s = 0.f;
  for (int e=0;e<16;++e){
    const float* sl = ws + SLAB + (e*72 + cum)*2048 + pos;
    for (int q=0;q<nb;++q) s += sl[q*2048];
  }
  out[t] = s;
}

// ================= launcher =================

extern "C" void kernel_launch(void* const* d_in, const int* in_sizes, int n_in,
                              void* d_out, int out_size, void* d_ws, size_t ws_size,
                              hipStream_t stream){
  const float* x         = (const float*)d_in[0];
  const float* noise     = (const float*)d_in[1];
  const float* fb_w      = (const float*)d_in[2];
  const float* reduce_w  = (const float*)d_in[3];
  const float* reduce_b  = (const float*)d_in[4];
  const float* dl_dw     = (const float*)d_in[5];
  const float* dl_db     = (const float*)d_in[6];
  const float* dl_pw     = (const float*)d_in[7];
  const float* dl_pb     = (const float*)d_in[8];
  const float* tt_w      = (const float*)d_in[9];
  const float* tt_b      = (const float*)d_in[10];
  const float* tr_w      = (const float*)d_in[11];
  const float* tr_b      = (const float*)d_in[12];
  const float* pos_lin_w = (const float*)d_in[13];
  const float* pos_lin_b = (const float*)d_in[14];
  const float* pos_up_w  = (const float*)d_in[15];
  const float* pos_up_b  = (const float*)d_in[16];
  const float* pos_out_w = (const float*)d_in[17];
  const float* pos_out_b = (const float*)d_in[18];
  const float* env_lin_w = (const float*)d_in[19];
  const float* env_lin_b = (const float*)d_in[20];
  const float* env_up_w  = (const float*)d_in[21];
  const float* env_up_b  = (const float*)d_in[22];
  const float* env_out_w = (const float*)d_in[23];
  const float* env_out_b = (const float*)d_in[24];
  const float* tfu_lin_w = (const float*)d_in[25];
  const float* tfu_lin_b = (const float*)d_in[26];
  const float* tfu_up_w  = (const float*)d_in[27];
  const float* tfu_up_b  = (const float*)d_in[28];
  const float* tfu_out_w = (const float*)d_in[29];
  const float* tfu_out_b = (const float*)d_in[30];
  float* out = (float*)d_out;
  float* ws  = (float*)d_ws;

  k_setup<<<3201, 1024, 0, stream>>>(x, pos_up_w, env_up_w, tfu_up_w, tt_w, tr_w,
                                     pos_lin_w, env_lin_w, tfu_lin_w,
                                     dl_dw, dl_db, dl_pw, dl_pb, ws);
  k_fbpool<<<4096, 512, 0, stream>>>(fb_w, ws);
  k_reduce<<<128, 128, 0, stream>>>(reduce_w, reduce_b, ws);
  const int DIL[5] = {1, 3, 9, 27, 1};
  int src = HA, dst = HB;
  for (int l=0;l<5;++l){
    k_dil<<<128, 256, 0, stream>>>(ws, l, DIL[l], src, dst);
    int tmp = src; src = dst; dst = tmp;
  }
  k_topk<<<1, 1024, 0, stream>>>(ws, out);
  k_tt<<<32, 1024, 0, stream>>>(ws, tt_b, tr_b, out);
  k_lin3<<<256, 1024, 0, stream>>>(ws, pos_lin_b, env_lin_b, tfu_lin_b);

  // fused decoder layers, JT=8 blocks (pos convT | env conv3 | tfu conv3)
  k_layer<<<64, 128, 0, stream>>>(ws, pos_up_b, env_up_b, tfu_up_b, 16, 32,
      4,  WT_POS + 0,      0,   1, PA,   PB,
      4,  WT_ENV + 0,      0,   1, BUFA, BUFB,
      8,  WT_TFU + 0,      0,   2, TA,   TB);
  k_layer<<<128, 128, 0, stream>>>(ws, pos_up_b, env_up_b, tfu_up_b, 32, 64,
      8,  WT_POS + 65536,  128, 2, PB,   PA,
      8,  WT_ENV + 49152,  128, 2, BUFB, BUFA,
      16, WT_TFU + 49152,  128, 4, TB,   TA);
  k_layer<<<256, 128, 0, stream>>>(ws, pos_up_b, env_up_b, tfu_up_b, 64, 128,
      16, WT_POS + 131072, 256, 4, PA,   PB,
      16, WT_ENV + 98304,  256, 4, BUFA, BUFB,
      32, WT_TFU + 98304,  256, 8, TA,   TB);
  k_layer<<<256, 128, 0, stream>>>(ws, pos_up_b, env_up_b, tfu_up_b, 128, 256,
      32, WT_POS + 196608, 384, 8, PB,   PA,
      32, WT_ENV + 147456, 384, 8, BUFB, BUFA,
      1,  0,               0,   1, 0,    0);
  k_layer<<<512, 128, 0, stream>>>(ws, pos_up_b, env_up_b, tfu_up_b, 256, 512,
      64, WT_POS + 262144, 512, 16, PA,   PB,
      64, WT_ENV + 196608, 512, 16, BUFA, BUFB,
      1,  0,               0,   1, 0,    0);
  k_layer<<<512, 128, 0, stream>>>(ws, pos_up_b, env_up_b, tfu_up_b, 0, 512,
      1,  0,               0,   1, 0,    0,
      128, WT_ENV + 245760, 640, 32, BUFB, BUFA,
      1,  0,               0,   1, 0,    0);

  k_outs<<<144, 512, 0, stream>>>(ws, pos_out_w, pos_out_b, env_out_w, env_out_b,
                                  tfu_out_w, tfu_out_b, out);

  k_envK<<<4096, 256, 0, stream>>>(ws, noise);
  k_c<<<512, 1024, 0, stream>>>(ws);
  k_bigmfma<<<1152, 256, 0, stream>>>(ws);
  k_final<<<32, 1024, 0, stream>>>(ws, out);
}

// Round 12
// 525.711 us; speedup vs baseline: 1.7073x; 1.0631x over previous
//
#include <hip/hip_runtime.h>
#include <math.h>

// ---------------- constants ----------------
#define NSAMP 32768
#define NFRM  128

// ---- ws layout (float offsets) ----
static constexpr int S_OFF  = 0;
static constexpr int HP     = 32772;
static constexpr int NSQ    = HP + 16384;
static constexpr int HA     = NSQ + 16;
static constexpr int HB     = HA + 16384;
static constexpr int TFQ    = HA;                  // tf scores (overlays HA+HB, dead after topk)
static constexpr int WC     = HB + 16384;
static constexpr int WBC    = WC + 245760;
static constexpr int EWS    = WBC + 640;
static constexpr int TIMEO  = EWS + 2048;
static constexpr int TRANSO = TIMEO + 2048;
static constexpr int PE     = TRANSO + 2048;
static constexpr int RSEL   = PE + 2048;
static constexpr int ENVO   = RSEL + 1024;
static constexpr int BUFA   = ENVO + 4096;
static constexpr int BUFB   = BUFA + 524288;
static constexpr int WT     = BUFB + 524288;
static constexpr int WT_POS = WT;                  // 327680  [l][(c*4+k)*128+o]
static constexpr int WT_ENV = WT + 327680;         // 294912  [l][(c*3+k)*128+o]
static constexpr int WT_TFU = WT + 622592;         // 147456
static constexpr int WT_TT  = WT + 770048;
static constexpr int WT_TR  = WT + 786432;
static constexpr int LT_POS = WT + 802816;         // 65536  [s][k][c]  (s<4)
static constexpr int LT_ENV = WT + 868352;         // 65536  [s][k][c]  (s<4)
static constexpr int LT_TFU = WT + 933888;         // 131072 [s][k][c]  (s<8)
static constexpr int SINES  = WT + 1064960;        // 2097152 (64 x 32768)
static constexpr int ENVS   = SINES + 2097152;
static constexpr int SLAB   = SINES;               // overlays SINES+ENVS
static constexpr int CRB0   = ENVS + 524288;
static constexpr int CRB1   = CRB0 + 262656;
static constexpr int KB     = CRB1 + 262656;
static constexpr int PA     = KB + 278528;         // also hpn scratch before k_lin3
static constexpr int PB     = PA + 262144;
static constexpr int TA     = PB + 262144;
static constexpr int TB     = TA + 131072;

// ---- output offsets ----
static constexpr int O_IDX  = 32768;
static constexpr int O_ENC  = 32784;
static constexpr int O_ENV  = 34832;
static constexpr int O_TIME = 38928;
static constexpr int O_TR   = 40976;

typedef short bf16x8 __attribute__((ext_vector_type(8)));
typedef float f32x4  __attribute__((ext_vector_type(4)));
typedef float f32x16 __attribute__((ext_vector_type(16)));

static __device__ __forceinline__ unsigned short f2bf(float f){
  unsigned int u = __float_as_uint(f);
  unsigned int r = (u + 0x7FFFu + ((u >> 16) & 1u)) >> 16;
  return (unsigned short)r;
}

// ================= fused setup =================
__global__ void k_setup(const float* __restrict__ x,
                        const float* __restrict__ posw, const float* __restrict__ envw,
                        const float* __restrict__ tfuw, const float* __restrict__ ttw,
                        const float* __restrict__ trw,  const float* __restrict__ lpw,
                        const float* __restrict__ lew,  const float* __restrict__ ltw,
                        const float* __restrict__ dw,   const float* __restrict__ db,
                        const float* __restrict__ pw,   const float* __restrict__ pb2,
                        float* __restrict__ ws){
  __shared__ float ps[1024];
  int b = blockIdx.x, tid = threadIdx.x;
  if (b == 0){
    float* S = ws + S_OFF;
    float v[32];
    const float4* x4 = (const float4*)(x + tid*32);
    float s = 0.f;
#pragma unroll
    for (int i=0;i<8;++i){
      float4 q = x4[i];
      v[4*i]=q.x; v[4*i+1]=q.y; v[4*i+2]=q.z; v[4*i+3]=q.w;
      s += q.x+q.y+q.z+q.w;
    }
    ps[tid] = s; __syncthreads();
    for (int ofs=1; ofs<1024; ofs<<=1){
      float add = (tid>=ofs)? ps[tid-ofs] : 0.f;
      __syncthreads();
      ps[tid] += add;
      __syncthreads();
    }
    float run = ps[tid] - s;
#pragma unroll
    for (int i=0;i<32;++i){ S[tid*32+i] = run; run += v[i]; }
    if (tid==1023) S[32768] = ps[1023];
  } else if (b < 1041){
    int i = (b-1)*1024 + tid;
    float v;
    if (i < 327680){
      int l = i>>16, r = i & 65535, o = r & 127, ck = r>>7, c = ck>>2, k = ck&3;
      v = posw[(l<<16) + (((o<<7)+c)<<2) + k];
    } else if (i < 622592){
      int i2 = i - 327680; int l = i2/49152, r = i2 - l*49152, o = r&127, ck = r>>7;
      int c = ck/3, k = ck - 3*c;
      v = envw[l*49152 + ((o<<7)+c)*3 + k];
    } else if (i < 770048){
      int i2 = i - 622592; int l = i2/49152, r = i2 - l*49152, o = r&127, ck = r>>7;
      int c = ck/3, k = ck - 3*c;
      v = tfuw[l*49152 + ((o<<7)+c)*3 + k];
    } else if (i < 786432){
      int i2 = i - 770048; int o = i2 & 127, c = i2 >> 7;
      v = ttw[(o<<7) + c];
    } else if (i < 802816){
      int i2 = i - 786432; int o = i2 & 127, c = i2 >> 7;
      v = trw[(o<<7) + c];
    } else if (i < 868352){
      // pos_lin -> [s][k][c], r = c*4+s
      int i2 = i - 802816; int s = i2 >> 14, k = (i2 >> 7) & 127, c = i2 & 127;
      v = lpw[(((c<<2)+s)<<7) + k];
    } else if (i < 933888){
      // env_lin -> [s][k][c]
      int i2 = i - 868352; int s = i2 >> 14, k = (i2 >> 7) & 127, c = i2 & 127;
      v = lew[(((c<<2)+s)<<7) + k];
    } else {
      // tfu_lin -> [s][k][c], r = c*8+s
      int i2 = i - 933888; int s = i2 >> 14, k = (i2 >> 7) & 127, c = i2 & 127;
      v = ltw[(((c<<3)+s)<<7) + k];
    }
    ws[WT + i] = v;
  } else if (b < 1121){
    int idx = (b-1041)*1024 + tid;
    if (idx < 81920){
      int l = idx >> 14, r = idx & 16383, o = r >> 7, c = r & 127;
      float a0=0.f, a1=0.f, a2=0.f;
      for (int m=0;m<128;++m){
        float p = pw[(l*128 + o)*128 + m];
        const float* dp = dw + ((l*128 + m)*128 + c)*3;
        a0 += p*dp[0]; a1 += p*dp[1]; a2 += p*dp[2];
      }
      float* W = ws + WC + ((l*128 + o)*128 + c)*3;
      W[0]=a0; W[1]=a1; W[2]=a2;
      if (c==0){
        float bb = pb2[l*128 + o];
        for (int m=0;m<128;++m) bb += pw[(l*128 + o)*128 + m] * db[l*128 + m];
        ws[WBC + l*128 + o] = bb;
      }
    }
  } else if (b < 3169){
    int b2 = b - 1121;
    int band = b2 >> 5;
    int t = ((b2 & 31) << 10) + tid;
    if (tid == 0){
      float l0 = __fdiv_rn((float)log(20.0),   (float)log(10.0));
      float l1 = __fdiv_rn((float)log(9922.5), (float)log(10.0));
      float dl = __fdiv_rn(__fsub_rn(l1, l0), 63.0f);
      float lb = __fadd_rn(l0, __fmul_rn((float)band, dl));
      float freq = (float)pow(10.0, (double)lb);
      ps[0] = __fmul_rn((float)(2.0*M_PI), freq);
    }
    __syncthreads();
    float w = ps[0];
    float tn = __fdiv_rn((float)t, 22050.0f);
    ws[SINES + band*NSAMP + t] = sinf(__fmul_rn(w, tn));
  } else {
    int i = (b-3169)*1024 + tid;
    {
      int e = i >> 11, r = i & 2047;
      ((unsigned short*)(ws + KB))[e*34816 + r] = 0;
    }
    if (i < 16*128){
      int e = i >> 7, r = i & 127;
      if (r < 64) ((unsigned short*)(ws + CRB0))[e*32832 + (r==0 ? 0 : 32768 + r)] = 0;
      else        ((unsigned short*)(ws + CRB1))[e*32832 + 32768 + (r-64)] = 0;
    }
  }
}

// ================= front-end =================

__global__ void k_fbpool(const float* __restrict__ fbw, float* __restrict__ ws){
  const float* S = ws + S_OFF;
  int c = blockIdx.x >> 5, j0 = (blockIdx.x & 31) << 2;
  int jj = threadIdx.x >> 7, kk = threadIdx.x & 127;
  int j = j0 + jj;
  int i0 = max(0, 256*j - 256), i1 = min(32767, 256*j + 255);
  float acc = 0.f;
#pragma unroll
  for (int m=0;m<4;++m){
    int k = kk + (m<<7);
    int hi = min(max(i1 + k - 255, 0), 32768);
    int lo = min(max(i0 + k - 256, 0), 32768);
    acc += fbw[c*512 + k] * (S[hi] - S[lo]);
  }
  for (int o=32;o;o>>=1) acc += __shfl_down(acc, o);
  __shared__ float red[8];
  if ((threadIdx.x & 63) == 0) red[threadIdx.x>>6] = acc;
  __syncthreads();
  if (threadIdx.x < 4)
    ws[HP + c*128 + j0 + threadIdx.x] = (red[2*threadIdx.x] + red[2*threadIdx.x+1]) * (1.0f/512.0f);
}

// normalize hp by global L2 norm once: hpn -> PA scratch
__global__ void k_norm(float* __restrict__ ws){
  __shared__ float red[1024];
  int b = blockIdx.x, tid = threadIdx.x;
  const float* hp = ws + HP;
  float s = 0.f;
  for (int i=tid; i<16384; i+=1024){ float v = hp[i]; s += v*v; }
  red[tid] = s; __syncthreads();
  for (int ofs=512; ofs>=1; ofs>>=1){ if (tid < ofs) red[tid] += red[tid+ofs]; __syncthreads(); }
  float g = sqrtf(red[0]) + 1e-8f;
  int i = b*1024 + tid;
  ws[PA + i] = __fdiv_rn(hp[i], g);
}

// reduce linear + positional encoding: 512 threads, 4-way c-split, rw row LDS-staged
__global__ void k_reduce(const float* __restrict__ rw, const float* __restrict__ rb,
                         float* __restrict__ ws){
  int o = blockIdx.x, tid = threadIdx.x;
  int t = tid & 127, cg = tid >> 7;
  __shared__ float wl[161];
  __shared__ float pr[512];
  const float* hpn = ws + PA;
  if (tid < 161) wl[tid] = rw[o*161 + tid];
  __syncthreads();
  float acc = 0.f;
  int cb = cg << 5;
  for (int c2=0;c2<32;++c2){
    int c = cb + c2;
    acc += wl[c] * hpn[(c<<7) + t];
  }
  pr[tid] = acc;
  __syncthreads();
  if (tid < 128){
    float a = rb[o] + pr[tid] + pr[128+tid] + pr[256+tid] + pr[384+tid];
    float delta = __fdiv_rn(2.0f, 127.0f);
    float p = __fadd_rn(-1.0f, __fmul_rn((float)tid, delta));
    a += wl[128] * p;
    float sc = 1.0f;
    const float PIF = (float)M_PI;
#pragma unroll
    for (int i=0;i<16;++i){
      float f = __fmul_rn(__fmul_rn(p, sc), PIF);
      a += wl[129 + 2*i] * sinf(f);
      a += wl[130 + 2*i] * cosf(f);
      sc = sc * 2.0f;
    }
    ws[HA + o*128 + tid] = a;
  }
}

// dilated conv layer: 256 threads, 2-way c-split, LDS partial reduce
__global__ void k_dil(float* __restrict__ ws, int l, int d, int inoff, int outoff){
  __shared__ float xin[16384];
  __shared__ float pr[256];
  int o = blockIdx.x, tid = threadIdx.x;
  int t = tid & 127, half = tid >> 7;
  const float* in = ws + inoff;
  for (int idx=tid; idx<16384; idx+=256) xin[idx] = in[idx];
  __syncthreads();
  const float* Wo = ws + WC + (l*128 + o)*384 + half*192;
  float acc = (half == 0) ? (xin[o*128 + t] + ws[WBC + l*128 + o]) : 0.f;
  int cbase = half << 6;
  for (int c2=0;c2<64;++c2){
    int c = cbase + c2;
    float v0 = (t-d >= 0)  ? xin[c*128 + t - d] : 0.f;
    float v1 = xin[c*128 + t];
    float v2 = (t+d < 128) ? xin[c*128 + t + d] : 0.f;
    acc += Wo[c2*3]*v0 + Wo[c2*3+1]*v1 + Wo[c2*3+2]*v2;
  }
  pr[half*128 + t] = acc;
  __syncthreads();
  if (tid < 128){
    float a = pr[tid] + pr[128 + tid];
    ws[outoff + o*128 + tid] = a >= 0.f ? a : 0.2f*a;
  }
}

// topk + encoded: 1024 threads, LDS-staged h (swizzled), split reductions
__global__ void k_topk(float* __restrict__ ws, float* __restrict__ out){
  const float* h = ws + HB;
  int tid = threadIdx.x;
  int g = tid >> 7, t = tid & 127;
  __shared__ float xs[16384];
  __shared__ float part[1024];
  __shared__ float nt[128], nt0[128], csh[128];
  __shared__ int idxs[16];
  __shared__ float gsh[1];
  __shared__ float wv[2]; __shared__ int wi[2];
  for (int idx=tid; idx<16384; idx+=1024){
    int c = idx >> 7, tt = idx & 127;
    xs[(c<<7) + ((tt+c)&127)] = h[idx];
  }
  __syncthreads();
  float p = 0.f;
  for (int c=g; c<128; c+=8){ float v = xs[(c<<7) + ((t+c)&127)]; p += v*v; }
  part[tid] = p;
  __syncthreads();
  if (tid < 128){
    float cs = 0.f;
#pragma unroll
    for (int gg=0; gg<8; ++gg) cs += part[(gg<<7) + tid];
    csh[tid] = cs;
  }
  __syncthreads();
  if (tid < 64){
    float s = csh[tid] + csh[tid+64];
    for (int o=32;o;o>>=1) s += __shfl_down(s, o);
    if (tid == 0) gsh[0] = sqrtf(s) + 1e-8f;
  }
  __syncthreads();
  float g2 = gsh[0];
  float p2 = 0.f;
  for (int c=g; c<128; c+=8){ float v = __fdiv_rn(xs[(c<<7) + ((t+c)&127)], g2); p2 += v*v; }
  part[tid] = p2;
  __syncthreads();
  if (tid < 128){
    float cs = 0.f;
#pragma unroll
    for (int gg=0; gg<8; ++gg) cs += part[(gg<<7) + tid];
    float ntv = sqrtf(cs);
    nt[tid] = ntv; nt0[tid] = ntv;
  }
  __syncthreads();
  for (int j=0;j<16;++j){
    if (tid < 128){
      float v = nt[t]; int bi = t;
      for (int o=32;o;o>>=1){
        float ov = __shfl_down(v, o); int oi = __shfl_down(bi, o);
        if (ov > v || (ov == v && oi < bi)){ v = ov; bi = oi; }
      }
      if ((t & 63) == 0){ wv[t>>6] = v; wi[t>>6] = bi; }
    }
    __syncthreads();
    if (tid == 0){
      int win = (wv[1] > wv[0] || (wv[1] == wv[0] && wi[1] < wi[0])) ? wi[1] : wi[0];
      idxs[j] = win; nt[win] = -3.0e38f;
    }
    __syncthreads();
  }
  if (tid < 16) out[O_IDX + tid] = (float)idxs[tid];
  for (int pos=tid; pos<2048; pos+=1024){
    int j = pos >> 7, ch = pos & 127;
    int ij = idxs[j];
    float hv = __fdiv_rn(xs[(ch<<7) + ((ij+ch)&127)], g2);
    float enc = __fdiv_rn(hv, nt0[ij] + 1e-8f);
    out[O_ENC + pos] = enc;
    ws[EWS + pos] = enc;
  }
}

__global__ void k_tt(float* __restrict__ ws, const float* __restrict__ ttb,
                     const float* __restrict__ trb, float* __restrict__ out){
  int kind = blockIdx.x >> 4, j = blockIdx.x & 15;
  int tid = threadIdx.x;
  int o = tid & 127, cg = tid >> 7;
  __shared__ float er[128];
  __shared__ float part[8][128];
  if (tid < 128) er[tid] = ws[EWS + j*128 + tid];
  __syncthreads();
  const float* Wt = ws + (kind ? WT_TR : WT_TT);
  float acc = 0.f;
  for (int c=cg; c<128; c+=8) acc += er[c] * Wt[c*128 + o];
  part[cg][o] = acc;
  __syncthreads();
  if (tid < 128){
    float a = kind ? trb[tid] : ttb[tid];
#pragma unroll
    for (int g=0; g<8; ++g) a += part[g][tid];
    out[(kind ? O_TR : O_TIME) + j*128 + tid] = a;
    ws[(kind ? TRANSO : TIMEO) + j*128 + tid] = a;
  }
}

// ================= decoder stacks =================

// fused linears: block = (stack, e, s); 1024 threads = 8 kg x 128 c; LT is [s][k][c]
__global__ void k_lin3(float* __restrict__ ws, const float* __restrict__ plb,
                       const float* __restrict__ elb, const float* __restrict__ tlb){
  int b = blockIdx.x, tid = threadIdx.x;
  int kg = tid >> 7, c = tid & 127;
  int e, s, start, ltoff, zoff, dst;
  const float* lb;
  if (b < 64){
    e = b >> 2; s = b & 3; start = 4; ltoff = LT_POS; zoff = TIMEO; dst = PA; lb = plb;
  } else if (b < 128){
    int b2 = b - 64; e = b2 >> 2; s = b2 & 3; start = 4; ltoff = LT_ENV; zoff = TRANSO; dst = BUFA; lb = elb;
  } else {
    int b2 = b - 128; e = b2 >> 3; s = b2 & 7; start = 8; ltoff = LT_TFU; zoff = TRANSO; dst = TA; lb = tlb;
  }
  __shared__ float z[128];
  __shared__ float part[8][128];
  if (tid < 128) z[tid] = ws[zoff + e*128 + tid];
  __syncthreads();
  const float* lt = ws + ltoff + (s << 14);
  float acc = 0.f;
  for (int k=kg; k<128; k+=8) acc += z[k] * lt[(k<<7) + c];
  part[kg][c] = acc;
  __syncthreads();
  if (tid < 128){
    float a = lb[tid*start + s];
#pragma unroll
    for (int g=0; g<8; ++g) a += part[g][tid];
    ws[dst + e*(start<<7) + (s<<7) + tid] = a;   // (e, s, c) layout
  }
}

// convT (k=4, stride2), JT=8
static __device__ __forceinline__ void convT8_dev(float* __restrict__ ws, const float* __restrict__ bias,
                                                  int srcoff, int dstoff, int wtoff, int Lin,
                                                  int e, int jt, float* xs, float* wl){
  int j0 = jt*8, o = threadIdx.x;
  int s_lo = (j0 >> 1) - 1;
  const float* in = ws + srcoff + e*Lin*128;
  for (int idx=o; idx<6*128; idx+=128){
    int si = idx >> 7, c = idx & 127, s = s_lo + si;
    xs[idx] = (s >= 0 && s < Lin) ? in[s*128 + c] : 0.f;
  }
  float acc[8];
#pragma unroll
  for (int jj=0;jj<8;++jj) acc[jj] = bias[o];
  const float* wt = ws + wtoff;
#pragma unroll 1
  for (int cb=0; cb<128; cb+=16){
    __syncthreads();
    for (int idx=o; idx<8192; idx+=128) wl[idx] = wt[(cb<<9) + idx];
    __syncthreads();
#pragma unroll
    for (int cc=0; cc<16; ++cc){
      int c = cb + cc;
      float w0 = wl[((cc<<2)+0)*128 + o];
      float w1 = wl[((cc<<2)+1)*128 + o];
      float w2 = wl[((cc<<2)+2)*128 + o];
      float w3 = wl[((cc<<2)+3)*128 + o];
      float xr[6];
#pragma unroll
      for (int s=0;s<6;++s) xr[s] = xs[(s<<7) + c];
#pragma unroll
      for (int jj=0;jj<8;++jj){
        if ((jj & 1) == 0){
          acc[jj] += xr[jj>>1]*w3 + xr[(jj>>1)+1]*w1;
        } else {
          acc[jj] += xr[(jj+1)>>1]*w2 + xr[((jj+1)>>1)+1]*w0;
        }
      }
    }
  }
  float* outp = ws + dstoff + e*(Lin*2)*128;
#pragma unroll
  for (int jj=0;jj<8;++jj){
    float v = acc[jj];
    outp[(j0+jj)*128 + o] = v >= 0.f ? v : 0.2f*v;
  }
}

// conv3 on nearest-2x-upsampled input, JT=8
static __device__ __forceinline__ void conv3up8_dev(float* __restrict__ ws, const float* __restrict__ bias,
                                                    int srcoff, int dstoff, int wtoff, int Lin,
                                                    int e, int jt, float* xs, float* wl){
  int j0 = jt*8, o = threadIdx.x;
  int fs = (j0 >> 1) - 1;
  const float* in = ws + srcoff + e*Lin*128;
  for (int idx=o; idx<6*128; idx+=128){
    int si = idx >> 7, c = idx & 127, s = fs + si;
    xs[idx] = (s >= 0 && s < Lin) ? in[s*128 + c] : 0.f;
  }
  float acc[8];
#pragma unroll
  for (int jj=0;jj<8;++jj) acc[jj] = bias[o];
  const float* wt = ws + wtoff;
#pragma unroll 1
  for (int cb=0; cb<128; cb+=16){
    __syncthreads();
    for (int idx=o; idx<6144; idx+=128) wl[idx] = wt[cb*384 + idx];
    __syncthreads();
#pragma unroll
    for (int cc=0; cc<16; ++cc){
      int c = cb + cc;
      float w0 = wl[(cc*3+0)*128 + o];
      float w1 = wl[(cc*3+1)*128 + o];
      float w2 = wl[(cc*3+2)*128 + o];
      float xr[6];
#pragma unroll
      for (int s=0;s<6;++s) xr[s] = xs[(s<<7) + c];
#pragma unroll
      for (int jj=0;jj<8;++jj){
        acc[jj] += xr[((jj-1)>>1)+1]*w0
                 + xr[((jj  )>>1)+1]*w1
                 + xr[((jj+1)>>1)+1]*w2;
      }
    }
  }
  float* outp = ws + dstoff + e*(Lin*2)*128;
#pragma unroll
  for (int jj=0;jj<8;++jj){
    float v = acc[jj];
    outp[(j0+jj)*128 + o] = v >= 0.f ? v : 0.2f*v;
  }
}

__global__ __launch_bounds__(128, 4)
void k_layer(float* __restrict__ ws, const float* __restrict__ pbias,
             const float* __restrict__ ebias, const float* __restrict__ tbias,
             int c1, int c2,
             int pLin, int pWt, int pBo, int pNJ, int pSrc, int pDst,
             int eLin, int eWt, int eBo, int eNJ, int eSrc, int eDst,
             int tLin, int tWt, int tBo, int tNJ, int tSrc, int tDst){
  __shared__ float xs[6*128];
  __shared__ float wl[8192];
  int b = blockIdx.x;
  if (b < c1){
    int e = b / pNJ, jt = b - e*pNJ;
    convT8_dev(ws, pbias + pBo, pSrc, pDst, pWt, pLin, e, jt, xs, wl);
  } else if (b < c2){
    int bl = b - c1; int e = bl / eNJ, jt = bl - e*eNJ;
    conv3up8_dev(ws, ebias + eBo, eSrc, eDst, eWt, eLin, e, jt, xs, wl);
  } else {
    int bl = b - c2; int e = bl / tNJ, jt = bl - e*tNJ;
    conv3up8_dev(ws, tbias + tBo, tSrc, tDst, tWt, tLin, e, jt, xs, wl);
  }
}

// fused epilogues: blocks 0..15 out_pos, 16..79 out_env, 80..143 out_tfu ; 512 threads
__global__ void k_outs(float* __restrict__ ws,
                       const float* __restrict__ pw, const float* __restrict__ pb,
                       const float* __restrict__ ew, const float* __restrict__ eb,
                       const float* __restrict__ tw, const float* __restrict__ tb_,
                       float* __restrict__ out){
  __shared__ float xs[16384];
  int b = blockIdx.x, tid = threadIdx.x;
  if (b < 16){
    int e = b;
    const float* in = ws + PB + e*16384;
    for (int idx=tid; idx<16384; idx+=512){
      int q = idx >> 7, c = idx & 127;
      xs[(q<<7) + ((c+q)&127)] = in[idx];
    }
    __syncthreads();
    int j = tid & 127, cg = tid >> 7;        // 4-way c-split
    float acc = (cg == 0) ? pb[0] : 0.f;
    int cbase = cg << 5;
    for (int c2=0;c2<32;++c2){
      int c = cbase + c2;
#pragma unroll
      for (int k=0;k<3;++k){
        int q = j + k - 1;
        if (q >= 0 && q < 128) acc += xs[(q<<7) + ((c+q)&127)] * pw[c*3 + k];
      }
    }
    __syncthreads();                          // xs staging dead; reuse
    xs[tid] = acc;
    __syncthreads();
    float a = 0.f;
    if (tid < 128) a = xs[tid] + xs[128+tid] + xs[256+tid] + xs[384+tid];
    __syncthreads();
    xs[tid] = (tid < 128) ? a : -3.0e38f;
    __syncthreads();
    for (int s=256; s>=1; s>>=1){ if (tid < s) xs[tid] = fmaxf(xs[tid], xs[tid+s]); __syncthreads(); }
    float m = xs[0];
    __syncthreads();
    float ex = (tid < 128) ? expf(__fsub_rn(a, m)) : 0.f;
    xs[tid] = ex;
    __syncthreads();
    for (int s=256; s>=1; s>>=1){ if (tid < s) xs[tid] += xs[tid+s]; __syncthreads(); }
    if (tid < 128) ws[PE + e*128 + tid] = __fdiv_rn(ex, xs[0]);
  } else if (b < 80){
    int idx2 = b - 16; int e = idx2 >> 2, b0 = (idx2 & 3) << 6;
    const float* in = ws + BUFA + e*32768;
    for (int idx=tid; idx<8448; idx+=512){
      int qs = idx >> 7, c = idx & 127, q = b0 - 1 + qs;
      xs[(qs<<7) + ((c+qs)&127)] = (q >= 0 && q < 256) ? in[q*128 + c] : 0.f;
    }
    __syncthreads();
    int part = tid >> 6, bb = tid & 63;       // 8-way c-split
    float acc = (part == 0) ? eb[0] : 0.f;
    for (int c2=0;c2<16;++c2){
      int c = part*16 + c2;
#pragma unroll
      for (int k=0;k<3;++k){
        int qs = bb + k;
        acc += xs[(qs<<7) + ((c+qs)&127)] * ew[c*3 + k];
      }
    }
    xs[8448 + tid] = acc;
    __syncthreads();
    if (tid < 64){
      float a = 0.f;
#pragma unroll
      for (int g=0; g<8; ++g) a += xs[8448 + g*64 + tid];
      a = fmaxf(a, 0.f);
      out[O_ENV + e*256 + b0 + tid] = a;
      ws[ENVO + e*256 + b0 + tid] = a;
    }
  } else {
    int b2 = b - 80; int e = b2 >> 2, rg = b2 & 3;
    float* tws = xs + 8448;
    const float* in = ws + TB + e*8192;
    for (int idx=tid; idx<8448; idx+=512){
      int qs = idx >> 7, c = idx & 127, q = -1 + qs;
      xs[(qs<<7) + ((c+qs)&127)] = (q >= 0 && q < 64) ? in[q*128 + c] : 0.f;
    }
    for (int idx=tid; idx<3072; idx+=512) tws[idx] = tw[rg*3072 + idx];
    __syncthreads();
    int rl = tid >> 6, bb = tid & 63;         // 1 row per thread
    int rr = rg*8 + rl;
    float acc = tb_[rr];
    for (int c=0;c<128;++c){
#pragma unroll
      for (int k=0;k<3;++k){
        int qs = bb + k;
        acc += xs[(qs<<7) + ((c+qs)&127)] * tws[rl*384 + c*3 + k];
      }
    }
    ws[TFQ + e*2048 + rr*64 + bb] = acc;
  }
}

// ================= synthesis =================

__global__ void k_envK(float* __restrict__ ws, const float* __restrict__ noise){
  int b = blockIdx.x, tid = threadIdx.x;
  if (b < 2048){
    int e = b >> 7, F = b & 127;
    int t = (F << 8) + tid;
    __shared__ float ampl[64];
    if (tid < 64){
      const float* tf = ws + TFQ + e*2048;
      float best = tf[tid]; int bi = 0;
      for (int r=1;r<32;++r){ float v = tf[r*64 + tid]; if (v > best){ best = v; bi = r; } }
      float d = __fadd_rn(0.5f, __fmul_rn((float)bi, __fdiv_rn(__fsub_rn(0.9999f, 0.5f), 31.0f)));
      ampl[tid] = (float)pow((double)d, (double)F);
    }
    __syncthreads();
    float acc = 0.f;
    for (int band=0;band<64;++band) acc += ws[SINES + band*NSAMP + t] * ampl[band];
    ((unsigned short*)(ws + KB))[e*34816 + 2048 + t] = f2bf(acc * (1.0f/(64.0f*65536.0f)));
  } else {
    int idx = (b - 2048)*256 + tid;
    int e = idx >> 15, tau = idx & 32767;
    float cf = __fsub_rn(__fdiv_rn(__fmul_rn(__fadd_rn((float)tau, 0.5f), 256.0f), 32768.0f), 0.5f);
    float c = fminf(fmaxf(cf, 0.0f), 255.0f);
    int i0 = (int)floorf(c);
    int i1 = min(i0 + 1, 255);
    float w = __fsub_rn(c, (float)i0);
    float e0 = ws[ENVO + e*256 + i0], e1 = ws[ENVO + e*256 + i1];
    float val = __fadd_rn(__fmul_rn(e0, __fsub_rn(1.0f, w)), __fmul_rn(e1, w));
    ws[ENVS + e*NSAMP + tau] = val * noise[tau];
  }
}

__global__ void k_c(float* __restrict__ ws){
  int e = blockIdx.x >> 5, seg = blockIdx.x & 31;
  int t = (seg << 10) + threadIdx.x;
  __shared__ float pl[128];
  if (threadIdx.x < 128) pl[threadIdx.x] = ws[PE + e*128 + threadIdx.x];
  __syncthreads();
  const float* ev = ws + ENVS + e*NSAMP;
  int kub = min(127, (seg << 2) + 3);
  float acc = 0.f;
  for (int k=0;k<=kub;++k){
    int u = t - (k << 8);
    if (u >= 0) acc += pl[k] * ev[u];
  }
  unsigned short hv = f2bf(acc);
  ((unsigned short*)(ws + CRB0))[e*32832 + 32768 - t] = hv;
  ((unsigned short*)(ws + CRB1))[e*32832 + 32767 - t] = hv;
}

// Toeplitz conv via MFMA 32x32x16 bf16; K operand LDS-staged (padded, conflict-free),
// red buffer aliases the staging pool; no atomics.
__global__ __launch_bounds__(256, 4)
void k_bigmfma(float* __restrict__ ws){
  int b = blockIdx.x;
  int w = threadIdx.x >> 6;
  int lane = threadIdx.x & 63;
  int e = b / 72;
  int r = b - e*72;
  int T2 = 0, cum = 0;
  while (cum + ((T2+2)>>1) <= r){ cum += (T2+2)>>1; T2++; }
  int qb = r - cum;
  int nseg = 2*(T2+1);
  int seg = qb*4 + w;
  int t0 = T2 << 11;
  int il = lane & 31, h = lane >> 5;
  __shared__ __align__(16) float pool[4096];        // 16 KB: K stage, then red
  unsigned short* ks = (unsigned short*)pool;
  int wmax = nseg - 1 - qb*4; if (wmax > 3) wmax = 3;
  int U0 = -1984 + (qb << 12);
  int kcnt = wmax*1024 + 3008;
  const unsigned short* Kp = (const unsigned short*)(ws + KB) + e*34816 + 2048;
  {
    const unsigned short* src = Kp + U0;
    for (int i = threadIdx.x*8; i < kcnt; i += 2048){
      f32x4 v = *(const f32x4*)(src + i);
      *(f32x4*)(ks + i + ((i>>6)<<3)) = v;          // padded: +8 ushorts per 64
    }
  }
  __syncthreads();
  f32x16 acc0 = {}; f32x16 acc1 = {};
  if (seg < nseg){
    int u0 = -1984 + (seg << 10);
    const unsigned short* C0p = (const unsigned short*)(ws + CRB0) + e*32832;
    const unsigned short* C1p = (const unsigned short*)(ws + CRB1) + e*32832;
    int ku  = (u0 - U0) + (il << 6) + (h << 3);
    int bA0 = 32768 - t0 + u0 - (il << 1) + (h << 3);
    int bA1 = bA0 - 2;
#pragma unroll 2
    for (int q = 0; q < 64; ++q){
      union { f32x4 v; bf16x8 s; } a0u, a1u, bu;
      a0u.v = *(const f32x4*)(C0p + bA0);
      a1u.v = *(const f32x4*)(C1p + bA1);
      int pa = ku + ((ku>>6)<<3);
      bu.v  = *(const f32x4*)(ks + pa);
      acc0 = __builtin_amdgcn_mfma_f32_32x32x16_bf16(a0u.s, bu.s, acc0, 0, 0, 0);
      acc1 = __builtin_amdgcn_mfma_f32_32x32x16_bf16(a1u.s, bu.s, acc1, 0, 0, 0);
      bA0 += 16; bA1 += 16; ku += 16;
    }
  }
  __syncthreads();                                   // K stage dead; reuse as red
  float* red = pool;
  int wl = w & 1;
  if (w < 2){
#pragma unroll
    for (int rr = 0; rr < 16; ++rr){
      int row = (rr & 3) + ((rr >> 2) << 3) + (h << 2);
      red[(wl<<11) + (row << 6) + il]      = acc0[rr];
      red[(wl<<11) + (row << 6) + 32 + il] = acc1[rr];
    }
  }
  __syncthreads();
  if (w >= 2){
#pragma unroll
    for (int rr = 0; rr < 16; ++rr){
      int row = (rr & 3) + ((rr >> 2) << 3) + (h << 2);
      red[(wl<<11) + (row << 6) + il]      += acc0[rr];
      red[(wl<<11) + (row << 6) + 32 + il] += acc1[rr];
    }
  }
  __syncthreads();
  float* slab = ws + SLAB + b*2048;
  int tid = threadIdx.x;
#pragma unroll
  for (int jj = 0; jj < 8; ++jj){
    int pos = tid*8 + jj;
    int il2 = pos >> 6, x = pos & 63;
    int idx = ((x >> 1) << 6) + ((x & 1) << 5) + il2;
    slab[pos] = red[idx] + red[2048 + idx];
  }
}

__global__ void k_final(const float* __restrict__ ws, float* __restrict__ out){
  int t = blockIdx.x*1024 + threadIdx.x;
  int T2 = t >> 11, pos = t & 2047;
  int cum = 0;
  for (int j=0;j<T2;++j) cum += (j+2)>>1;
  int nb = (T2+2)>>1;
  float s = 0.f;
  for (int e=0;e<16;++e){
    const float* sl = ws + SLAB + (e*72 + cum)*2048 + pos;
    for (int q=0;q<nb;++q) s += sl[q*2048];
  }
  out[t] = s;
}

// ================= launcher =================

extern "C" void kernel_launch(void* const* d_in, const int* in_sizes, int n_in,
                              void* d_out, int out_size, void* d_ws, size_t ws_size,
                              hipStream_t stream){
  const float* x         = (const float*)d_in[0];
  const float* noise     = (const float*)d_in[1];
  const float* fb_w      = (const float*)d_in[2];
  const float* reduce_w  = (const float*)d_in[3];
  const float* reduce_b  = (const float*)d_in[4];
  const float* dl_dw     = (const float*)d_in[5];
  const float* dl_db     = (const float*)d_in[6];
  const float* dl_pw     = (const float*)d_in[7];
  const float* dl_pb     = (const float*)d_in[8];
  const float* tt_w      = (const float*)d_in[9];
  const float* tt_b      = (const float*)d_in[10];
  const float* tr_w      = (const float*)d_in[11];
  const float* tr_b      = (const float*)d_in[12];
  const float* pos_lin_w = (const float*)d_in[13];
  const float* pos_lin_b = (const float*)d_in[14];
  const float* pos_up_w  = (const float*)d_in[15];
  const float* pos_up_b  = (const float*)d_in[16];
  const float* pos_out_w = (const float*)d_in[17];
  const float* pos_out_b = (const float*)d_in[18];
  const float* env_lin_w = (const float*)d_in[19];
  const float* env_lin_b = (const float*)d_in[20];
  const float* env_up_w  = (const float*)d_in[21];
  const float* env_up_b  = (const float*)d_in[22];
  const float* env_out_w = (const float*)d_in[23];
  const float* env_out_b = (const float*)d_in[24];
  const float* tfu_lin_w = (const float*)d_in[25];
  const float* tfu_lin_b = (const float*)d_in[26];
  const float* tfu_up_w  = (const float*)d_in[27];
  const float* tfu_up_b  = (const float*)d_in[28];
  const float* tfu_out_w = (const float*)d_in[29];
  const float* tfu_out_b = (const float*)d_in[30];
  float* out = (float*)d_out;
  float* ws  = (float*)d_ws;

  k_setup<<<3201, 1024, 0, stream>>>(x, pos_up_w, env_up_w, tfu_up_w, tt_w, tr_w,
                                     pos_lin_w, env_lin_w, tfu_lin_w,
                                     dl_dw, dl_db, dl_pw, dl_pb, ws);
  k_fbpool<<<4096, 512, 0, stream>>>(fb_w, ws);
  k_norm<<<16, 1024, 0, stream>>>(ws);
  k_reduce<<<128, 512, 0, stream>>>(reduce_w, reduce_b, ws);
  const int DIL[5] = {1, 3, 9, 27, 1};
  int src = HA, dst = HB;
  for (int l=0;l<5;++l){
    k_dil<<<128, 256, 0, stream>>>(ws, l, DIL[l], src, dst);
    int tmp = src; src = dst; dst = tmp;
  }
  k_topk<<<1, 1024, 0, stream>>>(ws, out);
  k_tt<<<32, 1024, 0, stream>>>(ws, tt_b, tr_b, out);
  k_lin3<<<256, 1024, 0, stream>>>(ws, pos_lin_b, env_lin_b, tfu_lin_b);

  // fused decoder layers, JT=8 blocks (pos convT | env conv3 | tfu conv3)
  k_layer<<<64, 128, 0, stream>>>(ws, pos_up_b, env_up_b, tfu_up_b, 16, 32,
      4,  WT_POS + 0,      0,   1, PA,   PB,
      4,  WT_ENV + 0,      0,   1, BUFA, BUFB,
      8,  WT_TFU + 0,      0,   2, TA,   TB);
  k_layer<<<128, 128, 0, stream>>>(ws, pos_up_b, env_up_b, tfu_up_b, 32, 64,
      8,  WT_POS + 65536,  128, 2, PB,   PA,
      8,  WT_ENV + 49152,  128, 2, BUFB, BUFA,
      16, WT_TFU + 49152,  128, 4, TB,   TA);
  k_layer<<<256, 128, 0, stream>>>(ws, pos_up_b, env_up_b, tfu_up_b, 64, 128,
      16, WT_POS + 131072, 256, 4, PA,   PB,
      16, WT_ENV + 98304,  256, 4, BUFA, BUFB,
      32, WT_TFU + 98304,  256, 8, TA,   TB);
  k_layer<<<256, 128, 0, stream>>>(ws, pos_up_b, env_up_b, tfu_up_b, 128, 256,
      32, WT_POS + 196608, 384, 8, PB,   PA,
      32, WT_ENV + 147456, 384, 8, BUFB, BUFA,
      1,  0,               0,   1, 0,    0);
  k_layer<<<512, 128, 0, stream>>>(ws, pos_up_b, env_up_b, tfu_up_b, 256, 512,
      64, WT_POS + 262144, 512, 16, PA,   PB,
      64, WT_ENV + 196608, 512, 16, BUFA, BUFB,
      1,  0,               0,   1, 0,    0);
  k_layer<<<512, 128, 0, stream>>>(ws, pos_up_b, env_up_b, tfu_up_b, 0, 512,
      1,  0,               0,   1, 0,    0,
      128, WT_ENV + 245760, 640, 32, BUFB, BUFA,
      1,  0,               0,   1, 0,    0);

  k_outs<<<144, 512, 0, stream>>>(ws, pos_out_w, pos_out_b, env_out_w, env_out_b,
                                  tfu_out_w, tfu_out_b, out);

  k_envK<<<4096, 256, 0, stream>>>(ws, noise);
  k_c<<<512, 1024, 0, stream>>>(ws);
  k_bigmfma<<<1152, 256, 0, stream>>>(ws);
  k_final<<<32, 1024, 0, stream>>>(ws, out);
}